// Round 2
// baseline (1937.617 us; speedup 1.0000x reference)
//
#include <hip/hip_runtime.h>
#include <stdint.h>

// RWKV6 block: B=1, T=2048, C=2048, H=32, HS=64, FFN=7168, NS=4
// Workspace: 6*16M (f32) + 7*8M (bf16) + 28M (Wt) + 4M aux = 184 MiB.

#define TT 2048
#define CC 2048
#define NH 32
#define HSZ 64
#define FFND 7168
#define CHUNK 64
#define NCHUNK 32

typedef __attribute__((ext_vector_type(8))) short short8;
typedef __attribute__((ext_vector_type(4))) float f32x4;

__device__ __forceinline__ float bf2f(short s){
  return __uint_as_float(((uint32_t)(uint16_t)s) << 16);
}
__device__ __forceinline__ short f2bf(float f){
  uint32_t u = __float_as_uint(f);
  u = u + 0x7fffu + ((u >> 16) & 1u);
  return (short)(u >> 16);
}

// ---------------- LayerNorm (row over C) ----------------
__global__ __launch_bounds__(256) void ln_kernel(
    const float* __restrict__ xin, const float* __restrict__ gam,
    const float* __restrict__ bet, float* __restrict__ out, float eps)
{
  int t = blockIdx.x, tid = threadIdx.x;
  const float* row = xin + (size_t)t*CC;
  float4 v0 = *(const float4*)(row + tid*8);
  float4 v1 = *(const float4*)(row + tid*8 + 4);
  float s  = v0.x+v0.y+v0.z+v0.w + v1.x+v1.y+v1.z+v1.w;
  float ss = v0.x*v0.x+v0.y*v0.y+v0.z*v0.z+v0.w*v0.w
           + v1.x*v1.x+v1.y*v1.y+v1.z*v1.z+v1.w*v1.w;
  #pragma unroll
  for(int off=1; off<64; off<<=1){ s += __shfl_xor(s,off); ss += __shfl_xor(ss,off); }
  __shared__ float sm[8];
  int w = tid>>6;
  if((tid&63)==0){ sm[w]=s; sm[4+w]=ss; }
  __syncthreads();
  s = sm[0]+sm[1]+sm[2]+sm[3]; ss = sm[4]+sm[5]+sm[6]+sm[7];
  float mean = s * (1.f/CC);
  float var  = ss * (1.f/CC) - mean*mean;
  float rstd = rsqrtf(var + eps);
  float* orow = out + (size_t)t*CC;
  int c = tid*8;
  float vv[8] = {v0.x,v0.y,v0.z,v0.w,v1.x,v1.y,v1.z,v1.w};
  #pragma unroll
  for(int j=0;j<8;j++) orow[c+j] = (vv[j]-mean)*rstd*gam[c+j] + bet[c+j];
}

// ---------------- token shift (attention): xx = sh - xa (f32 out) ----------------
__global__ __launch_bounds__(256) void shift1_kernel(
    const float* __restrict__ xa, const float* __restrict__ st,
    const int* __restrict__ sp, float* __restrict__ xxb)
{
  int t = blockIdx.x, tid = threadIdx.x;
  int sp0=sp[0], sp1=sp[1], sp2=sp[2], sp3=sp[3];
  bool is_start = (sp0==t)|(sp1==t)|(sp2==t)|(sp3==t);
  int sid = (sp0<=t)+(sp1<=t)+(sp2<=t)+(sp3<=t) - 1;
  sid = sid<0?0:(sid>3?3:sid);
  int c = tid*8;
  const float* src = is_start ? (st + (size_t)sid*CC + c)
                   : (t>0 ? xa + (size_t)(t-1)*CC + c : nullptr);
  const float* cur = xa + (size_t)t*CC + c;
  float* o = xxb + (size_t)t*CC + c;
  #pragma unroll
  for(int jj=0;jj<8;jj++){
    float sh = src ? src[jj] : 0.f;
    o[jj] = sh - cur[jj];
  }
}

// ---------------- token shift (ffn): xk2/xr2 fused, bf16 out ----------------
__global__ __launch_bounds__(256) void shift2_kernel(
    const float* __restrict__ xf, const float* __restrict__ st,
    const int* __restrict__ sp, const float* __restrict__ cmk,
    const float* __restrict__ cmr, short* __restrict__ xk2, short* __restrict__ xr2)
{
  int t = blockIdx.x, tid = threadIdx.x;
  int sp0=sp[0], sp1=sp[1], sp2=sp[2], sp3=sp[3];
  bool is_start = (sp0==t)|(sp1==t)|(sp2==t)|(sp3==t);
  int sid = (sp0<=t)+(sp1<=t)+(sp2<=t)+(sp3<=t) - 1;
  sid = sid<0?0:(sid>3?3:sid);
  int c = tid*8;
  const float* src = is_start ? (st + (size_t)sid*CC + c)
                   : (t>0 ? xf + (size_t)(t-1)*CC + c : nullptr);
  const float* cur = xf + (size_t)t*CC + c;
  size_t ix = (size_t)t*CC + c;
  #pragma unroll
  for(int jj=0;jj<8;jj++){
    float xfv = cur[jj];
    float sh = src ? src[jj] : 0.f;
    float d = sh - xfv;
    xk2[ix+jj] = f2bf(xfv + d*cmk[c+jj]);
    xr2[ix+jj] = f2bf(xfv + d*cmr[c+jj]);
  }
}

// ---------------- z = xa + xx*maa_x (f32) ----------------
__global__ __launch_bounds__(256) void zprep_kernel(const float* __restrict__ xa,
   const float* __restrict__ xx, const float* __restrict__ maa, float* __restrict__ z)
{
  size_t i = ((size_t)blockIdx.x*256 + threadIdx.x)*8;
  int c = (int)(i & (CC-1));
  #pragma unroll
  for(int j=0;j<8;j++) z[i+j] = xa[i+j] + xx[i+j]*maa[c+j];
}

// ---------------- skinny GEMM + tanh: out[T,NOUT] = tanh(A[T,C] @ W[C,NOUT]) ----------------
// 4 tokens per block, 64 lanes each. Columns n, n+64, and n+128 (guarded vs NOUT).
template<int NOUT>
__global__ __launch_bounds__(256) void skinny_tanh_kernel(
    const float* __restrict__ Ain, const float* __restrict__ W, float* __restrict__ out)
{
  int t = blockIdx.x*4 + (threadIdx.x>>6);
  int n = threadIdx.x & 63;
  const float* arow = Ain + (size_t)t*CC;
  float acc0=0.f, acc1=0.f, acc2=0.f;
  bool has2 = (NOUT > 128) && (n + 128 < NOUT);
  #pragma unroll 4
  for(int k=0;k<CC;k++){
    float a = arow[k];
    const float* wr = W + (size_t)k*NOUT;
    acc0 += a*wr[n];
    if constexpr (NOUT>64)  acc1 += a*wr[n+64];
    if constexpr (NOUT>128) { if(has2) acc2 += a*wr[n+128]; }
  }
  float* orow = out + (size_t)t*NOUT;
  orow[n] = tanhf(acc0);
  if constexpr (NOUT>64)  orow[n+64]  = tanhf(acc1);
  if constexpr (NOUT>128) { if(has2) orow[n+128] = tanhf(acc2); }
}

// ---------------- one maa mix: x_s = xa + xx*(maa_s + xxx@w2_s) ----------------
template<int S, bool BF>
__global__ __launch_bounds__(256) void mix_kernel(
    const float* __restrict__ xxxb, const float* __restrict__ w2,
    const float* __restrict__ xa, const float* __restrict__ xxv,
    const float* __restrict__ maa, void* __restrict__ out)
{
  int g = blockIdx.x*256 + threadIdx.x;
  int c = g & (CC-1);
  int t0 = (g >> 11) * 8;
  float acc[8] = {0,0,0,0,0,0,0,0};
  for(int e=0;e<32;e++){
    float wv = w2[(size_t)(S*32+e)*CC + c];
    #pragma unroll
    for(int tt=0;tt<8;tt++)
      acc[tt] += xxxb[(size_t)(t0+tt)*160 + S*32 + e] * wv;
  }
  float mv = maa[c];
  #pragma unroll
  for(int tt=0;tt<8;tt++){
    size_t ix = (size_t)(t0+tt)*CC + c;
    float o = xa[ix] + xxv[ix]*(mv + acc[tt]);
    if constexpr (BF) ((short*)out)[ix] = f2bf(o);
    else              ((float*)out)[ix] = o;
  }
}

// ---------------- dec = exp(-exp(td + h1 @ td_w2)) (f32) ----------------
__global__ __launch_bounds__(256) void dec_kernel(
    const float* __restrict__ h1b, const float* __restrict__ tw2,
    const float* __restrict__ td, float* __restrict__ out)
{
  int g = blockIdx.x*256 + threadIdx.x;
  int c = g & (CC-1);
  int t0 = (g >> 11)*8;
  float acc[8] = {0,0,0,0,0,0,0,0};
  for(int e=0;e<64;e++){
    float wv = tw2[(size_t)e*CC + c];
    #pragma unroll
    for(int tt=0;tt<8;tt++) acc[tt] += h1b[(size_t)(t0+tt)*64 + e]*wv;
  }
  float tdc = td[c];
  #pragma unroll
  for(int tt=0;tt<8;tt++)
    out[(size_t)(t0+tt)*CC + c] = expf(-expf(tdc + acc[tt]));
}

// ---------------- W[K,N] f32 -> Wt[N,K] bf16 (transpose+convert) ----------------
__global__ __launch_bounds__(256) void transpose_f2bf_kernel(
    const float* __restrict__ W, short* __restrict__ Wt, int K, int N)
{
  __shared__ float tile[64][65];
  int n0 = blockIdx.x*64, k0 = blockIdx.y*64;
  int tid = threadIdx.x;
  #pragma unroll
  for(int q=0;q<16;q++){
    int ix = q*256 + tid;
    int r = ix >> 6, cc2 = ix & 63;
    tile[r][cc2] = W[(size_t)(k0+r)*N + n0 + cc2];
  }
  __syncthreads();
  #pragma unroll
  for(int q=0;q<16;q++){
    int ix = q*256 + tid;
    int r = ix >> 6, cc2 = ix & 63;
    Wt[(size_t)(n0+r)*K + k0 + cc2] = f2bf(tile[cc2][r]);
  }
}

// ---------------- bf16 MFMA GEMM (m97 structure): C[M,N] = A[M,K] @ Bt[N,K]^T ----------------
__device__ __forceinline__ void load_lds16(const void* g, void* l){
  __builtin_amdgcn_global_load_lds(
      (const __attribute__((address_space(1))) uint32_t*)g,
      (__attribute__((address_space(3))) uint32_t*)l, 16, 0, 0);
}

// EPI: 0 = bf16 store; 1 = silu bf16; 2 = f32 + residual; 3 = relu^2 bf16
template<int EPI>
__global__ __launch_bounds__(256) void gemm_bt_kernel(
    const short* __restrict__ A, const short* __restrict__ Bt,
    void* __restrict__ Cout, const float* __restrict__ extra,
    int M, int N, int K)
{
  __shared__ __align__(16) short As[128*32];
  __shared__ __align__(16) short Bs[128*32];
  int tid = threadIdx.x;
  int w = tid >> 6, lane = tid & 63;
  int l16 = lane & 15, lhi = lane >> 4;
  int wr = w >> 1, wc = w & 1;
  int bm = blockIdx.y, bn = blockIdx.x;
  const short* Ab = A + (size_t)bm*128*K;
  const short* Bb = Bt + (size_t)bn*128*K;
  f32x4 acc[4][4] = {};
  for(int kt=0; kt<K; kt+=32){
    __syncthreads();
    #pragma unroll
    for(int q=0;q<2;q++){
      int chunk = q*256 + tid;
      int row = chunk >> 2;
      int c8 = (chunk & 3)*8;
      int ldsoff = (q*256 + w*64)*8;   // wave-uniform LDS base (HW adds lane*16B)
      load_lds16(Ab + (size_t)row*K + kt + c8, As + ldsoff);
      load_lds16(Bb + (size_t)row*K + kt + c8, Bs + ldsoff);
    }
    __syncthreads();
    short8 af[4], bf[4];
    #pragma unroll
    for(int m=0;m<4;m++) af[m] = *(const short8*)(As + (wr*64 + m*16 + l16)*32 + lhi*8);
    #pragma unroll
    for(int n=0;n<4;n++) bf[n] = *(const short8*)(Bs + (wc*64 + n*16 + l16)*32 + lhi*8);
    #pragma unroll
    for(int m=0;m<4;m++){
      #pragma unroll
      for(int n=0;n<4;n++)
        acc[m][n] = __builtin_amdgcn_mfma_f32_16x16x32_bf16(af[m], bf[n], acc[m][n], 0, 0, 0);
    }
  }
  int m0 = bm*128 + wr*64;
  int n0 = bn*128 + wc*64;
  #pragma unroll
  for(int m=0;m<4;m++){
    #pragma unroll
    for(int n=0;n<4;n++){
      #pragma unroll
      for(int jj=0;jj<4;jj++){
        int row = m0 + m*16 + lhi*4 + jj;
        int col = n0 + n*16 + l16;
        size_t ix = (size_t)row*N + col;
        float val = acc[m][n][jj];
        if constexpr (EPI==0){ ((short*)Cout)[ix] = f2bf(val); }
        else if constexpr (EPI==1){ ((short*)Cout)[ix] = f2bf(val/(1.f+expf(-val))); }
        else if constexpr (EPI==2){ ((float*)Cout)[ix] = val + extra[ix]; }
        else { float rv = fmaxf(val, 0.f); ((short*)Cout)[ix] = f2bf(rv*rv); }
      }
    }
  }
}

// ---------------- WKV pass A: per-(chunk,head) local scan ----------------
// thread: a = tid&3 (i-subgroup of 16), j = tid>>2 (value column)
__global__ __launch_bounds__(256) void wkv_chunk_kernel(
    const short* __restrict__ rb, const short* __restrict__ kb,
    const short* __restrict__ vb, const float* __restrict__ db,
    const float* __restrict__ wkv_state, const float* __restrict__ u,
    const int* __restrict__ sp,
    float* __restrict__ yb, short* __restrict__ rtb,
    float* __restrict__ Bc, float* __restrict__ Pc)
{
  int blk = blockIdx.x;
  int ch = blk >> 5;       // chunk
  int h  = blk & 31;       // head
  int tid = threadIdx.x;
  int a = tid & 3, j = tid >> 2;
  __shared__ float sr[64], sk[64], sv[64], sd[64], su[64];
  if(tid < 64) su[tid] = u[h*64 + tid];
  float S[16], p[16];
  #pragma unroll
  for(int ii=0;ii<16;ii++){ S[ii]=0.f; p[ii]=1.f; }
  int sp0=sp[0], sp1=sp[1], sp2=sp[2], sp3=sp[3];
  for(int tl=0; tl<CHUNK; ++tl){
    int t = ch*CHUNK + tl;
    __syncthreads();
    size_t base = (size_t)t*CC + h*64;
    if(tid<64)        sr[tid]     = bf2f(rb[base + tid]);
    else if(tid<128)  sk[tid-64]  = bf2f(kb[base + (tid-64)]);
    else if(tid<192)  sv[tid-128] = bf2f(vb[base + (tid-128)]);
    else              sd[tid-192] = db[base + (tid-192)];
    __syncthreads();
    bool is_start = (sp0==t)|(sp1==t)|(sp2==t)|(sp3==t);
    if(is_start){
      int sid = (sp0<=t)+(sp1<=t)+(sp2<=t)+(sp3<=t) - 1;
      sid = sid<0?0:(sid>3?3:sid);
      const float* wsrc = wkv_state + (((size_t)sid*NH + h)*HSZ + a*16)*HSZ + j;
      #pragma unroll
      for(int ii=0;ii<16;ii++){ S[ii] = wsrc[(size_t)ii*HSZ]; p[ii] = 0.f; }
    }
    float vj = sv[j];
    float yp = 0.f, bp = 0.f;
    #pragma unroll
    for(int ii=0;ii<16;ii++){
      int i = a*16 + ii;
      float ri = sr[i];
      yp += ri * S[ii];
      bp += ri * su[i] * sk[i];
    }
    yp += __shfl_xor(yp, 1); yp += __shfl_xor(yp, 2);
    bp += __shfl_xor(bp, 1); bp += __shfl_xor(bp, 2);
    if(a == 0) yb[base + j] = yp + bp*vj;
    if(tid < 4){  // a==tid, j==0: owner of r~ and P for its 16 i's
      #pragma unroll
      for(int ii=0;ii<16;ii++) rtb[base + tid*16 + ii] = f2bf(sr[tid*16+ii] * p[ii]);
    }
    #pragma unroll
    for(int ii=0;ii<16;ii++){
      int i = a*16 + ii;
      S[ii] = sd[i]*S[ii] + sk[i]*vj;
    }
    if(tid < 4){
      #pragma unroll
      for(int ii=0;ii<16;ii++) p[ii] *= sd[tid*16+ii];
    }
  }
  size_t cb = ((size_t)ch*NH + h)*HSZ*HSZ;
  #pragma unroll
  for(int ii=0;ii<16;ii++) Bc[cb + (size_t)(a*16+ii)*HSZ + j] = S[ii];
  if(tid < 4){
    size_t pb = ((size_t)ch*NH + h)*HSZ;
    #pragma unroll
    for(int ii=0;ii<16;ii++) Pc[pb + tid*16 + ii] = p[ii];
  }
}

// ---------------- WKV pass B: sequential combine over chunks (in-place Bc->Sin) ----------------
__global__ __launch_bounds__(256) void wkv_combine_kernel(
    float* __restrict__ BS, const float* __restrict__ Pc)
{
  int idx = blockIdx.x*256 + threadIdx.x;   // h*4096 + i*64 + j
  int hi = idx >> 6;
  float s = 0.f;
  for(int cc=0; cc<NCHUNK; ++cc){
    size_t ix = (size_t)cc*(NH*HSZ*HSZ) + idx;
    float b = BS[ix];
    BS[ix] = s;                              // S_in for this chunk
    s = Pc[cc*(NH*HSZ) + hi]*s + b;
  }
}

// ---------------- WKV pass C: y += r~ @ S_in ----------------
__global__ __launch_bounds__(256) void wkv_corr_kernel(
    const short* __restrict__ rtb, const float* __restrict__ Sin, float* __restrict__ yb)
{
  int blk = blockIdx.x;
  int ch = blk >> 5, h = blk & 31;
  __shared__ float Ssm[64][64];
  __shared__ float Rsm[64][65];
  int tid = threadIdx.x;
  const float* Sp = Sin + (size_t)(ch*NH + h)*HSZ*HSZ;
  #pragma unroll
  for(int q=0;q<16;q++){
    int ix = q*256 + tid;
    ((float*)Ssm)[ix] = Sp[ix];
  }
  #pragma unroll
  for(int q=0;q<16;q++){
    int ix = q*256 + tid;
    int tl = ix>>6, i = ix&63;
    Rsm[tl][i] = bf2f(rtb[(size_t)(ch*64+tl)*CC + h*64 + i]);
  }
  __syncthreads();
  int tl = tid >> 2;
  int jq = tid & 3;
  float acc[16];
  #pragma unroll
  for(int jj=0;jj<16;jj++) acc[jj]=0.f;
  for(int i=0;i<64;i++){
    float rv = Rsm[tl][i];
    #pragma unroll
    for(int jj=0;jj<16;jj++) acc[jj] += rv * Ssm[i][jq*16+jj];
  }
  #pragma unroll
  for(int jj=0;jj<16;jj++){
    int j = jq*16 + jj;
    yb[(size_t)(ch*64+tl)*CC + h*64 + j] += acc[jj];
  }
}

// ---------------- GroupNorm(H groups) * g -> bf16 ----------------
__global__ __launch_bounds__(256) void gn_mul_kernel(
    const float* __restrict__ yb, const short* __restrict__ gb,
    const float* __restrict__ gam, const float* __restrict__ bet,
    short* __restrict__ yg)
{
  int t = blockIdx.x, tid = threadIdx.x;
  int w = tid >> 6, lane = tid & 63;
  for(int q=0;q<8;q++){
    int h = q*4 + w;
    int cc = h*64 + lane;
    float val = yb[(size_t)t*CC + cc];
    float s = val, ss = val*val;
    #pragma unroll
    for(int off=1;off<64;off<<=1){ s += __shfl_xor(s,off); ss += __shfl_xor(ss,off); }
    float mu = s*(1.f/64.f);
    float var = ss*(1.f/64.f) - mu*mu;
    float rstd = rsqrtf(var + 6.4e-4f);   // eps = 1e-5 * 8^2
    float o = (val-mu)*rstd*gam[cc] + bet[cc];
    yg[(size_t)t*CC + cc] = f2bf(o * bf2f(gb[(size_t)t*CC + cc]));
  }
}

// ---------------- final: out += sigmoid(s)*kv ----------------
__global__ __launch_bounds__(256) void final_kernel(const short* __restrict__ kv,
    const short* __restrict__ sb, float* __restrict__ out)
{
  size_t i = ((size_t)blockIdx.x*256 + threadIdx.x)*8;
  #pragma unroll
  for(int j=0;j<8;j++){
    float svv = bf2f(sb[i+j]);
    float sig = 1.f/(1.f + expf(-svv));
    out[i+j] = out[i+j] + sig*bf2f(kv[i+j]);
  }
}

extern "C" void kernel_launch(void* const* d_in, const int* in_sizes, int n_in,
                              void* d_out, int out_size, void* d_ws, size_t ws_size,
                              hipStream_t stream)
{
  (void)in_sizes; (void)n_in; (void)out_size;
  const float* x         = (const float*)d_in[0];
  const int*   sp        = (const int*)d_in[1];
  const float* att_state = (const float*)d_in[2];
  const float* wkv_state = (const float*)d_in[3];
  const float* ffn_state = (const float*)d_in[4];
  const float* ln1_g=(const float*)d_in[5],  *ln1_b=(const float*)d_in[6];
  const float* ln2_g=(const float*)d_in[7],  *ln2_b=(const float*)d_in[8];
  const float* maa_x=(const float*)d_in[9],  *maa_w=(const float*)d_in[10], *maa_k=(const float*)d_in[11];
  const float* maa_v=(const float*)d_in[12], *maa_r=(const float*)d_in[13], *maa_g=(const float*)d_in[14];
  const float* tm_w1=(const float*)d_in[15], *tm_w2=(const float*)d_in[16];
  const float* td=(const float*)d_in[17],    *td_w1=(const float*)d_in[18], *td_w2=(const float*)d_in[19];
  const float* u = (const float*)d_in[20];
  const float* Wr=(const float*)d_in[21], *Wk=(const float*)d_in[22], *Wv=(const float*)d_in[23];
  const float* Wg=(const float*)d_in[24], *Wo=(const float*)d_in[25];
  const float* lnx_g=(const float*)d_in[26], *lnx_b=(const float*)d_in[27];
  const float* cm_k=(const float*)d_in[28],  *cm_r=(const float*)d_in[29];
  const float* Wck=(const float*)d_in[30], *Wcv=(const float*)d_in[31], *Wcr=(const float*)d_in[32];

  char* ws = (char*)d_ws;
  const size_t SLOT  = (size_t)TT*CC*4;      // 16 MiB (f32 [T,C])
  const size_t BSLOT = (size_t)TT*CC*2;      // 8 MiB  (bf16 [T,C])
  const size_t WT_SZ = (size_t)FFND*CC*2;    // 28 MiB (largest W^T bf16)
  const size_t NEED  = 6*SLOT + 7*BSLOT + WT_SZ + (4u<<20);
  if(ws_size < NEED) return;   // diagnostic: leaves d_out poisoned instead of faulting

  float* xa   = (float*)(ws + 0*SLOT);   // S0 (FFN: hid low half)
  float* xxb  = (float*)(ws + 1*SLOT);   // S1 (FFN: hid high half)
  float* zw   = (float*)(ws + 2*SLOT);   // S2: z -> xw -> xf
  float* decb = (float*)(ws + 3*SLOT);   // S3
  float* yb   = (float*)(ws + 4*SLOT);   // S4
  float* BS   = (float*)(ws + 5*SLOT);   // S5: Bc -> Sin (in place)
  char*  bfb  = ws + 6*SLOT;
  short* b0 = (short*)(bfb + 0*BSLOT);   // mix staging (r/k/v/g inputs, serially)
  short* b1 = (short*)(bfb + 1*BSLOT);   // rb   (FFN: kvb)
  short* b2 = (short*)(bfb + 2*BSLOT);   // kb   (FFN: sbuf)
  short* b3 = (short*)(bfb + 3*BSLOT);   // vb   (FFN: xk2)
  short* b4 = (short*)(bfb + 4*BSLOT);   // gb   (FFN: xr2)
  short* b5 = (short*)(bfb + 5*BSLOT);   // rtb
  short* b6 = (short*)(bfb + 6*BSLOT);   // yg
  short* Bbf = (short*)(bfb + 7*BSLOT);  // transposed weight, 28 MiB
  char*  aux = (char*)Bbf + WT_SZ;
  float* xxxb = (float*)(aux);                 // 1.25 MiB
  float* h1b  = (float*)(aux + (2u<<20));      // 0.5 MiB
  float* Pc   = (float*)(aux + (3u<<20));      // 0.25 MiB
  short* hid  = (short*)(ws + 0*SLOT);         // 28 MiB over S0..S1 (FFN phase)
  float* xmid = (float*)d_out;

  dim3 B256(256);
  const int NTC8 = TT*CC/8/256;   // 2048 blocks for flat [T,C] elementwise

  // ---- Tmix front ----
  ln_kernel<<<TT, B256, 0, stream>>>(x, ln1_g, ln1_b, xa, 1e-5f);
  shift1_kernel<<<TT, B256, 0, stream>>>(xa, att_state, sp, xxb);
  zprep_kernel<<<NTC8, B256, 0, stream>>>(xa, xxb, maa_x, zw);
  skinny_tanh_kernel<160><<<TT/4, B256, 0, stream>>>(zw, tm_w1, xxxb);
  mix_kernel<0,false><<<NTC8, B256, 0, stream>>>(xxxb, tm_w2, xa, xxb, maa_w, zw); // xw -> S2
  skinny_tanh_kernel<64><<<TT/4, B256, 0, stream>>>(zw, td_w1, h1b);
  dec_kernel<<<NTC8, B256, 0, stream>>>(h1b, td_w2, td, decb);

  // ---- r,k,v,g projections (bf16 MFMA), staged through b0 ----
  mix_kernel<3,true><<<NTC8, B256, 0, stream>>>(xxxb, tm_w2, xa, xxb, maa_r, b0);
  transpose_f2bf_kernel<<<dim3(CC/64, CC/64), B256, 0, stream>>>(Wr, Bbf, CC, CC);
  gemm_bt_kernel<0><<<dim3(CC/128, TT/128), B256, 0, stream>>>(b0, Bbf, b1, nullptr, TT, CC, CC);
  mix_kernel<1,true><<<NTC8, B256, 0, stream>>>(xxxb, tm_w2, xa, xxb, maa_k, b0);
  transpose_f2bf_kernel<<<dim3(CC/64, CC/64), B256, 0, stream>>>(Wk, Bbf, CC, CC);
  gemm_bt_kernel<0><<<dim3(CC/128, TT/128), B256, 0, stream>>>(b0, Bbf, b2, nullptr, TT, CC, CC);
  mix_kernel<2,true><<<NTC8, B256, 0, stream>>>(xxxb, tm_w2, xa, xxb, maa_v, b0);
  transpose_f2bf_kernel<<<dim3(CC/64, CC/64), B256, 0, stream>>>(Wv, Bbf, CC, CC);
  gemm_bt_kernel<0><<<dim3(CC/128, TT/128), B256, 0, stream>>>(b0, Bbf, b3, nullptr, TT, CC, CC);
  mix_kernel<4,true><<<NTC8, B256, 0, stream>>>(xxxb, tm_w2, xa, xxb, maa_g, b0);
  transpose_f2bf_kernel<<<dim3(CC/64, CC/64), B256, 0, stream>>>(Wg, Bbf, CC, CC);
  gemm_bt_kernel<1><<<dim3(CC/128, TT/128), B256, 0, stream>>>(b0, Bbf, b4, nullptr, TT, CC, CC);

  // ---- WKV chunked scan ----
  wkv_chunk_kernel<<<NCHUNK*NH, B256, 0, stream>>>(b1, b2, b3, decb, wkv_state, u, sp,
                                                   yb, b5, BS, Pc);
  wkv_combine_kernel<<<NH*HSZ*HSZ/256, B256, 0, stream>>>(BS, Pc);
  wkv_corr_kernel<<<NCHUNK*NH, B256, 0, stream>>>(b5, BS, yb);
  gn_mul_kernel<<<TT, B256, 0, stream>>>(yb, b4, lnx_g, lnx_b, b6);

  // ---- output projection + residual ----
  transpose_f2bf_kernel<<<dim3(CC/64, CC/64), B256, 0, stream>>>(Wo, Bbf, CC, CC);
  gemm_bt_kernel<2><<<dim3(CC/128, TT/128), B256, 0, stream>>>(b6, Bbf, xmid, x, TT, CC, CC);

  // ---- CMix ----
  ln_kernel<<<TT, B256, 0, stream>>>(xmid, ln2_g, ln2_b, zw, 1e-5f);
  shift2_kernel<<<TT, B256, 0, stream>>>(zw, ffn_state, sp, cm_k, cm_r, b3, b4);
  transpose_f2bf_kernel<<<dim3(FFND/64, CC/64), B256, 0, stream>>>(Wck, Bbf, CC, FFND);
  gemm_bt_kernel<3><<<dim3(FFND/128, TT/128), B256, 0, stream>>>(b3, Bbf, hid, nullptr, TT, FFND, CC);
  transpose_f2bf_kernel<<<dim3(CC/64, FFND/64), B256, 0, stream>>>(Wcv, Bbf, FFND, CC);
  gemm_bt_kernel<0><<<dim3(CC/128, TT/128), B256, 0, stream>>>(hid, Bbf, b1, nullptr, TT, CC, FFND);
  transpose_f2bf_kernel<<<dim3(CC/64, CC/64), B256, 0, stream>>>(Wcr, Bbf, CC, CC);
  gemm_bt_kernel<0><<<dim3(CC/128, TT/128), B256, 0, stream>>>(b4, Bbf, b2, nullptr, TT, CC, CC);
  final_kernel<<<NTC8, B256, 0, stream>>>(b1, b2, xmid);
}

// Round 3
// 1155.100 us; speedup vs baseline: 1.6774x; 1.6774x over previous
//
#include <hip/hip_runtime.h>
#include <stdint.h>

// RWKV6 block: B=1, T=2048, C=2048, H=32, HS=64, FFN=7168, NS=4
// Workspace: 6*16M (f32) + 7*8M (bf16) + 28M (Wt) + 4M aux = 184 MiB.

#define TT 2048
#define CC 2048
#define NH 32
#define HSZ 64
#define FFND 7168
#define CHUNK 64
#define NCHUNK 32

typedef __attribute__((ext_vector_type(8))) short short8;
typedef __attribute__((ext_vector_type(4))) float f32x4;

__device__ __forceinline__ float bf2f(short s){
  return __uint_as_float(((uint32_t)(uint16_t)s) << 16);
}
__device__ __forceinline__ short f2bf(float f){
  uint32_t u = __float_as_uint(f);
  u = u + 0x7fffu + ((u >> 16) & 1u);
  return (short)(u >> 16);
}

// ---------------- LayerNorm (row over C) ----------------
__global__ __launch_bounds__(256) void ln_kernel(
    const float* __restrict__ xin, const float* __restrict__ gam,
    const float* __restrict__ bet, float* __restrict__ out, float eps)
{
  int t = blockIdx.x, tid = threadIdx.x;
  const float* row = xin + (size_t)t*CC;
  float4 v0 = *(const float4*)(row + tid*8);
  float4 v1 = *(const float4*)(row + tid*8 + 4);
  float s  = v0.x+v0.y+v0.z+v0.w + v1.x+v1.y+v1.z+v1.w;
  float ss = v0.x*v0.x+v0.y*v0.y+v0.z*v0.z+v0.w*v0.w
           + v1.x*v1.x+v1.y*v1.y+v1.z*v1.z+v1.w*v1.w;
  #pragma unroll
  for(int off=1; off<64; off<<=1){ s += __shfl_xor(s,off); ss += __shfl_xor(ss,off); }
  __shared__ float sm[8];
  int w = tid>>6;
  if((tid&63)==0){ sm[w]=s; sm[4+w]=ss; }
  __syncthreads();
  s = sm[0]+sm[1]+sm[2]+sm[3]; ss = sm[4]+sm[5]+sm[6]+sm[7];
  float mean = s * (1.f/CC);
  float var  = ss * (1.f/CC) - mean*mean;
  float rstd = rsqrtf(var + eps);
  float* orow = out + (size_t)t*CC;
  int c = tid*8;
  float vv[8] = {v0.x,v0.y,v0.z,v0.w,v1.x,v1.y,v1.z,v1.w};
  #pragma unroll
  for(int j=0;j<8;j++) orow[c+j] = (vv[j]-mean)*rstd*gam[c+j] + bet[c+j];
}

// ---------------- token shift (attention): xx = sh - xa (f32 out) ----------------
__global__ __launch_bounds__(256) void shift1_kernel(
    const float* __restrict__ xa, const float* __restrict__ st,
    const int* __restrict__ sp, float* __restrict__ xxb)
{
  int t = blockIdx.x, tid = threadIdx.x;
  int sp0=sp[0], sp1=sp[1], sp2=sp[2], sp3=sp[3];
  bool is_start = (sp0==t)|(sp1==t)|(sp2==t)|(sp3==t);
  int sid = (sp0<=t)+(sp1<=t)+(sp2<=t)+(sp3<=t) - 1;
  sid = sid<0?0:(sid>3?3:sid);
  int c = tid*8;
  const float* src = is_start ? (st + (size_t)sid*CC + c)
                   : (t>0 ? xa + (size_t)(t-1)*CC + c : nullptr);
  const float* cur = xa + (size_t)t*CC + c;
  float* o = xxb + (size_t)t*CC + c;
  #pragma unroll
  for(int jj=0;jj<8;jj++){
    float sh = src ? src[jj] : 0.f;
    o[jj] = sh - cur[jj];
  }
}

// ---------------- token shift (ffn): xk2/xr2 fused, bf16 out ----------------
__global__ __launch_bounds__(256) void shift2_kernel(
    const float* __restrict__ xf, const float* __restrict__ st,
    const int* __restrict__ sp, const float* __restrict__ cmk,
    const float* __restrict__ cmr, short* __restrict__ xk2, short* __restrict__ xr2)
{
  int t = blockIdx.x, tid = threadIdx.x;
  int sp0=sp[0], sp1=sp[1], sp2=sp[2], sp3=sp[3];
  bool is_start = (sp0==t)|(sp1==t)|(sp2==t)|(sp3==t);
  int sid = (sp0<=t)+(sp1<=t)+(sp2<=t)+(sp3<=t) - 1;
  sid = sid<0?0:(sid>3?3:sid);
  int c = tid*8;
  const float* src = is_start ? (st + (size_t)sid*CC + c)
                   : (t>0 ? xf + (size_t)(t-1)*CC + c : nullptr);
  const float* cur = xf + (size_t)t*CC + c;
  size_t ix = (size_t)t*CC + c;
  #pragma unroll
  for(int jj=0;jj<8;jj++){
    float xfv = cur[jj];
    float sh = src ? src[jj] : 0.f;
    float d = sh - xfv;
    xk2[ix+jj] = f2bf(xfv + d*cmk[c+jj]);
    xr2[ix+jj] = f2bf(xfv + d*cmr[c+jj]);
  }
}

// ---------------- z = xa + xx*maa_x -> bf16 ----------------
__global__ __launch_bounds__(256) void zprep_kernel(const float* __restrict__ xa,
   const float* __restrict__ xx, const float* __restrict__ maa, short* __restrict__ z)
{
  size_t i = ((size_t)blockIdx.x*256 + threadIdx.x)*8;
  int c = (int)(i & (CC-1));
  #pragma unroll
  for(int j=0;j<8;j++) z[i+j] = f2bf(xa[i+j] + xx[i+j]*maa[c+j]);
}

// ---------------- one maa mix: x_s = xa + xx*(maa_s + xxx@w2_s) ----------------
template<int S, bool BF>
__global__ __launch_bounds__(256) void mix_kernel(
    const float* __restrict__ xxxb, const float* __restrict__ w2,
    const float* __restrict__ xa, const float* __restrict__ xxv,
    const float* __restrict__ maa, void* __restrict__ out)
{
  int g = blockIdx.x*256 + threadIdx.x;
  int c = g & (CC-1);
  int t0 = (g >> 11) * 8;
  float acc[8] = {0,0,0,0,0,0,0,0};
  for(int e=0;e<32;e++){
    float wv = w2[(size_t)(S*32+e)*CC + c];
    #pragma unroll
    for(int tt=0;tt<8;tt++)
      acc[tt] += xxxb[(size_t)(t0+tt)*160 + S*32 + e] * wv;
  }
  float mv = maa[c];
  #pragma unroll
  for(int tt=0;tt<8;tt++){
    size_t ix = (size_t)(t0+tt)*CC + c;
    float o = xa[ix] + xxv[ix]*(mv + acc[tt]);
    if constexpr (BF) ((short*)out)[ix] = f2bf(o);
    else              ((float*)out)[ix] = o;
  }
}

// ---------------- dec = exp(-exp(td + h1 @ td_w2)) (f32) ----------------
__global__ __launch_bounds__(256) void dec_kernel(
    const float* __restrict__ h1b, const float* __restrict__ tw2,
    const float* __restrict__ td, float* __restrict__ out)
{
  int g = blockIdx.x*256 + threadIdx.x;
  int c = g & (CC-1);
  int t0 = (g >> 11)*8;
  float acc[8] = {0,0,0,0,0,0,0,0};
  for(int e=0;e<64;e++){
    float wv = tw2[(size_t)e*CC + c];
    #pragma unroll
    for(int tt=0;tt<8;tt++) acc[tt] += h1b[(size_t)(t0+tt)*64 + e]*wv;
  }
  float tdc = td[c];
  #pragma unroll
  for(int tt=0;tt<8;tt++)
    out[(size_t)(t0+tt)*CC + c] = expf(-expf(tdc + acc[tt]));
}

// ---------------- W[K,N] f32 -> Wt[NPAD,K] bf16 (transpose+convert, zero-pad rows >= N) ----------------
__global__ __launch_bounds__(256) void transpose_f2bf_kernel(
    const float* __restrict__ W, short* __restrict__ Wt, int K, int N)
{
  __shared__ float tile[64][65];
  int n0 = blockIdx.x*64, k0 = blockIdx.y*64;
  int tid = threadIdx.x;
  #pragma unroll
  for(int q=0;q<16;q++){
    int ix = q*256 + tid;
    int r = ix >> 6, cc2 = ix & 63;
    tile[r][cc2] = (n0 + cc2 < N) ? W[(size_t)(k0+r)*N + n0 + cc2] : 0.f;
  }
  __syncthreads();
  #pragma unroll
  for(int q=0;q<16;q++){
    int ix = q*256 + tid;
    int r = ix >> 6, cc2 = ix & 63;
    Wt[(size_t)(n0+r)*K + k0 + cc2] = f2bf(tile[cc2][r]);
  }
}

// ---------------- bf16 MFMA GEMM (m97 structure): C[M,N] = A[M,K] @ Bt[N,K]^T ----------------
__device__ __forceinline__ void load_lds16(const void* g, void* l){
  __builtin_amdgcn_global_load_lds(
      (const __attribute__((address_space(1))) uint32_t*)g,
      (__attribute__((address_space(3))) uint32_t*)l, 16, 0, 0);
}

// EPI: 0 = bf16 store; 1 = silu bf16; 2 = f32 + residual; 3 = relu^2 bf16;
//      4 = tanh f32 store with col < nstore guard (skinny GEMM, stride nstore)
template<int EPI>
__global__ __launch_bounds__(256) void gemm_bt_kernel(
    const short* __restrict__ A, const short* __restrict__ Bt,
    void* __restrict__ Cout, const float* __restrict__ extra,
    int M, int N, int K, int nstore)
{
  __shared__ __align__(16) short As[128*32];
  __shared__ __align__(16) short Bs[128*32];
  int tid = threadIdx.x;
  int w = tid >> 6, lane = tid & 63;
  int l16 = lane & 15, lhi = lane >> 4;
  int wr = w >> 1, wc = w & 1;
  int bm = blockIdx.y, bn = blockIdx.x;
  const short* Ab = A + (size_t)bm*128*K;
  const short* Bb = Bt + (size_t)bn*128*K;
  f32x4 acc[4][4] = {};
  for(int kt=0; kt<K; kt+=32){
    __syncthreads();
    #pragma unroll
    for(int q=0;q<2;q++){
      int chunk = q*256 + tid;
      int row = chunk >> 2;
      int c8 = (chunk & 3)*8;
      int ldsoff = (q*256 + w*64)*8;   // wave-uniform LDS base (HW adds lane*16B)
      load_lds16(Ab + (size_t)row*K + kt + c8, As + ldsoff);
      load_lds16(Bb + (size_t)row*K + kt + c8, Bs + ldsoff);
    }
    __syncthreads();
    short8 af[4], bf[4];
    #pragma unroll
    for(int m=0;m<4;m++) af[m] = *(const short8*)(As + (wr*64 + m*16 + l16)*32 + lhi*8);
    #pragma unroll
    for(int n=0;n<4;n++) bf[n] = *(const short8*)(Bs + (wc*64 + n*16 + l16)*32 + lhi*8);
    #pragma unroll
    for(int m=0;m<4;m++){
      #pragma unroll
      for(int n=0;n<4;n++)
        acc[m][n] = __builtin_amdgcn_mfma_f32_16x16x32_bf16(af[m], bf[n], acc[m][n], 0, 0, 0);
    }
  }
  int m0 = bm*128 + wr*64;
  int n0 = bn*128 + wc*64;
  #pragma unroll
  for(int m=0;m<4;m++){
    #pragma unroll
    for(int n=0;n<4;n++){
      #pragma unroll
      for(int jj=0;jj<4;jj++){
        int row = m0 + m*16 + lhi*4 + jj;
        int col = n0 + n*16 + l16;
        size_t ix = (size_t)row*N + col;
        float val = acc[m][n][jj];
        if constexpr (EPI==0){ ((short*)Cout)[ix] = f2bf(val); }
        else if constexpr (EPI==1){ ((short*)Cout)[ix] = f2bf(val/(1.f+expf(-val))); }
        else if constexpr (EPI==2){ ((float*)Cout)[ix] = val + extra[ix]; }
        else if constexpr (EPI==3){ float rv = fmaxf(val, 0.f); ((short*)Cout)[ix] = f2bf(rv*rv); }
        else {
          if(col < nstore) ((float*)Cout)[(size_t)row*nstore + col] = tanhf(val);
        }
      }
    }
  }
}

// ---------------- WKV pass A: per-(chunk,head) local scan ----------------
// thread: a = tid&3 (i-subgroup of 16), j = tid>>2 (value column)
__global__ __launch_bounds__(256) void wkv_chunk_kernel(
    const short* __restrict__ rb, const short* __restrict__ kb,
    const short* __restrict__ vb, const float* __restrict__ db,
    const float* __restrict__ wkv_state, const float* __restrict__ u,
    const int* __restrict__ sp,
    float* __restrict__ yb, short* __restrict__ rtb,
    float* __restrict__ Bc, float* __restrict__ Pc)
{
  int blk = blockIdx.x;
  int ch = blk >> 5;       // chunk
  int h  = blk & 31;       // head
  int tid = threadIdx.x;
  int a = tid & 3, j = tid >> 2;
  __shared__ float sr[64], sk[64], sv[64], sd[64], su[64];
  if(tid < 64) su[tid] = u[h*64 + tid];
  float S[16], p[16];
  #pragma unroll
  for(int ii=0;ii<16;ii++){ S[ii]=0.f; p[ii]=1.f; }
  int sp0=sp[0], sp1=sp[1], sp2=sp[2], sp3=sp[3];
  for(int tl=0; tl<CHUNK; ++tl){
    int t = ch*CHUNK + tl;
    __syncthreads();
    size_t base = (size_t)t*CC + h*64;
    if(tid<64)        sr[tid]     = bf2f(rb[base + tid]);
    else if(tid<128)  sk[tid-64]  = bf2f(kb[base + (tid-64)]);
    else if(tid<192)  sv[tid-128] = bf2f(vb[base + (tid-128)]);
    else              sd[tid-192] = db[base + (tid-192)];
    __syncthreads();
    bool is_start = (sp0==t)|(sp1==t)|(sp2==t)|(sp3==t);
    if(is_start){
      int sid = (sp0<=t)+(sp1<=t)+(sp2<=t)+(sp3<=t) - 1;
      sid = sid<0?0:(sid>3?3:sid);
      const float* wsrc = wkv_state + (((size_t)sid*NH + h)*HSZ + a*16)*HSZ + j;
      #pragma unroll
      for(int ii=0;ii<16;ii++){ S[ii] = wsrc[(size_t)ii*HSZ]; p[ii] = 0.f; }
    }
    float vj = sv[j];
    float yp = 0.f, bp = 0.f;
    #pragma unroll
    for(int ii=0;ii<16;ii++){
      int i = a*16 + ii;
      float ri = sr[i];
      yp += ri * S[ii];
      bp += ri * su[i] * sk[i];
    }
    yp += __shfl_xor(yp, 1); yp += __shfl_xor(yp, 2);
    bp += __shfl_xor(bp, 1); bp += __shfl_xor(bp, 2);
    if(a == 0) yb[base + j] = yp + bp*vj;
    if(tid < 4){  // a==tid, j==0: owner of r~ and P for its 16 i's
      #pragma unroll
      for(int ii=0;ii<16;ii++) rtb[base + tid*16 + ii] = f2bf(sr[tid*16+ii] * p[ii]);
    }
    #pragma unroll
    for(int ii=0;ii<16;ii++){
      int i = a*16 + ii;
      S[ii] = sd[i]*S[ii] + sk[i]*vj;
    }
    if(tid < 4){
      #pragma unroll
      for(int ii=0;ii<16;ii++) p[ii] *= sd[tid*16+ii];
    }
  }
  size_t cb = ((size_t)ch*NH + h)*HSZ*HSZ;
  #pragma unroll
  for(int ii=0;ii<16;ii++) Bc[cb + (size_t)(a*16+ii)*HSZ + j] = S[ii];
  if(tid < 4){
    size_t pb = ((size_t)ch*NH + h)*HSZ;
    #pragma unroll
    for(int ii=0;ii<16;ii++) Pc[pb + tid*16 + ii] = p[ii];
  }
}

// ---------------- WKV pass B: sequential combine over chunks (in-place Bc->Sin) ----------------
__global__ __launch_bounds__(256) void wkv_combine_kernel(
    float* __restrict__ BS, const float* __restrict__ Pc)
{
  int idx = blockIdx.x*256 + threadIdx.x;   // h*4096 + i*64 + j
  int hi = idx >> 6;
  float s = 0.f;
  for(int cc=0; cc<NCHUNK; ++cc){
    size_t ix = (size_t)cc*(NH*HSZ*HSZ) + idx;
    float b = BS[ix];
    BS[ix] = s;                              // S_in for this chunk
    s = Pc[cc*(NH*HSZ) + hi]*s + b;
  }
}

// ---------------- WKV pass C: y += r~ @ S_in ----------------
__global__ __launch_bounds__(256) void wkv_corr_kernel(
    const short* __restrict__ rtb, const float* __restrict__ Sin, float* __restrict__ yb)
{
  int blk = blockIdx.x;
  int ch = blk >> 5, h = blk & 31;
  __shared__ float Ssm[64][64];
  __shared__ float Rsm[64][65];
  int tid = threadIdx.x;
  const float* Sp = Sin + (size_t)(ch*NH + h)*HSZ*HSZ;
  #pragma unroll
  for(int q=0;q<16;q++){
    int ix = q*256 + tid;
    ((float*)Ssm)[ix] = Sp[ix];
  }
  #pragma unroll
  for(int q=0;q<16;q++){
    int ix = q*256 + tid;
    int tl = ix>>6, i = ix&63;
    Rsm[tl][i] = bf2f(rtb[(size_t)(ch*64+tl)*CC + h*64 + i]);
  }
  __syncthreads();
  int tl = tid >> 2;
  int jq = tid & 3;
  float acc[16];
  #pragma unroll
  for(int jj=0;jj<16;jj++) acc[jj]=0.f;
  for(int i=0;i<64;i++){
    float rv = Rsm[tl][i];
    #pragma unroll
    for(int jj=0;jj<16;jj++) acc[jj] += rv * Ssm[i][jq*16+jj];
  }
  #pragma unroll
  for(int jj=0;jj<16;jj++){
    int j = jq*16 + jj;
    yb[(size_t)(ch*64+tl)*CC + h*64 + j] += acc[jj];
  }
}

// ---------------- GroupNorm(H groups) * g -> bf16 ----------------
__global__ __launch_bounds__(256) void gn_mul_kernel(
    const float* __restrict__ yb, const short* __restrict__ gb,
    const float* __restrict__ gam, const float* __restrict__ bet,
    short* __restrict__ yg)
{
  int t = blockIdx.x, tid = threadIdx.x;
  int w = tid >> 6, lane = tid & 63;
  for(int q=0;q<8;q++){
    int h = q*4 + w;
    int cc = h*64 + lane;
    float val = yb[(size_t)t*CC + cc];
    float s = val, ss = val*val;
    #pragma unroll
    for(int off=1;off<64;off<<=1){ s += __shfl_xor(s,off); ss += __shfl_xor(ss,off); }
    float mu = s*(1.f/64.f);
    float var = ss*(1.f/64.f) - mu*mu;
    float rstd = rsqrtf(var + 6.4e-4f);   // eps = 1e-5 * 8^2
    float o = (val-mu)*rstd*gam[cc] + bet[cc];
    yg[(size_t)t*CC + cc] = f2bf(o * bf2f(gb[(size_t)t*CC + cc]));
  }
}

// ---------------- final: out += sigmoid(s)*kv ----------------
__global__ __launch_bounds__(256) void final_kernel(const short* __restrict__ kv,
    const short* __restrict__ sb, float* __restrict__ out)
{
  size_t i = ((size_t)blockIdx.x*256 + threadIdx.x)*8;
  #pragma unroll
  for(int j=0;j<8;j++){
    float svv = bf2f(sb[i+j]);
    float sig = 1.f/(1.f + expf(-svv));
    out[i+j] = out[i+j] + sig*bf2f(kv[i+j]);
  }
}

extern "C" void kernel_launch(void* const* d_in, const int* in_sizes, int n_in,
                              void* d_out, int out_size, void* d_ws, size_t ws_size,
                              hipStream_t stream)
{
  (void)in_sizes; (void)n_in; (void)out_size;
  const float* x         = (const float*)d_in[0];
  const int*   sp        = (const int*)d_in[1];
  const float* att_state = (const float*)d_in[2];
  const float* wkv_state = (const float*)d_in[3];
  const float* ffn_state = (const float*)d_in[4];
  const float* ln1_g=(const float*)d_in[5],  *ln1_b=(const float*)d_in[6];
  const float* ln2_g=(const float*)d_in[7],  *ln2_b=(const float*)d_in[8];
  const float* maa_x=(const float*)d_in[9],  *maa_w=(const float*)d_in[10], *maa_k=(const float*)d_in[11];
  const float* maa_v=(const float*)d_in[12], *maa_r=(const float*)d_in[13], *maa_g=(const float*)d_in[14];
  const float* tm_w1=(const float*)d_in[15], *tm_w2=(const float*)d_in[16];
  const float* td=(const float*)d_in[17],    *td_w1=(const float*)d_in[18], *td_w2=(const float*)d_in[19];
  const float* u = (const float*)d_in[20];
  const float* Wr=(const float*)d_in[21], *Wk=(const float*)d_in[22], *Wv=(const float*)d_in[23];
  const float* Wg=(const float*)d_in[24], *Wo=(const float*)d_in[25];
  const float* lnx_g=(const float*)d_in[26], *lnx_b=(const float*)d_in[27];
  const float* cm_k=(const float*)d_in[28],  *cm_r=(const float*)d_in[29];
  const float* Wck=(const float*)d_in[30], *Wcv=(const float*)d_in[31], *Wcr=(const float*)d_in[32];

  char* ws = (char*)d_ws;
  const size_t SLOT  = (size_t)TT*CC*4;      // 16 MiB (f32 [T,C])
  const size_t BSLOT = (size_t)TT*CC*2;      // 8 MiB  (bf16 [T,C])
  const size_t WT_SZ = (size_t)FFND*CC*2;    // 28 MiB (largest W^T bf16)
  const size_t NEED  = 6*SLOT + 7*BSLOT + WT_SZ + (4u<<20);
  if(ws_size < NEED) return;   // diagnostic: leaves d_out poisoned instead of faulting

  float* xa   = (float*)(ws + 0*SLOT);   // S0 (FFN: hid low half)
  float* xxb  = (float*)(ws + 1*SLOT);   // S1 (FFN: hid high half)
  float* zw   = (float*)(ws + 2*SLOT);   // S2: xf (FFN phase)
  float* decb = (float*)(ws + 3*SLOT);   // S3
  float* yb   = (float*)(ws + 4*SLOT);   // S4
  float* BS   = (float*)(ws + 5*SLOT);   // S5: Bc -> Sin (in place)
  char*  bfb  = ws + 6*SLOT;
  short* b0 = (short*)(bfb + 0*BSLOT);   // z / xw / mix staging (serially)
  short* b1 = (short*)(bfb + 1*BSLOT);   // rb   (FFN: kvb)
  short* b2 = (short*)(bfb + 2*BSLOT);   // kb   (FFN: sbuf)
  short* b3 = (short*)(bfb + 3*BSLOT);   // vb   (FFN: xk2)
  short* b4 = (short*)(bfb + 4*BSLOT);   // gb   (FFN: xr2)
  short* b5 = (short*)(bfb + 5*BSLOT);   // rtb
  short* b6 = (short*)(bfb + 6*BSLOT);   // yg
  short* Bbf = (short*)(bfb + 7*BSLOT);  // transposed weight, 28 MiB
  char*  aux = (char*)Bbf + WT_SZ;
  float* xxxb = (float*)(aux);                 // 1.25 MiB
  float* h1b  = (float*)(aux + (2u<<20));      // 0.5 MiB
  float* Pc   = (float*)(aux + (3u<<20));      // 0.25 MiB
  short* hid  = (short*)(ws + 0*SLOT);         // 28 MiB over S0..S1 (FFN phase)
  float* xmid = (float*)d_out;

  dim3 B256(256);
  const int NTC8 = TT*CC/8/256;   // 2048 blocks for flat [T,C] elementwise

  // ---- Tmix front ----
  ln_kernel<<<TT, B256, 0, stream>>>(x, ln1_g, ln1_b, xa, 1e-5f);
  shift1_kernel<<<TT, B256, 0, stream>>>(xa, att_state, sp, xxb);
  // xxx = tanh(z @ tm_w1): MFMA skinny GEMM, N padded 160->256
  zprep_kernel<<<NTC8, B256, 0, stream>>>(xa, xxb, maa_x, b0);
  transpose_f2bf_kernel<<<dim3(256/64, CC/64), B256, 0, stream>>>(tm_w1, Bbf, CC, 160);
  gemm_bt_kernel<4><<<dim3(256/128, TT/128), B256, 0, stream>>>(b0, Bbf, xxxb, nullptr, TT, 256, CC, 160);
  // h1 = tanh(xw @ td_w1): MFMA skinny GEMM, N padded 64->128
  mix_kernel<0,true><<<NTC8, B256, 0, stream>>>(xxxb, tm_w2, xa, xxb, maa_w, b0);
  transpose_f2bf_kernel<<<dim3(128/64, CC/64), B256, 0, stream>>>(td_w1, Bbf, CC, 64);
  gemm_bt_kernel<4><<<dim3(1, TT/128), B256, 0, stream>>>(b0, Bbf, h1b, nullptr, TT, 128, CC, 64);
  dec_kernel<<<NTC8, B256, 0, stream>>>(h1b, td_w2, td, decb);

  // ---- r,k,v,g projections (bf16 MFMA), staged through b0 ----
  mix_kernel<3,true><<<NTC8, B256, 0, stream>>>(xxxb, tm_w2, xa, xxb, maa_r, b0);
  transpose_f2bf_kernel<<<dim3(CC/64, CC/64), B256, 0, stream>>>(Wr, Bbf, CC, CC);
  gemm_bt_kernel<0><<<dim3(CC/128, TT/128), B256, 0, stream>>>(b0, Bbf, b1, nullptr, TT, CC, CC, 0);
  mix_kernel<1,true><<<NTC8, B256, 0, stream>>>(xxxb, tm_w2, xa, xxb, maa_k, b0);
  transpose_f2bf_kernel<<<dim3(CC/64, CC/64), B256, 0, stream>>>(Wk, Bbf, CC, CC);
  gemm_bt_kernel<0><<<dim3(CC/128, TT/128), B256, 0, stream>>>(b0, Bbf, b2, nullptr, TT, CC, CC, 0);
  mix_kernel<2,true><<<NTC8, B256, 0, stream>>>(xxxb, tm_w2, xa, xxb, maa_v, b0);
  transpose_f2bf_kernel<<<dim3(CC/64, CC/64), B256, 0, stream>>>(Wv, Bbf, CC, CC);
  gemm_bt_kernel<0><<<dim3(CC/128, TT/128), B256, 0, stream>>>(b0, Bbf, b3, nullptr, TT, CC, CC, 0);
  mix_kernel<4,true><<<NTC8, B256, 0, stream>>>(xxxb, tm_w2, xa, xxb, maa_g, b0);
  transpose_f2bf_kernel<<<dim3(CC/64, CC/64), B256, 0, stream>>>(Wg, Bbf, CC, CC);
  gemm_bt_kernel<1><<<dim3(CC/128, TT/128), B256, 0, stream>>>(b0, Bbf, b4, nullptr, TT, CC, CC, 0);

  // ---- WKV chunked scan ----
  wkv_chunk_kernel<<<NCHUNK*NH, B256, 0, stream>>>(b1, b2, b3, decb, wkv_state, u, sp,
                                                   yb, b5, BS, Pc);
  wkv_combine_kernel<<<NH*HSZ*HSZ/256, B256, 0, stream>>>(BS, Pc);
  wkv_corr_kernel<<<NCHUNK*NH, B256, 0, stream>>>(b5, BS, yb);
  gn_mul_kernel<<<TT, B256, 0, stream>>>(yb, b4, lnx_g, lnx_b, b6);

  // ---- output projection + residual ----
  transpose_f2bf_kernel<<<dim3(CC/64, CC/64), B256, 0, stream>>>(Wo, Bbf, CC, CC);
  gemm_bt_kernel<2><<<dim3(CC/128, TT/128), B256, 0, stream>>>(b6, Bbf, xmid, x, TT, CC, CC, 0);

  // ---- CMix ----
  ln_kernel<<<TT, B256, 0, stream>>>(xmid, ln2_g, ln2_b, zw, 1e-5f);
  shift2_kernel<<<TT, B256, 0, stream>>>(zw, ffn_state, sp, cm_k, cm_r, b3, b4);
  transpose_f2bf_kernel<<<dim3(FFND/64, CC/64), B256, 0, stream>>>(Wck, Bbf, CC, FFND);
  gemm_bt_kernel<3><<<dim3(FFND/128, TT/128), B256, 0, stream>>>(b3, Bbf, hid, nullptr, TT, FFND, CC, 0);
  transpose_f2bf_kernel<<<dim3(CC/64, FFND/64), B256, 0, stream>>>(Wcv, Bbf, FFND, CC);
  gemm_bt_kernel<0><<<dim3(CC/128, TT/128), B256, 0, stream>>>(hid, Bbf, b1, nullptr, TT, CC, FFND, 0);
  transpose_f2bf_kernel<<<dim3(CC/64, CC/64), B256, 0, stream>>>(Wcr, Bbf, CC, CC);
  gemm_bt_kernel<0><<<dim3(CC/128, TT/128), B256, 0, stream>>>(b4, Bbf, b2, nullptr, TT, CC, CC, 0);
  final_kernel<<<NTC8, B256, 0, stream>>>(b1, b2, xmid);
}

// Round 4
// 925.431 us; speedup vs baseline: 2.0937x; 1.2482x over previous
//
#include <hip/hip_runtime.h>
#include <stdint.h>

// RWKV6 block: B=1, T=2048, C=2048, H=32, HS=64, FFN=7168, NS=4
// Workspace: 6*16M (f32) + 4*8M (bA) + 6*8M (bO) + 32M (WT) + 4M aux = 212 MiB.

#define TT 2048
#define CC 2048
#define NH 32
#define HSZ 64
#define FFND 7168
#define CHUNK 64
#define NCHUNK 32

typedef __attribute__((ext_vector_type(8))) short short8;
typedef __attribute__((ext_vector_type(4))) float f32x4;

__device__ __forceinline__ float bf2f(short s){
  return __uint_as_float(((uint32_t)(uint16_t)s) << 16);
}
__device__ __forceinline__ short f2bf(float f){
  uint32_t u = __float_as_uint(f);
  u = u + 0x7fffu + ((u >> 16) & 1u);
  return (short)(u >> 16);
}

// ---------------- LayerNorm (row over C) ----------------
__global__ __launch_bounds__(256) void ln_kernel(
    const float* __restrict__ xin, const float* __restrict__ gam,
    const float* __restrict__ bet, float* __restrict__ out, float eps)
{
  int t = blockIdx.x, tid = threadIdx.x;
  const float* row = xin + (size_t)t*CC;
  float4 v0 = *(const float4*)(row + tid*8);
  float4 v1 = *(const float4*)(row + tid*8 + 4);
  float s  = v0.x+v0.y+v0.z+v0.w + v1.x+v1.y+v1.z+v1.w;
  float ss = v0.x*v0.x+v0.y*v0.y+v0.z*v0.z+v0.w*v0.w
           + v1.x*v1.x+v1.y*v1.y+v1.z*v1.z+v1.w*v1.w;
  #pragma unroll
  for(int off=1; off<64; off<<=1){ s += __shfl_xor(s,off); ss += __shfl_xor(ss,off); }
  __shared__ float sm[8];
  int w = tid>>6;
  if((tid&63)==0){ sm[w]=s; sm[4+w]=ss; }
  __syncthreads();
  s = sm[0]+sm[1]+sm[2]+sm[3]; ss = sm[4]+sm[5]+sm[6]+sm[7];
  float mean = s * (1.f/CC);
  float var  = ss * (1.f/CC) - mean*mean;
  float rstd = rsqrtf(var + eps);
  float* orow = out + (size_t)t*CC;
  int c = tid*8;
  float vv[8] = {v0.x,v0.y,v0.z,v0.w,v1.x,v1.y,v1.z,v1.w};
  #pragma unroll
  for(int j=0;j<8;j++) orow[c+j] = (vv[j]-mean)*rstd*gam[c+j] + bet[c+j];
}

// ---------------- fused: xmid = p0+p1+x ; zw = LN(xmid) ----------------
__global__ __launch_bounds__(256) void ln2_fused_kernel(
    const float* __restrict__ p0, const float* __restrict__ p1,
    const float* __restrict__ xres, const float* __restrict__ gam,
    const float* __restrict__ bet, float* __restrict__ xsum,
    float* __restrict__ lnout, float eps)
{
  int t = blockIdx.x, tid = threadIdx.x;
  size_t base = (size_t)t*CC + tid*8;
  float vv[8];
  float s = 0.f, ss = 0.f;
  #pragma unroll
  for(int j=0;j<8;j++){
    float v = p0[base+j] + p1[base+j] + xres[base+j];
    vv[j] = v; s += v; ss += v*v;
    xsum[base+j] = v;
  }
  #pragma unroll
  for(int off=1; off<64; off<<=1){ s += __shfl_xor(s,off); ss += __shfl_xor(ss,off); }
  __shared__ float sm[8];
  int w = tid>>6;
  if((tid&63)==0){ sm[w]=s; sm[4+w]=ss; }
  __syncthreads();
  s = sm[0]+sm[1]+sm[2]+sm[3]; ss = sm[4]+sm[5]+sm[6]+sm[7];
  float mean = s * (1.f/CC);
  float var  = ss * (1.f/CC) - mean*mean;
  float rstd = rsqrtf(var + eps);
  int c = tid*8;
  #pragma unroll
  for(int j=0;j<8;j++) lnout[base+j] = (vv[j]-mean)*rstd*gam[c+j] + bet[c+j];
}

// ---------------- token shift (attention): xx = sh - xa (f32 out) ----------------
__global__ __launch_bounds__(256) void shift1_kernel(
    const float* __restrict__ xa, const float* __restrict__ st,
    const int* __restrict__ sp, float* __restrict__ xxb)
{
  int t = blockIdx.x, tid = threadIdx.x;
  int sp0=sp[0], sp1=sp[1], sp2=sp[2], sp3=sp[3];
  bool is_start = (sp0==t)|(sp1==t)|(sp2==t)|(sp3==t);
  int sid = (sp0<=t)+(sp1<=t)+(sp2<=t)+(sp3<=t) - 1;
  sid = sid<0?0:(sid>3?3:sid);
  int c = tid*8;
  const float* src = is_start ? (st + (size_t)sid*CC + c)
                   : (t>0 ? xa + (size_t)(t-1)*CC + c : nullptr);
  const float* cur = xa + (size_t)t*CC + c;
  float* o = xxb + (size_t)t*CC + c;
  #pragma unroll
  for(int jj=0;jj<8;jj++){
    float sh = src ? src[jj] : 0.f;
    o[jj] = sh - cur[jj];
  }
}

// ---------------- token shift (ffn): xk2/xr2 fused, bf16 out ----------------
__global__ __launch_bounds__(256) void shift2_kernel(
    const float* __restrict__ xf, const float* __restrict__ st,
    const int* __restrict__ sp, const float* __restrict__ cmk,
    const float* __restrict__ cmr, short* __restrict__ xk2, short* __restrict__ xr2)
{
  int t = blockIdx.x, tid = threadIdx.x;
  int sp0=sp[0], sp1=sp[1], sp2=sp[2], sp3=sp[3];
  bool is_start = (sp0==t)|(sp1==t)|(sp2==t)|(sp3==t);
  int sid = (sp0<=t)+(sp1<=t)+(sp2<=t)+(sp3<=t) - 1;
  sid = sid<0?0:(sid>3?3:sid);
  int c = tid*8;
  const float* src = is_start ? (st + (size_t)sid*CC + c)
                   : (t>0 ? xf + (size_t)(t-1)*CC + c : nullptr);
  const float* cur = xf + (size_t)t*CC + c;
  size_t ix = (size_t)t*CC + c;
  #pragma unroll
  for(int jj=0;jj<8;jj++){
    float xfv = cur[jj];
    float sh = src ? src[jj] : 0.f;
    float d = sh - xfv;
    xk2[ix+jj] = f2bf(xfv + d*cmk[c+jj]);
    xr2[ix+jj] = f2bf(xfv + d*cmr[c+jj]);
  }
}

// ---------------- z = xa + xx*maa_x -> bf16 ----------------
__global__ __launch_bounds__(256) void zprep_kernel(const float* __restrict__ xa,
   const float* __restrict__ xx, const float* __restrict__ maa, short* __restrict__ z)
{
  size_t i = ((size_t)blockIdx.x*256 + threadIdx.x)*8;
  int c = (int)(i & (CC-1));
  #pragma unroll
  for(int j=0;j<8;j++) z[i+j] = f2bf(xa[i+j] + xx[i+j]*maa[c+j]);
}

// ---------------- fused 5-way maa mix -> bf16 outputs ----------------
// w2 s-order: 0=w 1=k 2=v 3=r 4=g
__global__ __launch_bounds__(256) void mix5_kernel(
    const float* __restrict__ xxxb, const float* __restrict__ w2,
    const float* __restrict__ xa, const float* __restrict__ xxv,
    const float* __restrict__ mw, const float* __restrict__ mk,
    const float* __restrict__ mv, const float* __restrict__ mr,
    const float* __restrict__ mg,
    short* __restrict__ ow, short* __restrict__ ok, short* __restrict__ ov,
    short* __restrict__ orr, short* __restrict__ og)
{
  int g = blockIdx.x*256 + threadIdx.x;
  int c = g & (CC-1);
  int t0 = (g >> 11) * 8;
  float acc[5][8];
  #pragma unroll
  for(int s=0;s<5;s++)
    #pragma unroll
    for(int tt=0;tt<8;tt++) acc[s][tt]=0.f;
  #pragma unroll
  for(int s=0;s<5;s++){
    for(int e=0;e<32;e++){
      float wv = w2[(size_t)(s*32+e)*CC + c];
      #pragma unroll
      for(int tt=0;tt<8;tt++)
        acc[s][tt] += xxxb[(size_t)(t0+tt)*160 + s*32 + e] * wv;
    }
  }
  float vmw=mw[c], vmk=mk[c], vmv=mv[c], vmr=mr[c], vmg=mg[c];
  #pragma unroll
  for(int tt=0;tt<8;tt++){
    size_t ix = (size_t)(t0+tt)*CC + c;
    float av = xa[ix], xv = xxv[ix];
    ow[ix]  = f2bf(av + xv*(vmw + acc[0][tt]));
    ok[ix]  = f2bf(av + xv*(vmk + acc[1][tt]));
    ov[ix]  = f2bf(av + xv*(vmv + acc[2][tt]));
    orr[ix] = f2bf(av + xv*(vmr + acc[3][tt]));
    og[ix]  = f2bf(av + xv*(vmg + acc[4][tt]));
  }
}

// ---------------- dec = exp(-exp(td + h1 @ td_w2)) (f32) ----------------
__global__ __launch_bounds__(256) void dec_kernel(
    const float* __restrict__ h1b, const float* __restrict__ tw2,
    const float* __restrict__ td, float* __restrict__ out)
{
  int g = blockIdx.x*256 + threadIdx.x;
  int c = g & (CC-1);
  int t0 = (g >> 11)*8;
  float acc[8] = {0,0,0,0,0,0,0,0};
  for(int e=0;e<64;e++){
    float wv = tw2[(size_t)e*CC + c];
    #pragma unroll
    for(int tt=0;tt<8;tt++) acc[tt] += h1b[(size_t)(t0+tt)*64 + e]*wv;
  }
  float tdc = td[c];
  #pragma unroll
  for(int tt=0;tt<8;tt++)
    out[(size_t)(t0+tt)*CC + c] = expf(-expf(tdc + acc[tt]));
}

// ---------------- W[K,N] f32 -> Wt[NPAD,K] bf16 (transpose, zero-pad n >= N) ----------------
__global__ __launch_bounds__(256) void transpose_f2bf_kernel(
    const float* __restrict__ W, short* __restrict__ Wt, int K, int N)
{
  __shared__ float tile[64][65];
  int n0 = blockIdx.x*64, k0 = blockIdx.y*64;
  int tid = threadIdx.x;
  #pragma unroll
  for(int q=0;q<16;q++){
    int ix = q*256 + tid;
    int r = ix >> 6, cc2 = ix & 63;
    tile[r][cc2] = (n0 + cc2 < N) ? W[(size_t)(k0+r)*N + n0 + cc2] : 0.f;
  }
  __syncthreads();
  #pragma unroll
  for(int q=0;q<16;q++){
    int ix = q*256 + tid;
    int r = ix >> 6, cc2 = ix & 63;
    Wt[(size_t)(n0+r)*K + k0 + cc2] = f2bf(tile[cc2][r]);
  }
}

// batched variant: 4 square CCxCC weights -> WT + z*CC*CC
struct WPtr4 { const float* w[4]; };
__global__ __launch_bounds__(256) void transpose4_f2bf_kernel(
    WPtr4 ws4, short* __restrict__ Wt)
{
  __shared__ float tile[64][65];
  int z = blockIdx.z;
  const float* W = ws4.w[z];
  short* dst = Wt + (size_t)z*CC*CC;
  int n0 = blockIdx.x*64, k0 = blockIdx.y*64;
  int tid = threadIdx.x;
  #pragma unroll
  for(int q=0;q<16;q++){
    int ix = q*256 + tid;
    int r = ix >> 6, cc2 = ix & 63;
    tile[r][cc2] = W[(size_t)(k0+r)*CC + n0 + cc2];
  }
  __syncthreads();
  #pragma unroll
  for(int q=0;q<16;q++){
    int ix = q*256 + tid;
    int r = ix >> 6, cc2 = ix & 63;
    dst[(size_t)(n0+r)*CC + k0 + cc2] = f2bf(tile[cc2][r]);
  }
}

// ---------------- bf16 MFMA GEMM, BK=64, XOR-swizzled LDS, XCD swizzle ----------------
// LDS[row][slot16B] holds global[row][slot ^ (row&7)] (both-sides swizzle, rule 21).
__device__ __forceinline__ void load_lds16(const void* g, void* l){
  __builtin_amdgcn_global_load_lds(
      (const __attribute__((address_space(1))) uint32_t*)g,
      (__attribute__((address_space(3))) uint32_t*)l, 16, 0, 0);
}

// EPI: 0 = bf16 store; 3 = relu^2 bf16; 4 = tanh f32 guarded (stride nstore);
//      5 = f32 partial (split-K, slab z*zC); 6 = batch rkvg (z==3 -> silu bf16)
template<int EPI>
__global__ __launch_bounds__(256) void gemm_bt_kernel(
    const short* __restrict__ A, const short* __restrict__ Bt,
    void* __restrict__ Cout, int M, int N, int Kstride, int Klen,
    long zA, long zB, long zC, int nstore)
{
  __shared__ __align__(16) short As[128*64];
  __shared__ __align__(16) short Bs[128*64];
  int z = blockIdx.z;
  const short* A0 = A + (size_t)z*zA;
  const short* B0 = Bt + (size_t)z*zB;
  int tid = threadIdx.x;
  int w = tid >> 6, lane = tid & 63;
  int l16 = lane & 15, lhi = lane >> 4;
  int wr = w >> 1, wc = w & 1;
  // XCD-chunked block swizzle (requires gx*gy % 8 == 0)
  int gx = gridDim.x;
  int nwg = gx*gridDim.y;
  int lin = blockIdx.y*gx + blockIdx.x;
  int wg = (lin & 7)*(nwg >> 3) + (lin >> 3);
  int bn = wg % gx, bm = wg / gx;
  const short* Ab = A0 + (size_t)bm*128*Kstride;
  const short* Bb = B0 + (size_t)bn*128*Kstride;
  int srow = w*8 + (lane>>3);      // staging row within 32-row group
  int scol = lane & 7;             // staging slot
  f32x4 acc[4][4] = {};
  for(int kt=0; kt<Klen; kt+=64){
    __syncthreads();
    #pragma unroll
    for(int q=0;q<4;q++){
      int row = q*32 + srow;
      int c8 = scol ^ (row & 7);   // pre-swizzled global source
      int ldsoff = (q*256 + w*64)*8;   // shorts; wave-uniform (HW adds lane*16B)
      load_lds16(Ab + (size_t)row*Kstride + kt + c8*8, As + ldsoff);
      load_lds16(Bb + (size_t)row*Kstride + kt + c8*8, Bs + ldsoff);
    }
    __syncthreads();
    #pragma unroll
    for(int kk=0;kk<2;kk++){
      short8 af[4], bf[4];
      #pragma unroll
      for(int m=0;m<4;m++){
        int row = wr*64 + m*16 + l16;
        int slot = (kk*4 + lhi) ^ (row & 7);
        af[m] = *(const short8*)(As + row*64 + slot*8);
      }
      #pragma unroll
      for(int n=0;n<4;n++){
        int row = wc*64 + n*16 + l16;
        int slot = (kk*4 + lhi) ^ (row & 7);
        bf[n] = *(const short8*)(Bs + row*64 + slot*8);
      }
      #pragma unroll
      for(int m=0;m<4;m++){
        #pragma unroll
        for(int n=0;n<4;n++)
          acc[m][n] = __builtin_amdgcn_mfma_f32_16x16x32_bf16(af[m], bf[n], acc[m][n], 0, 0, 0);
      }
    }
  }
  int m0 = bm*128 + wr*64;
  int n0 = bn*128 + wc*64;
  #pragma unroll
  for(int m=0;m<4;m++){
    #pragma unroll
    for(int n=0;n<4;n++){
      #pragma unroll
      for(int jj=0;jj<4;jj++){
        int row = m0 + m*16 + lhi*4 + jj;
        int col = n0 + n*16 + l16;
        size_t ix = (size_t)row*N + col;
        float val = acc[m][n][jj];
        if constexpr (EPI==0){ ((short*)Cout)[(size_t)z*zC + ix] = f2bf(val); }
        else if constexpr (EPI==3){ float rv = fmaxf(val, 0.f); ((short*)Cout)[ix] = f2bf(rv*rv); }
        else if constexpr (EPI==4){
          if(col < nstore) ((float*)Cout)[(size_t)row*nstore + col] = tanhf(val);
        }
        else if constexpr (EPI==5){ ((float*)Cout)[(size_t)z*zC + ix] = val; }
        else { // 6: rkvg batch
          short* o = (short*)Cout + (size_t)z*zC;
          o[ix] = (z==3) ? f2bf(val/(1.f+expf(-val))) : f2bf(val);
        }
      }
    }
  }
}

// ---------------- WKV pass A: per-(chunk,head) local scan ----------------
__global__ __launch_bounds__(256) void wkv_chunk_kernel(
    const short* __restrict__ rb, const short* __restrict__ kb,
    const short* __restrict__ vb, const float* __restrict__ db,
    const float* __restrict__ wkv_state, const float* __restrict__ u,
    const int* __restrict__ sp,
    float* __restrict__ yb, short* __restrict__ rtb,
    float* __restrict__ Bc, float* __restrict__ Pc)
{
  int blk = blockIdx.x;
  int ch = blk >> 5;       // chunk
  int h  = blk & 31;       // head
  int tid = threadIdx.x;
  int a = tid & 3, j = tid >> 2;
  __shared__ float sr[64], sk[64], sv[64], sd[64], su[64];
  if(tid < 64) su[tid] = u[h*64 + tid];
  float S[16], p[16];
  #pragma unroll
  for(int ii=0;ii<16;ii++){ S[ii]=0.f; p[ii]=1.f; }
  int sp0=sp[0], sp1=sp[1], sp2=sp[2], sp3=sp[3];
  for(int tl=0; tl<CHUNK; ++tl){
    int t = ch*CHUNK + tl;
    __syncthreads();
    size_t base = (size_t)t*CC + h*64;
    if(tid<64)        sr[tid]     = bf2f(rb[base + tid]);
    else if(tid<128)  sk[tid-64]  = bf2f(kb[base + (tid-64)]);
    else if(tid<192)  sv[tid-128] = bf2f(vb[base + (tid-128)]);
    else              sd[tid-192] = db[base + (tid-192)];
    __syncthreads();
    bool is_start = (sp0==t)|(sp1==t)|(sp2==t)|(sp3==t);
    if(is_start){
      int sid = (sp0<=t)+(sp1<=t)+(sp2<=t)+(sp3<=t) - 1;
      sid = sid<0?0:(sid>3?3:sid);
      const float* wsrc = wkv_state + (((size_t)sid*NH + h)*HSZ + a*16)*HSZ + j;
      #pragma unroll
      for(int ii=0;ii<16;ii++){ S[ii] = wsrc[(size_t)ii*HSZ]; p[ii] = 0.f; }
    }
    float vj = sv[j];
    float yp = 0.f, bp = 0.f;
    #pragma unroll
    for(int ii=0;ii<16;ii++){
      int i = a*16 + ii;
      float ri = sr[i];
      yp += ri * S[ii];
      bp += ri * su[i] * sk[i];
    }
    yp += __shfl_xor(yp, 1); yp += __shfl_xor(yp, 2);
    bp += __shfl_xor(bp, 1); bp += __shfl_xor(bp, 2);
    if(a == 0) yb[base + j] = yp + bp*vj;
    if(tid < 4){
      #pragma unroll
      for(int ii=0;ii<16;ii++) rtb[base + tid*16 + ii] = f2bf(sr[tid*16+ii] * p[ii]);
    }
    #pragma unroll
    for(int ii=0;ii<16;ii++){
      int i = a*16 + ii;
      S[ii] = sd[i]*S[ii] + sk[i]*vj;
    }
    if(tid < 4){
      #pragma unroll
      for(int ii=0;ii<16;ii++) p[ii] *= sd[tid*16+ii];
    }
  }
  size_t cb = ((size_t)ch*NH + h)*HSZ*HSZ;
  #pragma unroll
  for(int ii=0;ii<16;ii++) Bc[cb + (size_t)(a*16+ii)*HSZ + j] = S[ii];
  if(tid < 4){
    size_t pb = ((size_t)ch*NH + h)*HSZ;
    #pragma unroll
    for(int ii=0;ii<16;ii++) Pc[pb + tid*16 + ii] = p[ii];
  }
}

// ---------------- WKV pass B: sequential combine (in-place Bc->Sin) ----------------
__global__ __launch_bounds__(256) void wkv_combine_kernel(
    float* __restrict__ BS, const float* __restrict__ Pc)
{
  int idx = blockIdx.x*256 + threadIdx.x;
  int hi = idx >> 6;
  float s = 0.f;
  for(int cc=0; cc<NCHUNK; ++cc){
    size_t ix = (size_t)cc*(NH*HSZ*HSZ) + idx;
    float b = BS[ix];
    BS[ix] = s;
    s = Pc[cc*(NH*HSZ) + hi]*s + b;
  }
}

// ---------------- WKV pass C: y += r~ @ S_in ----------------
__global__ __launch_bounds__(256) void wkv_corr_kernel(
    const short* __restrict__ rtb, const float* __restrict__ Sin, float* __restrict__ yb)
{
  int blk = blockIdx.x;
  int ch = blk >> 5, h = blk & 31;
  __shared__ float Ssm[64][64];
  __shared__ float Rsm[64][65];
  int tid = threadIdx.x;
  const float* Sp = Sin + (size_t)(ch*NH + h)*HSZ*HSZ;
  #pragma unroll
  for(int q=0;q<16;q++){
    int ix = q*256 + tid;
    ((float*)Ssm)[ix] = Sp[ix];
  }
  #pragma unroll
  for(int q=0;q<16;q++){
    int ix = q*256 + tid;
    int tl = ix>>6, i = ix&63;
    Rsm[tl][i] = bf2f(rtb[(size_t)(ch*64+tl)*CC + h*64 + i]);
  }
  __syncthreads();
  int tl = tid >> 2;
  int jq = tid & 3;
  float acc[16];
  #pragma unroll
  for(int jj=0;jj<16;jj++) acc[jj]=0.f;
  for(int i=0;i<64;i++){
    float rv = Rsm[tl][i];
    #pragma unroll
    for(int jj=0;jj<16;jj++) acc[jj] += rv * Ssm[i][jq*16+jj];
  }
  #pragma unroll
  for(int jj=0;jj<16;jj++){
    int j = jq*16 + jj;
    yb[(size_t)(ch*64+tl)*CC + h*64 + j] += acc[jj];
  }
}

// ---------------- GroupNorm(H groups) * g -> bf16 ----------------
__global__ __launch_bounds__(256) void gn_mul_kernel(
    const float* __restrict__ yb, const short* __restrict__ gb,
    const float* __restrict__ gam, const float* __restrict__ bet,
    short* __restrict__ yg)
{
  int t = blockIdx.x, tid = threadIdx.x;
  int w = tid >> 6, lane = tid & 63;
  for(int q=0;q<8;q++){
    int h = q*4 + w;
    int cc = h*64 + lane;
    float val = yb[(size_t)t*CC + cc];
    float s = val, ss = val*val;
    #pragma unroll
    for(int off=1;off<64;off<<=1){ s += __shfl_xor(s,off); ss += __shfl_xor(ss,off); }
    float mu = s*(1.f/64.f);
    float var = ss*(1.f/64.f) - mu*mu;
    float rstd = rsqrtf(var + 6.4e-4f);   // eps = 1e-5 * 8^2
    float o = (val-mu)*rstd*gam[cc] + bet[cc];
    yg[(size_t)t*CC + cc] = f2bf(o * bf2f(gb[(size_t)t*CC + cc]));
  }
}

// ---------------- final: out += sigmoid(s0+s1)*(kv0+kv1) ----------------
__global__ __launch_bounds__(256) void final_kernel(
    const float* __restrict__ s0, const float* __restrict__ s1,
    const float* __restrict__ kv0, const float* __restrict__ kv1,
    float* __restrict__ out)
{
  size_t i = ((size_t)blockIdx.x*256 + threadIdx.x)*8;
  #pragma unroll
  for(int j=0;j<8;j++){
    float sv = s0[i+j] + s1[i+j];
    float sig = 1.f/(1.f + expf(-sv));
    out[i+j] = out[i+j] + sig*(kv0[i+j] + kv1[i+j]);
  }
}

extern "C" void kernel_launch(void* const* d_in, const int* in_sizes, int n_in,
                              void* d_out, int out_size, void* d_ws, size_t ws_size,
                              hipStream_t stream)
{
  (void)in_sizes; (void)n_in; (void)out_size;
  const float* x         = (const float*)d_in[0];
  const int*   sp        = (const int*)d_in[1];
  const float* att_state = (const float*)d_in[2];
  const float* wkv_state = (const float*)d_in[3];
  const float* ffn_state = (const float*)d_in[4];
  const float* ln1_g=(const float*)d_in[5],  *ln1_b=(const float*)d_in[6];
  const float* ln2_g=(const float*)d_in[7],  *ln2_b=(const float*)d_in[8];
  const float* maa_x=(const float*)d_in[9],  *maa_w=(const float*)d_in[10], *maa_k=(const float*)d_in[11];
  const float* maa_v=(const float*)d_in[12], *maa_r=(const float*)d_in[13], *maa_g=(const float*)d_in[14];
  const float* tm_w1=(const float*)d_in[15], *tm_w2=(const float*)d_in[16];
  const float* td=(const float*)d_in[17],    *td_w1=(const float*)d_in[18], *td_w2=(const float*)d_in[19];
  const float* u = (const float*)d_in[20];
  const float* Wr=(const float*)d_in[21], *Wk=(const float*)d_in[22], *Wv=(const float*)d_in[23];
  const float* Wg=(const float*)d_in[24], *Wo=(const float*)d_in[25];
  const float* lnx_g=(const float*)d_in[26], *lnx_b=(const float*)d_in[27];
  const float* cm_k=(const float*)d_in[28],  *cm_r=(const float*)d_in[29];
  const float* Wck=(const float*)d_in[30], *Wcv=(const float*)d_in[31], *Wcr=(const float*)d_in[32];

  char* ws = (char*)d_ws;
  const size_t SLOT  = (size_t)TT*CC*4;      // 16 MiB (f32 [T,C])
  const size_t BSLOT = (size_t)TT*CC*2;      // 8 MiB  (bf16 [T,C])
  const size_t WT_SZ = (size_t)4*CC*CC*2;    // 32 MiB (4 square weights / Wck^T 28M)
  const size_t NEED  = 6*SLOT + 10*BSLOT + WT_SZ + (4u<<20);  // 212 MiB
  if(ws_size < NEED) return;   // diagnostic: absmax-fail instead of fault

  float* xa   = (float*)(ws + 0*SLOT);   // S0 (FFN: cr partial z0)
  float* xxb  = (float*)(ws + 1*SLOT);   // S1 (FFN: cr partial z1)
  float* zw   = (float*)(ws + 2*SLOT);   // S2: xf (FFN phase)
  float* decb = (float*)(ws + 3*SLOT);   // S3
  float* yb   = (float*)(ws + 4*SLOT);   // S4 (o/Wcv partial z0)
  float* BS   = (float*)(ws + 5*SLOT);   // S5: Bc->Sin (o/Wcv partial z1)
  short* bA   = (short*)(ws + 6*SLOT);               // 4 slots: staging r,k,v,g / z / xk2,xr2
  short* bO   = (short*)(ws + 6*SLOT + 4*BSLOT);     // 6 slots
  short* b1 = bO + 0*(TT*CC);   // rb   (FFN: hid, 28M over b1..b4)
  short* b2 = bO + 1*(TT*CC);   // kb
  short* b3 = bO + 2*(TT*CC);   // vb
  short* b4 = bO + 3*(TT*CC);   // gb
  short* b5 = bO + 4*(TT*CC);   // xw then rtb
  short* b6 = bO + 5*(TT*CC);   // yg
  short* WT = (short*)(ws + 6*SLOT + 10*BSLOT);
  char*  aux = (char*)WT + WT_SZ;
  float* xxxb = (float*)(aux);                 // [T,160] f32, 1.25 MiB
  float* h1b  = (float*)(aux + (2u<<20));      // [T,64] f32
  float* Pc   = (float*)(aux + (3u<<20));      // 256 KiB
  float* xmid = (float*)d_out;

  dim3 B256(256);
  const int NTC8 = TT*CC/8/256;

  // ---- Tmix front ----
  ln_kernel<<<TT, B256, 0, stream>>>(x, ln1_g, ln1_b, xa, 1e-5f);
  shift1_kernel<<<TT, B256, 0, stream>>>(xa, att_state, sp, xxb);
  zprep_kernel<<<NTC8, B256, 0, stream>>>(xa, xxb, maa_x, bA);
  transpose_f2bf_kernel<<<dim3(4, CC/64), B256, 0, stream>>>(tm_w1, WT, CC, 160);
  gemm_bt_kernel<4><<<dim3(2, TT/128, 1), B256, 0, stream>>>(bA, WT, xxxb, TT, 256, CC, CC, 0,0,0, 160);
  mix5_kernel<<<NTC8, B256, 0, stream>>>(xxxb, tm_w2, xa, xxb,
      maa_w, maa_k, maa_v, maa_r, maa_g,
      b5, bA + 1*(TT*CC), bA + 2*(TT*CC), bA, bA + 3*(TT*CC));
  transpose_f2bf_kernel<<<dim3(2, CC/64), B256, 0, stream>>>(td_w1, WT, CC, 64);
  gemm_bt_kernel<4><<<dim3(1, TT/128, 1), B256, 0, stream>>>(b5, WT, h1b, TT, 128, CC, CC, 0,0,0, 64);
  dec_kernel<<<NTC8, B256, 0, stream>>>(h1b, td_w2, td, decb);

  // ---- r,k,v,g projections: one batched dispatch (z=4) ----
  WPtr4 w4; w4.w[0]=Wr; w4.w[1]=Wk; w4.w[2]=Wv; w4.w[3]=Wg;
  transpose4_f2bf_kernel<<<dim3(CC/64, CC/64, 4), B256, 0, stream>>>(w4, WT);
  gemm_bt_kernel<6><<<dim3(CC/128, TT/128, 4), B256, 0, stream>>>(bA, WT, b1, TT, CC, CC, CC,
      (long)TT*CC, (long)CC*CC, (long)TT*CC, 0);

  // ---- WKV chunked scan ----
  wkv_chunk_kernel<<<NCHUNK*NH, B256, 0, stream>>>(b1, b2, b3, decb, wkv_state, u, sp,
                                                   yb, b5, BS, Pc);
  wkv_combine_kernel<<<NH*HSZ*HSZ/256, B256, 0, stream>>>(BS, Pc);
  wkv_corr_kernel<<<NCHUNK*NH, B256, 0, stream>>>(b5, BS, yb);
  gn_mul_kernel<<<TT, B256, 0, stream>>>(yb, b4, lnx_g, lnx_b, b6);

  // ---- output projection (split-K=2, partials S4/S5) + fused residual+LN2 ----
  transpose_f2bf_kernel<<<dim3(CC/64, CC/64), B256, 0, stream>>>(Wo, WT, CC, CC);
  gemm_bt_kernel<5><<<dim3(CC/128, TT/128, 2), B256, 0, stream>>>(b6, WT, yb, TT, CC, CC, 1024,
      1024, 1024, (long)TT*CC, 0);
  ln2_fused_kernel<<<TT, B256, 0, stream>>>(yb, BS, x, ln2_g, ln2_b, xmid, zw, 1e-5f);

  // ---- CMix ----
  shift2_kernel<<<TT, B256, 0, stream>>>(zw, ffn_state, sp, cm_k, cm_r, bA, bA + 1*(TT*CC));
  transpose_f2bf_kernel<<<dim3(FFND/64, CC/64), B256, 0, stream>>>(Wck, WT, CC, FFND);
  gemm_bt_kernel<3><<<dim3(FFND/128, TT/128, 1), B256, 0, stream>>>(bA, WT, b1, TT, FFND, CC, CC, 0,0,0, 0);
  transpose_f2bf_kernel<<<dim3(CC/64, FFND/64), B256, 0, stream>>>(Wcv, WT, FFND, CC);
  gemm_bt_kernel<5><<<dim3(CC/128, TT/128, 2), B256, 0, stream>>>(b1, WT, yb, TT, CC, FFND, 3584,
      3584, 3584, (long)TT*CC, 0);
  transpose_f2bf_kernel<<<dim3(CC/64, CC/64), B256, 0, stream>>>(Wcr, WT, CC, CC);
  gemm_bt_kernel<5><<<dim3(CC/128, TT/128, 2), B256, 0, stream>>>(bA + 1*(TT*CC), WT, xa, TT, CC, CC, 1024,
      1024, 1024, (long)TT*CC, 0);
  final_kernel<<<NTC8, B256, 0, stream>>>(xa, xxb, yb, BS, xmid);
}

// Round 5
// 845.063 us; speedup vs baseline: 2.2929x; 1.0951x over previous
//
#include <hip/hip_runtime.h>
#include <stdint.h>

// RWKV6 block: B=1, T=2048, C=2048, H=32, HS=64, FFN=7168, NS=4
// Workspace: 6*16M (f32) + 4*8M (bA) + 6*8M (bO) + 32M (WT) + 4M aux = 212 MiB.

#define TT 2048
#define CC 2048
#define NH 32
#define HSZ 64
#define FFND 7168
#define CHUNK 32
#define NCHUNK 64

typedef __attribute__((ext_vector_type(8))) short short8;
typedef __attribute__((ext_vector_type(4))) float f32x4;

__device__ __forceinline__ float bf2f(short s){
  return __uint_as_float(((uint32_t)(uint16_t)s) << 16);
}
__device__ __forceinline__ short f2bf(float f){
  uint32_t u = __float_as_uint(f);
  u = u + 0x7fffu + ((u >> 16) & 1u);
  return (short)(u >> 16);
}

// ---------------- LayerNorm (row over C) ----------------
__global__ __launch_bounds__(256) void ln_kernel(
    const float* __restrict__ xin, const float* __restrict__ gam,
    const float* __restrict__ bet, float* __restrict__ out, float eps)
{
  int t = blockIdx.x, tid = threadIdx.x;
  const float* row = xin + (size_t)t*CC;
  float4 v0 = *(const float4*)(row + tid*8);
  float4 v1 = *(const float4*)(row + tid*8 + 4);
  float s  = v0.x+v0.y+v0.z+v0.w + v1.x+v1.y+v1.z+v1.w;
  float ss = v0.x*v0.x+v0.y*v0.y+v0.z*v0.z+v0.w*v0.w
           + v1.x*v1.x+v1.y*v1.y+v1.z*v1.z+v1.w*v1.w;
  #pragma unroll
  for(int off=1; off<64; off<<=1){ s += __shfl_xor(s,off); ss += __shfl_xor(ss,off); }
  __shared__ float sm[8];
  int w = tid>>6;
  if((tid&63)==0){ sm[w]=s; sm[4+w]=ss; }
  __syncthreads();
  s = sm[0]+sm[1]+sm[2]+sm[3]; ss = sm[4]+sm[5]+sm[6]+sm[7];
  float mean = s * (1.f/CC);
  float var  = ss * (1.f/CC) - mean*mean;
  float rstd = rsqrtf(var + eps);
  float* orow = out + (size_t)t*CC;
  int c = tid*8;
  float vv[8] = {v0.x,v0.y,v0.z,v0.w,v1.x,v1.y,v1.z,v1.w};
  #pragma unroll
  for(int j=0;j<8;j++) orow[c+j] = (vv[j]-mean)*rstd*gam[c+j] + bet[c+j];
}

// ---------------- fused: xmid = p0+p1+x ; zw = LN(xmid) ----------------
__global__ __launch_bounds__(256) void ln2_fused_kernel(
    const float* __restrict__ p0, const float* __restrict__ p1,
    const float* __restrict__ xres, const float* __restrict__ gam,
    const float* __restrict__ bet, float* __restrict__ xsum,
    float* __restrict__ lnout, float eps)
{
  int t = blockIdx.x, tid = threadIdx.x;
  size_t base = (size_t)t*CC + tid*8;
  float vv[8];
  float s = 0.f, ss = 0.f;
  #pragma unroll
  for(int j=0;j<8;j++){
    float v = p0[base+j] + p1[base+j] + xres[base+j];
    vv[j] = v; s += v; ss += v*v;
    xsum[base+j] = v;
  }
  #pragma unroll
  for(int off=1; off<64; off<<=1){ s += __shfl_xor(s,off); ss += __shfl_xor(ss,off); }
  __shared__ float sm[8];
  int w = tid>>6;
  if((tid&63)==0){ sm[w]=s; sm[4+w]=ss; }
  __syncthreads();
  s = sm[0]+sm[1]+sm[2]+sm[3]; ss = sm[4]+sm[5]+sm[6]+sm[7];
  float mean = s * (1.f/CC);
  float var  = ss * (1.f/CC) - mean*mean;
  float rstd = rsqrtf(var + eps);
  int c = tid*8;
  #pragma unroll
  for(int j=0;j<8;j++) lnout[base+j] = (vv[j]-mean)*rstd*gam[c+j] + bet[c+j];
}

// ---------------- token shift (attention): xx = sh - xa (f32 out) ----------------
__global__ __launch_bounds__(256) void shift1_kernel(
    const float* __restrict__ xa, const float* __restrict__ st,
    const int* __restrict__ sp, float* __restrict__ xxb)
{
  int t = blockIdx.x, tid = threadIdx.x;
  int sp0=sp[0], sp1=sp[1], sp2=sp[2], sp3=sp[3];
  bool is_start = (sp0==t)|(sp1==t)|(sp2==t)|(sp3==t);
  int sid = (sp0<=t)+(sp1<=t)+(sp2<=t)+(sp3<=t) - 1;
  sid = sid<0?0:(sid>3?3:sid);
  int c = tid*8;
  const float* src = is_start ? (st + (size_t)sid*CC + c)
                   : (t>0 ? xa + (size_t)(t-1)*CC + c : nullptr);
  const float* cur = xa + (size_t)t*CC + c;
  float* o = xxb + (size_t)t*CC + c;
  #pragma unroll
  for(int jj=0;jj<8;jj++){
    float sh = src ? src[jj] : 0.f;
    o[jj] = sh - cur[jj];
  }
}

// ---------------- token shift (ffn): xk2/xr2 fused, bf16 out ----------------
__global__ __launch_bounds__(256) void shift2_kernel(
    const float* __restrict__ xf, const float* __restrict__ st,
    const int* __restrict__ sp, const float* __restrict__ cmk,
    const float* __restrict__ cmr, short* __restrict__ xk2, short* __restrict__ xr2)
{
  int t = blockIdx.x, tid = threadIdx.x;
  int sp0=sp[0], sp1=sp[1], sp2=sp[2], sp3=sp[3];
  bool is_start = (sp0==t)|(sp1==t)|(sp2==t)|(sp3==t);
  int sid = (sp0<=t)+(sp1<=t)+(sp2<=t)+(sp3<=t) - 1;
  sid = sid<0?0:(sid>3?3:sid);
  int c = tid*8;
  const float* src = is_start ? (st + (size_t)sid*CC + c)
                   : (t>0 ? xf + (size_t)(t-1)*CC + c : nullptr);
  const float* cur = xf + (size_t)t*CC + c;
  size_t ix = (size_t)t*CC + c;
  #pragma unroll
  for(int jj=0;jj<8;jj++){
    float xfv = cur[jj];
    float sh = src ? src[jj] : 0.f;
    float d = sh - xfv;
    xk2[ix+jj] = f2bf(xfv + d*cmk[c+jj]);
    xr2[ix+jj] = f2bf(xfv + d*cmr[c+jj]);
  }
}

// ---------------- z = xa + xx*maa_x -> bf16 ----------------
__global__ __launch_bounds__(256) void zprep_kernel(const float* __restrict__ xa,
   const float* __restrict__ xx, const float* __restrict__ maa, short* __restrict__ z)
{
  size_t i = ((size_t)blockIdx.x*256 + threadIdx.x)*8;
  int c = (int)(i & (CC-1));
  #pragma unroll
  for(int j=0;j<8;j++) z[i+j] = f2bf(xa[i+j] + xx[i+j]*maa[c+j]);
}

// ---------------- fused 5-way maa mix -> bf16 outputs ----------------
__global__ __launch_bounds__(256) void mix5_kernel(
    const float* __restrict__ xxxb, const float* __restrict__ w2,
    const float* __restrict__ xa, const float* __restrict__ xxv,
    const float* __restrict__ mw, const float* __restrict__ mk,
    const float* __restrict__ mv, const float* __restrict__ mr,
    const float* __restrict__ mg,
    short* __restrict__ ow, short* __restrict__ ok, short* __restrict__ ov,
    short* __restrict__ orr, short* __restrict__ og)
{
  int g = blockIdx.x*256 + threadIdx.x;
  int c = g & (CC-1);
  int t0 = (g >> 11) * 8;
  float acc[5][8];
  #pragma unroll
  for(int s=0;s<5;s++)
    #pragma unroll
    for(int tt=0;tt<8;tt++) acc[s][tt]=0.f;
  #pragma unroll
  for(int s=0;s<5;s++){
    for(int e=0;e<32;e++){
      float wv = w2[(size_t)(s*32+e)*CC + c];
      #pragma unroll
      for(int tt=0;tt<8;tt++)
        acc[s][tt] += xxxb[(size_t)(t0+tt)*160 + s*32 + e] * wv;
    }
  }
  float vmw=mw[c], vmk=mk[c], vmv=mv[c], vmr=mr[c], vmg=mg[c];
  #pragma unroll
  for(int tt=0;tt<8;tt++){
    size_t ix = (size_t)(t0+tt)*CC + c;
    float av = xa[ix], xv = xxv[ix];
    ow[ix]  = f2bf(av + xv*(vmw + acc[0][tt]));
    ok[ix]  = f2bf(av + xv*(vmk + acc[1][tt]));
    ov[ix]  = f2bf(av + xv*(vmv + acc[2][tt]));
    orr[ix] = f2bf(av + xv*(vmr + acc[3][tt]));
    og[ix]  = f2bf(av + xv*(vmg + acc[4][tt]));
  }
}

// ---------------- dec = exp(-exp(td + h1 @ td_w2)) (f32) ----------------
__global__ __launch_bounds__(256) void dec_kernel(
    const float* __restrict__ h1b, const float* __restrict__ tw2,
    const float* __restrict__ td, float* __restrict__ out)
{
  int g = blockIdx.x*256 + threadIdx.x;
  int c = g & (CC-1);
  int t0 = (g >> 11)*8;
  float acc[8] = {0,0,0,0,0,0,0,0};
  for(int e=0;e<64;e++){
    float wv = tw2[(size_t)e*CC + c];
    #pragma unroll
    for(int tt=0;tt<8;tt++) acc[tt] += h1b[(size_t)(t0+tt)*64 + e]*wv;
  }
  float tdc = td[c];
  #pragma unroll
  for(int tt=0;tt<8;tt++)
    out[(size_t)(t0+tt)*CC + c] = expf(-expf(tdc + acc[tt]));
}

// ---------------- tanh split-K reduce: out[row,col<NK] = tanh(sum_z part) ----------------
template<int N, int NK>
__global__ __launch_bounds__(256) void tanh_reduce_kernel(
    const float* __restrict__ part, float* __restrict__ out)
{
  int idx = blockIdx.x*256 + threadIdx.x;
  int col = idx & (N-1);
  int row = idx >> (N==256 ? 8 : 7);
  float s = 0.f;
  #pragma unroll
  for(int z=0;z<8;z++) s += part[(size_t)z*TT*N + idx];
  if(col < NK) out[(size_t)row*NK + col] = tanhf(s);
}

// ---------------- W[K,N] f32 -> Wt[NPAD,K] bf16 (transpose, zero-pad n >= N) ----------------
__global__ __launch_bounds__(256) void transpose_f2bf_kernel(
    const float* __restrict__ W, short* __restrict__ Wt, int K, int N)
{
  __shared__ float tile[64][65];
  int n0 = blockIdx.x*64, k0 = blockIdx.y*64;
  int tid = threadIdx.x;
  #pragma unroll
  for(int q=0;q<16;q++){
    int ix = q*256 + tid;
    int r = ix >> 6, cc2 = ix & 63;
    tile[r][cc2] = (n0 + cc2 < N) ? W[(size_t)(k0+r)*N + n0 + cc2] : 0.f;
  }
  __syncthreads();
  #pragma unroll
  for(int q=0;q<16;q++){
    int ix = q*256 + tid;
    int r = ix >> 6, cc2 = ix & 63;
    Wt[(size_t)(n0+r)*K + k0 + cc2] = f2bf(tile[cc2][r]);
  }
}

// batched variant: 4 square CCxCC weights -> WT + z*CC*CC
struct WPtr4 { const float* w[4]; };
__global__ __launch_bounds__(256) void transpose4_f2bf_kernel(
    WPtr4 ws4, short* __restrict__ Wt)
{
  __shared__ float tile[64][65];
  int z = blockIdx.z;
  const float* W = ws4.w[z];
  short* dst = Wt + (size_t)z*CC*CC;
  int n0 = blockIdx.x*64, k0 = blockIdx.y*64;
  int tid = threadIdx.x;
  #pragma unroll
  for(int q=0;q<16;q++){
    int ix = q*256 + tid;
    int r = ix >> 6, cc2 = ix & 63;
    tile[r][cc2] = W[(size_t)(k0+r)*CC + n0 + cc2];
  }
  __syncthreads();
  #pragma unroll
  for(int q=0;q<16;q++){
    int ix = q*256 + tid;
    int r = ix >> 6, cc2 = ix & 63;
    dst[(size_t)(n0+r)*CC + k0 + cc2] = f2bf(tile[cc2][r]);
  }
}

// ---------------- bf16 MFMA GEMM, BK=64, XOR-swizzled LDS, XCD swizzle ----------------
__device__ __forceinline__ void load_lds16(const void* g, void* l){
  __builtin_amdgcn_global_load_lds(
      (const __attribute__((address_space(1))) uint32_t*)g,
      (__attribute__((address_space(3))) uint32_t*)l, 16, 0, 0);
}

// EPI: 0 = bf16 store; 3 = relu^2 bf16; 5 = f32 partial (split-K slab z*zC);
//      6 = batch rkvg (z==3 -> silu bf16)
template<int EPI>
__global__ __launch_bounds__(256) void gemm_bt_kernel(
    const short* __restrict__ A, const short* __restrict__ Bt,
    void* __restrict__ Cout, int M, int N, int Kstride, int Klen,
    long zA, long zB, long zC)
{
  __shared__ __align__(16) short As[128*64];
  __shared__ __align__(16) short Bs[128*64];
  int z = blockIdx.z;
  const short* A0 = A + (size_t)z*zA;
  const short* B0 = Bt + (size_t)z*zB;
  int tid = threadIdx.x;
  int w = tid >> 6, lane = tid & 63;
  int l16 = lane & 15, lhi = lane >> 4;
  int wr = w >> 1, wc = w & 1;
  // XCD-chunked block swizzle (requires gx*gy % 8 == 0)
  int gx = gridDim.x;
  int nwg = gx*gridDim.y;
  int lin = blockIdx.y*gx + blockIdx.x;
  int wg = (lin & 7)*(nwg >> 3) + (lin >> 3);
  int bn = wg % gx, bm = wg / gx;
  const short* Ab = A0 + (size_t)bm*128*Kstride;
  const short* Bb = B0 + (size_t)bn*128*Kstride;
  int srow = w*8 + (lane>>3);      // staging row within 32-row group
  int scol = lane & 7;             // staging slot
  f32x4 acc[4][4] = {};
  for(int kt=0; kt<Klen; kt+=64){
    __syncthreads();
    #pragma unroll
    for(int q=0;q<4;q++){
      int row = q*32 + srow;
      int c8 = scol ^ (row & 7);   // pre-swizzled global source
      int ldsoff = (q*256 + w*64)*8;   // shorts; wave-uniform (HW adds lane*16B)
      load_lds16(Ab + (size_t)row*Kstride + kt + c8*8, As + ldsoff);
      load_lds16(Bb + (size_t)row*Kstride + kt + c8*8, Bs + ldsoff);
    }
    __syncthreads();
    #pragma unroll
    for(int kk=0;kk<2;kk++){
      short8 af[4], bf[4];
      #pragma unroll
      for(int m=0;m<4;m++){
        int row = wr*64 + m*16 + l16;
        int slot = (kk*4 + lhi) ^ (row & 7);
        af[m] = *(const short8*)(As + row*64 + slot*8);
      }
      #pragma unroll
      for(int n=0;n<4;n++){
        int row = wc*64 + n*16 + l16;
        int slot = (kk*4 + lhi) ^ (row & 7);
        bf[n] = *(const short8*)(Bs + row*64 + slot*8);
      }
      #pragma unroll
      for(int m=0;m<4;m++){
        #pragma unroll
        for(int n=0;n<4;n++)
          acc[m][n] = __builtin_amdgcn_mfma_f32_16x16x32_bf16(af[m], bf[n], acc[m][n], 0, 0, 0);
      }
    }
  }
  int m0 = bm*128 + wr*64;
  int n0 = bn*128 + wc*64;
  #pragma unroll
  for(int m=0;m<4;m++){
    #pragma unroll
    for(int n=0;n<4;n++){
      #pragma unroll
      for(int jj=0;jj<4;jj++){
        int row = m0 + m*16 + lhi*4 + jj;
        int col = n0 + n*16 + l16;
        size_t ix = (size_t)row*N + col;
        float val = acc[m][n][jj];
        if constexpr (EPI==0){ ((short*)Cout)[(size_t)z*zC + ix] = f2bf(val); }
        else if constexpr (EPI==3){ float rv = fmaxf(val, 0.f); ((short*)Cout)[ix] = f2bf(rv*rv); }
        else if constexpr (EPI==5){ ((float*)Cout)[(size_t)z*zC + ix] = val; }
        else { // 6: rkvg batch
          short* o = (short*)Cout + (size_t)z*zC;
          o[ix] = (z==3) ? f2bf(val/(1.f+expf(-val))) : f2bf(val);
        }
      }
    }
  }
}

// ---------------- WKV pass A: per-(chunk,head) local scan ----------------
// thread: a = tid&3 (i-subgroup of 16), j = tid>>2 (value column)
// Double-buffered LDS stage (1 barrier/step); decay product p lives in LDS.
__global__ __launch_bounds__(256) void wkv_chunk_kernel(
    const short* __restrict__ rb, const short* __restrict__ kb,
    const short* __restrict__ vb, const float* __restrict__ db,
    const float* __restrict__ wkv_state, const float* __restrict__ u,
    const int* __restrict__ sp,
    float* __restrict__ yb, short* __restrict__ rtb,
    float* __restrict__ Bc, float* __restrict__ Pc)
{
  int blk = blockIdx.x;
  int ch = blk >> 5;       // chunk (0..NCHUNK-1)
  int h  = blk & 31;       // head
  int tid = threadIdx.x;
  int a = tid & 3, j = tid >> 2;
  int w = tid >> 6, lane = tid & 63;
  __shared__ float sr[2][64], sk[2][64], suk[2][64], sv[2][64], sd[2][64];
  __shared__ float sp_[64];
  float u_reg = (w==1) ? u[h*64 + lane] : 0.f;
  if(tid < 64) sp_[tid] = 1.f;
  float S[16];
  #pragma unroll
  for(int ii=0;ii<16;ii++) S[ii]=0.f;
  int sp0=sp[0], sp1=sp[1], sp2=sp[2], sp3=sp[3];
  int tbase = ch*CHUNK;
  {
    size_t gb = (size_t)tbase*CC + h*64;
    if(w==0)      sr[0][lane] = bf2f(rb[gb+lane]);
    else if(w==1){ float kv_=bf2f(kb[gb+lane]); sk[0][lane]=kv_; suk[0][lane]=u_reg*kv_; }
    else if(w==2) sv[0][lane] = bf2f(vb[gb+lane]);
    else          sd[0][lane] = db[gb+lane];
  }
  __syncthreads();
  for(int tl=0; tl<CHUNK; ++tl){
    int t = tbase + tl;
    int buf = tl & 1;
    if(tl+1 < CHUNK){
      size_t nb = (size_t)(t+1)*CC + h*64;
      int b2_ = buf^1;
      if(w==0)      sr[b2_][lane] = bf2f(rb[nb+lane]);
      else if(w==1){ float kv_=bf2f(kb[nb+lane]); sk[b2_][lane]=kv_; suk[b2_][lane]=u_reg*kv_; }
      else if(w==2) sv[b2_][lane] = bf2f(vb[nb+lane]);
      else          sd[b2_][lane] = db[nb+lane];
    }
    size_t base = (size_t)t*CC + h*64;
    bool is_start = (sp0==t)|(sp1==t)|(sp2==t)|(sp3==t);
    if(is_start){
      int sid = (sp0<=t)+(sp1<=t)+(sp2<=t)+(sp3<=t) - 1;
      sid = sid<0?0:(sid>3?3:sid);
      const float* wsrc = wkv_state + (((size_t)sid*NH + h)*HSZ + a*16)*HSZ + j;
      #pragma unroll
      for(int ii=0;ii<16;ii++) S[ii] = wsrc[(size_t)ii*HSZ];
      if(tid < 64) sp_[tid] = 0.f;
    }
    float vj = sv[buf][j];
    float yp = 0.f, bp = 0.f;
    #pragma unroll
    for(int ii=0;ii<16;ii++){
      int i = a*16 + ii;
      float ri = sr[buf][i];
      yp += ri * S[ii];
      bp += ri * suk[buf][i];
    }
    yp += __shfl_xor(yp, 1); yp += __shfl_xor(yp, 2);
    bp += __shfl_xor(bp, 1); bp += __shfl_xor(bp, 2);
    if(a == 0) yb[base + j] = yp + bp*vj;
    if(tid < 64){
      rtb[base + tid] = f2bf(sr[buf][tid] * sp_[tid]);
      sp_[tid] *= sd[buf][tid];
    }
    #pragma unroll
    for(int ii=0;ii<16;ii++){
      int i = a*16 + ii;
      S[ii] = sd[buf][i]*S[ii] + sk[buf][i]*vj;
    }
    __syncthreads();
  }
  size_t cb = ((size_t)ch*NH + h)*HSZ*HSZ;
  #pragma unroll
  for(int ii=0;ii<16;ii++) Bc[cb + (size_t)(a*16+ii)*HSZ + j] = S[ii];
  if(tid < 64) Pc[((size_t)ch*NH + h)*HSZ + tid] = sp_[tid];
}

// ---------------- WKV pass B: sequential combine (in-place Bc->Sin) ----------------
__global__ __launch_bounds__(256) void wkv_combine_kernel(
    float* __restrict__ BS, const float* __restrict__ Pc)
{
  int idx = blockIdx.x*256 + threadIdx.x;
  int hi = idx >> 6;
  float s = 0.f;
  for(int cc=0; cc<NCHUNK; ++cc){
    size_t ix = (size_t)cc*(NH*HSZ*HSZ) + idx;
    float b = BS[ix];
    BS[ix] = s;
    s = Pc[cc*(NH*HSZ) + hi]*s + b;
  }
}

// ---------------- WKV pass C: y += r~ @ S_in  (CHUNK=32 rows per block) ----------------
__global__ __launch_bounds__(256) void wkv_corr_kernel(
    const short* __restrict__ rtb, const float* __restrict__ Sin, float* __restrict__ yb)
{
  int blk = blockIdx.x;
  int ch = blk >> 5, h = blk & 31;
  __shared__ float Ssm[64][64];
  __shared__ float Rsm[32][65];
  int tid = threadIdx.x;
  const float* Sp = Sin + (size_t)(ch*NH + h)*HSZ*HSZ;
  #pragma unroll
  for(int q=0;q<16;q++) ((float*)Ssm)[q*256+tid] = Sp[q*256+tid];
  #pragma unroll
  for(int q=0;q<8;q++){
    int ix = q*256 + tid;
    int tl = ix>>6, i = ix&63;
    Rsm[tl][i] = bf2f(rtb[(size_t)(ch*CHUNK+tl)*CC + h*64 + i]);
  }
  __syncthreads();
  int tl = tid >> 3;   // 0..31
  int jq = tid & 7;    // 0..7
  float acc[8];
  #pragma unroll
  for(int jj=0;jj<8;jj++) acc[jj]=0.f;
  for(int i=0;i<64;i++){
    float rv = Rsm[tl][i];
    #pragma unroll
    for(int jj=0;jj<8;jj++) acc[jj] += rv * Ssm[i][jq*8+jj];
  }
  #pragma unroll
  for(int jj=0;jj<8;jj++)
    yb[(size_t)(ch*CHUNK+tl)*CC + h*64 + jq*8+jj] += acc[jj];
}

// ---------------- GroupNorm(H groups) * g -> bf16 ----------------
__global__ __launch_bounds__(256) void gn_mul_kernel(
    const float* __restrict__ yb, const short* __restrict__ gb,
    const float* __restrict__ gam, const float* __restrict__ bet,
    short* __restrict__ yg)
{
  int t = blockIdx.x, tid = threadIdx.x;
  int w = tid >> 6, lane = tid & 63;
  for(int q=0;q<8;q++){
    int h = q*4 + w;
    int cc = h*64 + lane;
    float val = yb[(size_t)t*CC + cc];
    float s = val, ss = val*val;
    #pragma unroll
    for(int off=1;off<64;off<<=1){ s += __shfl_xor(s,off); ss += __shfl_xor(ss,off); }
    float mu = s*(1.f/64.f);
    float var = ss*(1.f/64.f) - mu*mu;
    float rstd = rsqrtf(var + 6.4e-4f);   // eps = 1e-5 * 8^2
    float o = (val-mu)*rstd*gam[cc] + bet[cc];
    yg[(size_t)t*CC + cc] = f2bf(o * bf2f(gb[(size_t)t*CC + cc]));
  }
}

// ---------------- final: out += sigmoid(s0+s1)*(kv0+kv1) ----------------
__global__ __launch_bounds__(256) void final_kernel(
    const float* __restrict__ s0, const float* __restrict__ s1,
    const float* __restrict__ kv0, const float* __restrict__ kv1,
    float* __restrict__ out)
{
  size_t i = ((size_t)blockIdx.x*256 + threadIdx.x)*8;
  #pragma unroll
  for(int j=0;j<8;j++){
    float sv = s0[i+j] + s1[i+j];
    float sig = 1.f/(1.f + expf(-sv));
    out[i+j] = out[i+j] + sig*(kv0[i+j] + kv1[i+j]);
  }
}

extern "C" void kernel_launch(void* const* d_in, const int* in_sizes, int n_in,
                              void* d_out, int out_size, void* d_ws, size_t ws_size,
                              hipStream_t stream)
{
  (void)in_sizes; (void)n_in; (void)out_size;
  const float* x         = (const float*)d_in[0];
  const int*   sp        = (const int*)d_in[1];
  const float* att_state = (const float*)d_in[2];
  const float* wkv_state = (const float*)d_in[3];
  const float* ffn_state = (const float*)d_in[4];
  const float* ln1_g=(const float*)d_in[5],  *ln1_b=(const float*)d_in[6];
  const float* ln2_g=(const float*)d_in[7],  *ln2_b=(const float*)d_in[8];
  const float* maa_x=(const float*)d_in[9],  *maa_w=(const float*)d_in[10], *maa_k=(const float*)d_in[11];
  const float* maa_v=(const float*)d_in[12], *maa_r=(const float*)d_in[13], *maa_g=(const float*)d_in[14];
  const float* tm_w1=(const float*)d_in[15], *tm_w2=(const float*)d_in[16];
  const float* td=(const float*)d_in[17],    *td_w1=(const float*)d_in[18], *td_w2=(const float*)d_in[19];
  const float* u = (const float*)d_in[20];
  const float* Wr=(const float*)d_in[21], *Wk=(const float*)d_in[22], *Wv=(const float*)d_in[23];
  const float* Wg=(const float*)d_in[24], *Wo=(const float*)d_in[25];
  const float* lnx_g=(const float*)d_in[26], *lnx_b=(const float*)d_in[27];
  const float* cm_k=(const float*)d_in[28],  *cm_r=(const float*)d_in[29];
  const float* Wck=(const float*)d_in[30], *Wcv=(const float*)d_in[31], *Wcr=(const float*)d_in[32];

  char* ws = (char*)d_ws;
  const size_t SLOT  = (size_t)TT*CC*4;      // 16 MiB (f32 [T,C])
  const size_t BSLOT = (size_t)TT*CC*2;      // 8 MiB  (bf16 [T,C])
  const size_t WT_SZ = (size_t)4*CC*CC*2;    // 32 MiB
  const size_t NEED  = 6*SLOT + 10*BSLOT + WT_SZ + (4u<<20);  // 212 MiB
  if(ws_size < NEED) return;

  float* xa   = (float*)(ws + 0*SLOT);   // S0: xa -> BS(32M, S0-S1) -> cr partial z0
  float* xxb  = (float*)(ws + 1*SLOT);   // S1: xxb -> (BS high) -> cr partial z1
  float* zw   = (float*)(ws + 2*SLOT);   // S2: xxx partials (16M) -> xf
  float* decb = (float*)(ws + 3*SLOT);   // S3
  float* yb   = (float*)(ws + 4*SLOT);   // S4: h1 partials -> y -> o/Wcv partial z0
  float* S5   = (float*)(ws + 5*SLOT);   // S5: o/Wcv partial z1
  float* BS   = xa;                      // 32 MiB spans S0-S1 during WKV
  float* xxxPart = zw;                   // [8][T,256] f32
  float* h1Part  = yb;                   // [8][T,128] f32
  short* bA   = (short*)(ws + 6*SLOT);               // 4 slots: z / r,k,v,g mix / xk2,xr2
  short* bO   = (short*)(ws + 6*SLOT + 4*BSLOT);     // 6 slots
  short* b1 = bO + 0*(TT*CC);   // rb   (FFN: hid 28M over b1..b4)
  short* b2 = bO + 1*(TT*CC);   // kb
  short* b3 = bO + 2*(TT*CC);   // vb
  short* b4 = bO + 3*(TT*CC);   // gb
  short* b5 = bO + 4*(TT*CC);   // xw then rtb
  short* b6 = bO + 5*(TT*CC);   // yg
  short* WT = (short*)(ws + 6*SLOT + 10*BSLOT);
  char*  aux = (char*)WT + WT_SZ;
  float* xxxb = (float*)(aux);                 // [T,160] f32, 1.25 MiB
  float* h1b  = (float*)(aux + (2u<<20));      // [T,64] f32
  float* Pc   = (float*)(aux + (5u<<19));      // [NCHUNK][NH][64] f32 = 512 KiB
  float* xmid = (float*)d_out;

  dim3 B256(256);
  const int NTC8 = TT*CC/8/256;

  // ---- Tmix front ----
  ln_kernel<<<TT, B256, 0, stream>>>(x, ln1_g, ln1_b, xa, 1e-5f);
  shift1_kernel<<<TT, B256, 0, stream>>>(xa, att_state, sp, xxb);
  zprep_kernel<<<NTC8, B256, 0, stream>>>(xa, xxb, maa_x, bA);
  transpose_f2bf_kernel<<<dim3(4, CC/64), B256, 0, stream>>>(tm_w1, WT, CC, 160);
  gemm_bt_kernel<5><<<dim3(2, TT/128, 8), B256, 0, stream>>>(bA, WT, xxxPart, TT, 256, CC, 256,
      256, 256, (long)TT*256);
  tanh_reduce_kernel<256,160><<<TT, B256, 0, stream>>>(xxxPart, xxxb);
  mix5_kernel<<<NTC8, B256, 0, stream>>>(xxxb, tm_w2, xa, xxb,
      maa_w, maa_k, maa_v, maa_r, maa_g,
      b5, bA + 1*(TT*CC), bA + 2*(TT*CC), bA, bA + 3*(TT*CC));
  transpose_f2bf_kernel<<<dim3(2, CC/64), B256, 0, stream>>>(td_w1, WT, CC, 64);
  gemm_bt_kernel<5><<<dim3(1, TT/128, 8), B256, 0, stream>>>(b5, WT, h1Part, TT, 128, CC, 256,
      256, 256, (long)TT*128);
  tanh_reduce_kernel<128,64><<<TT/2, B256, 0, stream>>>(h1Part, h1b);
  dec_kernel<<<NTC8, B256, 0, stream>>>(h1b, td_w2, td, decb);

  // ---- r,k,v,g projections: one batched dispatch (z=4) ----
  WPtr4 w4; w4.w[0]=Wr; w4.w[1]=Wk; w4.w[2]=Wv; w4.w[3]=Wg;
  transpose4_f2bf_kernel<<<dim3(CC/64, CC/64, 4), B256, 0, stream>>>(w4, WT);
  gemm_bt_kernel<6><<<dim3(CC/128, TT/128, 4), B256, 0, stream>>>(bA, WT, b1, TT, CC, CC, CC,
      (long)TT*CC, (long)CC*CC, (long)TT*CC);

  // ---- WKV chunked scan (CHUNK=32, 2048 blocks) ----
  wkv_chunk_kernel<<<NCHUNK*NH, B256, 0, stream>>>(b1, b2, b3, decb, wkv_state, u, sp,
                                                   yb, b5, BS, Pc);
  wkv_combine_kernel<<<NH*HSZ*HSZ/256, B256, 0, stream>>>(BS, Pc);
  wkv_corr_kernel<<<NCHUNK*NH, B256, 0, stream>>>(b5, BS, yb);
  gn_mul_kernel<<<TT, B256, 0, stream>>>(yb, b4, lnx_g, lnx_b, b6);

  // ---- output projection (split-K=2, partials S4/S5) + fused residual+LN2 ----
  transpose_f2bf_kernel<<<dim3(CC/64, CC/64), B256, 0, stream>>>(Wo, WT, CC, CC);
  gemm_bt_kernel<5><<<dim3(CC/128, TT/128, 2), B256, 0, stream>>>(b6, WT, yb, TT, CC, CC, 1024,
      1024, 1024, (long)TT*CC);
  ln2_fused_kernel<<<TT, B256, 0, stream>>>(yb, S5, x, ln2_g, ln2_b, xmid, zw, 1e-5f);

  // ---- CMix ----
  shift2_kernel<<<TT, B256, 0, stream>>>(zw, ffn_state, sp, cm_k, cm_r, bA, bA + 1*(TT*CC));
  transpose_f2bf_kernel<<<dim3(FFND/64, CC/64), B256, 0, stream>>>(Wck, WT, CC, FFND);
  gemm_bt_kernel<3><<<dim3(FFND/128, TT/128, 1), B256, 0, stream>>>(bA, WT, b1, TT, FFND, CC, CC, 0,0,0);
  transpose_f2bf_kernel<<<dim3(CC/64, FFND/64), B256, 0, stream>>>(Wcv, WT, FFND, CC);
  gemm_bt_kernel<5><<<dim3(CC/128, TT/128, 2), B256, 0, stream>>>(b1, WT, yb, TT, CC, FFND, 3584,
      3584, 3584, (long)TT*CC);
  transpose_f2bf_kernel<<<dim3(CC/64, CC/64), B256, 0, stream>>>(Wcr, WT, CC, CC);
  gemm_bt_kernel<5><<<dim3(CC/128, TT/128, 2), B256, 0, stream>>>(bA + 1*(TT*CC), WT, xa, TT, CC, CC, 1024,
      1024, 1024, (long)TT*CC);
  final_kernel<<<NTC8, B256, 0, stream>>>(xa, xxb, yb, S5, xmid);
}

// Round 7
// 792.355 us; speedup vs baseline: 2.4454x; 1.0665x over previous
//
#include <hip/hip_runtime.h>
#include <stdint.h>

// RWKV6 block: B=1, T=2048, C=2048, H=32, HS=64, FFN=7168, NS=4
// Workspace: 6*16M (f32) + 4*8M (bA) + 6*8M (bO) + 32M (WT) + 4M aux = 212 MiB.

#define TT 2048
#define CC 2048
#define NH 32
#define HSZ 64
#define FFND 7168
#define CHUNK 32
#define NCHUNK 64

typedef __attribute__((ext_vector_type(8))) short short8;
typedef __attribute__((ext_vector_type(4))) float f32x4;

__device__ __forceinline__ float bf2f(short s){
  return __uint_as_float(((uint32_t)(uint16_t)s) << 16);
}
__device__ __forceinline__ short f2bf(float f){
  uint32_t u = __float_as_uint(f);
  u = u + 0x7fffu + ((u >> 16) & 1u);
  return (short)(u >> 16);
}

// ---------------- LayerNorm (row over C) ----------------
__global__ __launch_bounds__(256) void ln_kernel(
    const float* __restrict__ xin, const float* __restrict__ gam,
    const float* __restrict__ bet, float* __restrict__ out, float eps)
{
  int t = blockIdx.x, tid = threadIdx.x;
  const float* row = xin + (size_t)t*CC;
  float4 v0 = *(const float4*)(row + tid*8);
  float4 v1 = *(const float4*)(row + tid*8 + 4);
  float s  = v0.x+v0.y+v0.z+v0.w + v1.x+v1.y+v1.z+v1.w;
  float ss = v0.x*v0.x+v0.y*v0.y+v0.z*v0.z+v0.w*v0.w
           + v1.x*v1.x+v1.y*v1.y+v1.z*v1.z+v1.w*v1.w;
  #pragma unroll
  for(int off=1; off<64; off<<=1){ s += __shfl_xor(s,off); ss += __shfl_xor(ss,off); }
  __shared__ float sm[8];
  int w = tid>>6;
  if((tid&63)==0){ sm[w]=s; sm[4+w]=ss; }
  __syncthreads();
  s = sm[0]+sm[1]+sm[2]+sm[3]; ss = sm[4]+sm[5]+sm[6]+sm[7];
  float mean = s * (1.f/CC);
  float var  = ss * (1.f/CC) - mean*mean;
  float rstd = rsqrtf(var + eps);
  float* orow = out + (size_t)t*CC;
  int c = tid*8;
  float vv[8] = {v0.x,v0.y,v0.z,v0.w,v1.x,v1.y,v1.z,v1.w};
  #pragma unroll
  for(int j=0;j<8;j++) orow[c+j] = (vv[j]-mean)*rstd*gam[c+j] + bet[c+j];
}

// ---------------- fused: xmid = p0+p1+x ; zw = LN(xmid) ----------------
__global__ __launch_bounds__(256) void ln2_fused_kernel(
    const float* __restrict__ p0, const float* __restrict__ p1,
    const float* __restrict__ xres, const float* __restrict__ gam,
    const float* __restrict__ bet, float* __restrict__ xsum,
    float* __restrict__ lnout, float eps)
{
  int t = blockIdx.x, tid = threadIdx.x;
  size_t base = (size_t)t*CC + tid*8;
  float vv[8];
  float s = 0.f, ss = 0.f;
  #pragma unroll
  for(int j=0;j<8;j++){
    float v = p0[base+j] + p1[base+j] + xres[base+j];
    vv[j] = v; s += v; ss += v*v;
    xsum[base+j] = v;
  }
  #pragma unroll
  for(int off=1; off<64; off<<=1){ s += __shfl_xor(s,off); ss += __shfl_xor(ss,off); }
  __shared__ float sm[8];
  int w = tid>>6;
  if((tid&63)==0){ sm[w]=s; sm[4+w]=ss; }
  __syncthreads();
  s = sm[0]+sm[1]+sm[2]+sm[3]; ss = sm[4]+sm[5]+sm[6]+sm[7];
  float mean = s * (1.f/CC);
  float var  = ss * (1.f/CC) - mean*mean;
  float rstd = rsqrtf(var + eps);
  int c = tid*8;
  #pragma unroll
  for(int j=0;j<8;j++) lnout[base+j] = (vv[j]-mean)*rstd*gam[c+j] + bet[c+j];
}

// ---------------- token shift (attention): xx = sh - xa (f32 out) ----------------
__global__ __launch_bounds__(256) void shift1_kernel(
    const float* __restrict__ xa, const float* __restrict__ st,
    const int* __restrict__ sp, float* __restrict__ xxb)
{
  int t = blockIdx.x, tid = threadIdx.x;
  int sp0=sp[0], sp1=sp[1], sp2=sp[2], sp3=sp[3];
  bool is_start = (sp0==t)|(sp1==t)|(sp2==t)|(sp3==t);
  int sid = (sp0<=t)+(sp1<=t)+(sp2<=t)+(sp3<=t) - 1;
  sid = sid<0?0:(sid>3?3:sid);
  int c = tid*8;
  const float* src = is_start ? (st + (size_t)sid*CC + c)
                   : (t>0 ? xa + (size_t)(t-1)*CC + c : nullptr);
  const float* cur = xa + (size_t)t*CC + c;
  float* o = xxb + (size_t)t*CC + c;
  #pragma unroll
  for(int jj=0;jj<8;jj++){
    float sh = src ? src[jj] : 0.f;
    o[jj] = sh - cur[jj];
  }
}

// ---------------- token shift (ffn): xk2/xr2 fused, bf16 out ----------------
__global__ __launch_bounds__(256) void shift2_kernel(
    const float* __restrict__ xf, const float* __restrict__ st,
    const int* __restrict__ sp, const float* __restrict__ cmk,
    const float* __restrict__ cmr, short* __restrict__ xk2, short* __restrict__ xr2)
{
  int t = blockIdx.x, tid = threadIdx.x;
  int sp0=sp[0], sp1=sp[1], sp2=sp[2], sp3=sp[3];
  bool is_start = (sp0==t)|(sp1==t)|(sp2==t)|(sp3==t);
  int sid = (sp0<=t)+(sp1<=t)+(sp2<=t)+(sp3<=t) - 1;
  sid = sid<0?0:(sid>3?3:sid);
  int c = tid*8;
  const float* src = is_start ? (st + (size_t)sid*CC + c)
                   : (t>0 ? xf + (size_t)(t-1)*CC + c : nullptr);
  const float* cur = xf + (size_t)t*CC + c;
  size_t ix = (size_t)t*CC + c;
  #pragma unroll
  for(int jj=0;jj<8;jj++){
    float xfv = cur[jj];
    float sh = src ? src[jj] : 0.f;
    float d = sh - xfv;
    xk2[ix+jj] = f2bf(xfv + d*cmk[c+jj]);
    xr2[ix+jj] = f2bf(xfv + d*cmr[c+jj]);
  }
}

// ---------------- z = xa + xx*maa_x -> bf16 ----------------
__global__ __launch_bounds__(256) void zprep_kernel(const float* __restrict__ xa,
   const float* __restrict__ xx, const float* __restrict__ maa, short* __restrict__ z)
{
  size_t i = ((size_t)blockIdx.x*256 + threadIdx.x)*8;
  int c = (int)(i & (CC-1));
  #pragma unroll
  for(int j=0;j<8;j++) z[i+j] = f2bf(xa[i+j] + xx[i+j]*maa[c+j]);
}

// ---------------- fused 5-way maa mix -> bf16 outputs ----------------
__global__ __launch_bounds__(256) void mix5_kernel(
    const float* __restrict__ xxxb, const float* __restrict__ w2,
    const float* __restrict__ xa, const float* __restrict__ xxv,
    const float* __restrict__ mw, const float* __restrict__ mk,
    const float* __restrict__ mv, const float* __restrict__ mr,
    const float* __restrict__ mg,
    short* __restrict__ ow, short* __restrict__ ok, short* __restrict__ ov,
    short* __restrict__ orr, short* __restrict__ og)
{
  int g = blockIdx.x*256 + threadIdx.x;
  int c = g & (CC-1);
  int t0 = (g >> 11) * 8;
  float acc[5][8];
  #pragma unroll
  for(int s=0;s<5;s++)
    #pragma unroll
    for(int tt=0;tt<8;tt++) acc[s][tt]=0.f;
  #pragma unroll
  for(int s=0;s<5;s++){
    for(int e=0;e<32;e++){
      float wv = w2[(size_t)(s*32+e)*CC + c];
      #pragma unroll
      for(int tt=0;tt<8;tt++)
        acc[s][tt] += xxxb[(size_t)(t0+tt)*160 + s*32 + e] * wv;
    }
  }
  float vmw=mw[c], vmk=mk[c], vmv=mv[c], vmr=mr[c], vmg=mg[c];
  #pragma unroll
  for(int tt=0;tt<8;tt++){
    size_t ix = (size_t)(t0+tt)*CC + c;
    float av = xa[ix], xv = xxv[ix];
    ow[ix]  = f2bf(av + xv*(vmw + acc[0][tt]));
    ok[ix]  = f2bf(av + xv*(vmk + acc[1][tt]));
    ov[ix]  = f2bf(av + xv*(vmv + acc[2][tt]));
    orr[ix] = f2bf(av + xv*(vmr + acc[3][tt]));
    og[ix]  = f2bf(av + xv*(vmg + acc[4][tt]));
  }
}

// ---------------- dec = exp(-exp(td + h1 @ td_w2)) (f32) ----------------
__global__ __launch_bounds__(256) void dec_kernel(
    const float* __restrict__ h1b, const float* __restrict__ tw2,
    const float* __restrict__ td, float* __restrict__ out)
{
  int g = blockIdx.x*256 + threadIdx.x;
  int c = g & (CC-1);
  int t0 = (g >> 11)*8;
  float acc[8] = {0,0,0,0,0,0,0,0};
  for(int e=0;e<64;e++){
    float wv = tw2[(size_t)e*CC + c];
    #pragma unroll
    for(int tt=0;tt<8;tt++) acc[tt] += h1b[(size_t)(t0+tt)*64 + e]*wv;
  }
  float tdc = td[c];
  #pragma unroll
  for(int tt=0;tt<8;tt++)
    out[(size_t)(t0+tt)*CC + c] = expf(-expf(tdc + acc[tt]));
}

// ---------------- tanh split-K reduce ----------------
template<int N, int NK>
__global__ __launch_bounds__(256) void tanh_reduce_kernel(
    const float* __restrict__ part, float* __restrict__ out)
{
  int idx = blockIdx.x*256 + threadIdx.x;
  int col = idx & (N-1);
  int row = idx >> (N==256 ? 8 : 7);
  float s = 0.f;
  #pragma unroll
  for(int z=0;z<8;z++) s += part[(size_t)z*TT*N + idx];
  if(col < NK) out[(size_t)row*NK + col] = tanhf(s);
}

// ---------------- W[K,N] f32 -> Wt[NPAD,K] bf16 ----------------
__global__ __launch_bounds__(256) void transpose_f2bf_kernel(
    const float* __restrict__ W, short* __restrict__ Wt, int K, int N)
{
  __shared__ float tile[64][65];
  int n0 = blockIdx.x*64, k0 = blockIdx.y*64;
  int tid = threadIdx.x;
  #pragma unroll
  for(int q=0;q<16;q++){
    int ix = q*256 + tid;
    int r = ix >> 6, cc2 = ix & 63;
    tile[r][cc2] = (n0 + cc2 < N) ? W[(size_t)(k0+r)*N + n0 + cc2] : 0.f;
  }
  __syncthreads();
  #pragma unroll
  for(int q=0;q<16;q++){
    int ix = q*256 + tid;
    int r = ix >> 6, cc2 = ix & 63;
    Wt[(size_t)(n0+r)*K + k0 + cc2] = f2bf(tile[cc2][r]);
  }
}

struct WPtr4 { const float* w[4]; };
__global__ __launch_bounds__(256) void transpose4_f2bf_kernel(
    WPtr4 ws4, short* __restrict__ Wt)
{
  __shared__ float tile[64][65];
  int z = blockIdx.z;
  const float* W = ws4.w[z];
  short* dst = Wt + (size_t)z*CC*CC;
  int n0 = blockIdx.x*64, k0 = blockIdx.y*64;
  int tid = threadIdx.x;
  #pragma unroll
  for(int q=0;q<16;q++){
    int ix = q*256 + tid;
    int r = ix >> 6, cc2 = ix & 63;
    tile[r][cc2] = W[(size_t)(k0+r)*CC + n0 + cc2];
  }
  __syncthreads();
  #pragma unroll
  for(int q=0;q<16;q++){
    int ix = q*256 + tid;
    int r = ix >> 6, cc2 = ix & 63;
    dst[(size_t)(n0+r)*CC + k0 + cc2] = f2bf(tile[cc2][r]);
  }
}

__device__ __forceinline__ void load_lds16(const void* g, void* l){
  __builtin_amdgcn_global_load_lds(
      (const __attribute__((address_space(1))) uint32_t*)g,
      (__attribute__((address_space(3))) uint32_t*)l, 16, 0, 0);
}

// ---------------- 128^2 MFMA GEMM (m97-structure + swizzle) ----------------
// EPI: 0 bf16; 3 relu^2 bf16; 5 f32 partial slab; 6 rkvg batch
template<int EPI>
__global__ __launch_bounds__(256) void gemm_bt_kernel(
    const short* __restrict__ A, const short* __restrict__ Bt,
    void* __restrict__ Cout, int M, int N, int Kstride, int Klen,
    long zA, long zB, long zC)
{
  __shared__ __align__(16) short As[128*64];
  __shared__ __align__(16) short Bs[128*64];
  int z = blockIdx.z;
  const short* A0 = A + (size_t)z*zA;
  const short* B0 = Bt + (size_t)z*zB;
  int tid = threadIdx.x;
  int w = tid >> 6, lane = tid & 63;
  int l16 = lane & 15, lhi = lane >> 4;
  int wr = w >> 1, wc = w & 1;
  int gx = gridDim.x;
  int nwg = gx*gridDim.y;
  int lin = blockIdx.y*gx + blockIdx.x;
  int wg = (lin & 7)*(nwg >> 3) + (lin >> 3);
  int bn = wg % gx, bm = wg / gx;
  const short* Ab = A0 + (size_t)bm*128*Kstride;
  const short* Bb = B0 + (size_t)bn*128*Kstride;
  int srow = w*8 + (lane>>3);
  int scol = lane & 7;
  f32x4 acc[4][4] = {};
  for(int kt=0; kt<Klen; kt+=64){
    __syncthreads();
    #pragma unroll
    for(int q=0;q<4;q++){
      int row = q*32 + srow;
      int c8 = scol ^ (row & 7);
      int ldsoff = (q*256 + w*64)*8;
      load_lds16(Ab + (size_t)row*Kstride + kt + c8*8, As + ldsoff);
      load_lds16(Bb + (size_t)row*Kstride + kt + c8*8, Bs + ldsoff);
    }
    __syncthreads();
    #pragma unroll
    for(int kk=0;kk<2;kk++){
      short8 af[4], bf[4];
      #pragma unroll
      for(int m=0;m<4;m++){
        int row = wr*64 + m*16 + l16;
        int slot = (kk*4 + lhi) ^ (row & 7);
        af[m] = *(const short8*)(As + row*64 + slot*8);
      }
      #pragma unroll
      for(int n=0;n<4;n++){
        int row = wc*64 + n*16 + l16;
        int slot = (kk*4 + lhi) ^ (row & 7);
        bf[n] = *(const short8*)(Bs + row*64 + slot*8);
      }
      #pragma unroll
      for(int m=0;m<4;m++){
        #pragma unroll
        for(int n=0;n<4;n++)
          acc[m][n] = __builtin_amdgcn_mfma_f32_16x16x32_bf16(af[m], bf[n], acc[m][n], 0, 0, 0);
      }
    }
  }
  int m0 = bm*128 + wr*64;
  int n0 = bn*128 + wc*64;
  #pragma unroll
  for(int m=0;m<4;m++){
    #pragma unroll
    for(int n=0;n<4;n++){
      #pragma unroll
      for(int jj=0;jj<4;jj++){
        int row = m0 + m*16 + lhi*4 + jj;
        int col = n0 + n*16 + l16;
        size_t ix = (size_t)row*N + col;
        float val = acc[m][n][jj];
        if constexpr (EPI==0){ ((short*)Cout)[(size_t)z*zC + ix] = f2bf(val); }
        else if constexpr (EPI==3){ float rv = fmaxf(val, 0.f); ((short*)Cout)[ix] = f2bf(rv*rv); }
        else if constexpr (EPI==5){ ((float*)Cout)[(size_t)z*zC + ix] = val; }
        else {
          short* o = (short*)Cout + (size_t)z*zC;
          o[ix] = (z==3) ? f2bf(val/(1.f+expf(-val))) : f2bf(val);
        }
      }
    }
  }
}

// ---------------- 256^2 MFMA GEMM, counted-vmcnt pipeline (T2+T3+T4+T5) -----
// 512 threads = 8 waves (2M x 4N), wave tile 128x64, BK=64, LDS 128 KiB dbuf.
// Raw s_barrier + explicit "s_waitcnt vmcnt(8)" keeps next tile's 8
// global_load_lds in flight across the whole compute (the m218 lever).
// EPI: 3 relu^2 bf16; 5 f32 partial slab; 6 rkvg batch (z==3 silu)
template<int EPI>
__global__ __launch_bounds__(512, 1) void gemm256_kernel(
    const short* __restrict__ A, const short* __restrict__ Bt,
    void* __restrict__ Cout, int M, int N, int Kstride, int Klen,
    long zA, long zB, long zC)
{
  __shared__ __align__(16) short As[2][256*64];   // 64 KiB
  __shared__ __align__(16) short Bs[2][256*64];   // 64 KiB
  int z = blockIdx.z;
  const short* A0 = A + (size_t)z*zA;
  const short* B0 = Bt + (size_t)z*zB;
  int tid = threadIdx.x;
  int w = tid >> 6, lane = tid & 63;
  int l16 = lane & 15, lhi = lane >> 4;
  int wr = w >> 2, wc = w & 3;
  int gx = gridDim.x;
  int nwg = gx*gridDim.y;
  int lin = blockIdx.y*gx + blockIdx.x;
  int wg = (lin & 7)*(nwg >> 3) + (lin >> 3);
  int bn = wg % gx, bm = wg / gx;
  const short* Ab = A0 + (size_t)bm*256*Kstride;
  const short* Bb = B0 + (size_t)bn*256*Kstride;
  int srow_w = w*8 + (lane>>3);    // row within each 64-row stage group
  int scol = lane & 7;
  f32x4 acc[8][4] = {};

  auto STAGE = [&](int kt, int b){
    #pragma unroll
    for(int q=0;q<4;q++){
      int row = q*64 + srow_w;
      int c8 = scol ^ (row & 7);           // inverse-swizzled global source
      int ldsoff = (q*64 + w*8)*64;        // wave-uniform linear dest (shorts)
      load_lds16(Ab + (size_t)row*Kstride + kt + c8*8, &As[b][ldsoff]);
      load_lds16(Bb + (size_t)row*Kstride + kt + c8*8, &Bs[b][ldsoff]);
    }
  };

  int NT = Klen >> 6;
  int cur = 0;
  STAGE(0, 0);                              // 8 calls in flight
  for(int t=0; t<NT; ++t){
    __builtin_amdgcn_sched_barrier(0);
    if(t+1 < NT){
      STAGE((t+1)<<6, cur^1);               // 8 more calls
      asm volatile("s_waitcnt vmcnt(8)" ::: "memory");   // tile t landed, 8 in flight
    } else {
      asm volatile("s_waitcnt vmcnt(0)" ::: "memory");
    }
    __builtin_amdgcn_s_barrier();           // everyone's tile-t data visible
    __builtin_amdgcn_sched_barrier(0);
    const short* Ac = &As[cur][0];
    const short* Bc = &Bs[cur][0];
    short8 bfr[4][2];
    #pragma unroll
    for(int n=0;n<4;n++){
      #pragma unroll
      for(int kk=0;kk<2;kk++){
        int row = wc*64 + n*16 + l16;
        int slot = (kk*4 + lhi) ^ (row & 7);
        bfr[n][kk] = *(const short8*)(Bc + row*64 + slot*8);
      }
    }
    #pragma unroll
    for(int p=0;p<4;p++){
      short8 afr[2][2];
      #pragma unroll
      for(int mm=0;mm<2;mm++){
        #pragma unroll
        for(int kk=0;kk<2;kk++){
          int row = wr*128 + (p*2+mm)*16 + l16;
          int slot = (kk*4 + lhi) ^ (row & 7);
          afr[mm][kk] = *(const short8*)(Ac + row*64 + slot*8);
        }
      }
      __builtin_amdgcn_s_setprio(1);
      #pragma unroll
      for(int mm=0;mm<2;mm++){
        #pragma unroll
        for(int n=0;n<4;n++){
          #pragma unroll
          for(int kk=0;kk<2;kk++)
            acc[p*2+mm][n] = __builtin_amdgcn_mfma_f32_16x16x32_bf16(
                afr[mm][kk], bfr[n][kk], acc[p*2+mm][n], 0, 0, 0);
        }
      }
      __builtin_amdgcn_s_setprio(0);
      __builtin_amdgcn_s_barrier();         // phase lockstep; p==3 releases buf
    }
    cur ^= 1;
  }
  int m0 = bm*256 + wr*128;
  int n0 = bn*256 + wc*64;
  #pragma unroll
  for(int m=0;m<8;m++){
    #pragma unroll
    for(int n=0;n<4;n++){
      #pragma unroll
      for(int jj=0;jj<4;jj++){
        int row = m0 + m*16 + lhi*4 + jj;
        int col = n0 + n*16 + l16;
        size_t ix = (size_t)row*N + col;
        float val = acc[m][n][jj];
        if constexpr (EPI==3){ float rv = fmaxf(val, 0.f); ((short*)Cout)[ix] = f2bf(rv*rv); }
        else if constexpr (EPI==5){ ((float*)Cout)[(size_t)z*zC + ix] = val; }
        else {
          short* o = (short*)Cout + (size_t)z*zC;
          o[ix] = (z==3) ? f2bf(val/(1.f+expf(-val))) : f2bf(val);
        }
      }
    }
  }
}

// ---------------- WKV pass A ----------------
__global__ __launch_bounds__(256) void wkv_chunk_kernel(
    const short* __restrict__ rb, const short* __restrict__ kb,
    const short* __restrict__ vb, const float* __restrict__ db,
    const float* __restrict__ wkv_state, const float* __restrict__ u,
    const int* __restrict__ sp,
    float* __restrict__ yb, short* __restrict__ rtb,
    float* __restrict__ Bc, float* __restrict__ Pc)
{
  int blk = blockIdx.x;
  int ch = blk >> 5;
  int h  = blk & 31;
  int tid = threadIdx.x;
  int a = tid & 3, j = tid >> 2;
  int w = tid >> 6, lane = tid & 63;
  __shared__ float sr[2][64], sk[2][64], suk[2][64], sv[2][64], sd[2][64];
  __shared__ float sp_[64];
  float u_reg = (w==1) ? u[h*64 + lane] : 0.f;
  if(tid < 64) sp_[tid] = 1.f;
  float S[16];
  #pragma unroll
  for(int ii=0;ii<16;ii++) S[ii]=0.f;
  int sp0=sp[0], sp1=sp[1], sp2=sp[2], sp3=sp[3];
  int tbase = ch*CHUNK;
  {
    size_t gb = (size_t)tbase*CC + h*64;
    if(w==0)      sr[0][lane] = bf2f(rb[gb+lane]);
    else if(w==1){ float kv_=bf2f(kb[gb+lane]); sk[0][lane]=kv_; suk[0][lane]=u_reg*kv_; }
    else if(w==2) sv[0][lane] = bf2f(vb[gb+lane]);
    else          sd[0][lane] = db[gb+lane];
  }
  __syncthreads();
  for(int tl=0; tl<CHUNK; ++tl){
    int t = tbase + tl;
    int buf = tl & 1;
    if(tl+1 < CHUNK){
      size_t nb = (size_t)(t+1)*CC + h*64;
      int b2_ = buf^1;
      if(w==0)      sr[b2_][lane] = bf2f(rb[nb+lane]);
      else if(w==1){ float kv_=bf2f(kb[nb+lane]); sk[b2_][lane]=kv_; suk[b2_][lane]=u_reg*kv_; }
      else if(w==2) sv[b2_][lane] = bf2f(vb[nb+lane]);
      else          sd[b2_][lane] = db[nb+lane];
    }
    size_t base = (size_t)t*CC + h*64;
    bool is_start = (sp0==t)|(sp1==t)|(sp2==t)|(sp3==t);
    if(is_start){
      int sid = (sp0<=t)+(sp1<=t)+(sp2<=t)+(sp3<=t) - 1;
      sid = sid<0?0:(sid>3?3:sid);
      const float* wsrc = wkv_state + (((size_t)sid*NH + h)*HSZ + a*16)*HSZ + j;
      #pragma unroll
      for(int ii=0;ii<16;ii++) S[ii] = wsrc[(size_t)ii*HSZ];
      if(tid < 64) sp_[tid] = 0.f;
    }
    float vj = sv[buf][j];
    float yp = 0.f, bp = 0.f;
    #pragma unroll
    for(int ii=0;ii<16;ii++){
      int i = a*16 + ii;
      float ri = sr[buf][i];
      yp += ri * S[ii];
      bp += ri * suk[buf][i];
    }
    yp += __shfl_xor(yp, 1); yp += __shfl_xor(yp, 2);
    bp += __shfl_xor(bp, 1); bp += __shfl_xor(bp, 2);
    if(a == 0) yb[base + j] = yp + bp*vj;
    if(tid < 64){
      rtb[base + tid] = f2bf(sr[buf][tid] * sp_[tid]);
      sp_[tid] *= sd[buf][tid];
    }
    #pragma unroll
    for(int ii=0;ii<16;ii++){
      int i = a*16 + ii;
      S[ii] = sd[buf][i]*S[ii] + sk[buf][i]*vj;
    }
    __syncthreads();
  }
  size_t cb = ((size_t)ch*NH + h)*HSZ*HSZ;
  #pragma unroll
  for(int ii=0;ii<16;ii++) Bc[cb + (size_t)(a*16+ii)*HSZ + j] = S[ii];
  if(tid < 64) Pc[((size_t)ch*NH + h)*HSZ + tid] = sp_[tid];
}

// ---------------- WKV pass B ----------------
__global__ __launch_bounds__(256) void wkv_combine_kernel(
    float* __restrict__ BS, const float* __restrict__ Pc)
{
  int idx = blockIdx.x*256 + threadIdx.x;
  int hi = idx >> 6;
  float s = 0.f;
  for(int cc=0; cc<NCHUNK; ++cc){
    size_t ix = (size_t)cc*(NH*HSZ*HSZ) + idx;
    float b = BS[ix];
    BS[ix] = s;
    s = Pc[cc*(NH*HSZ) + hi]*s + b;
  }
}

// ---------------- WKV pass C ----------------
__global__ __launch_bounds__(256) void wkv_corr_kernel(
    const short* __restrict__ rtb, const float* __restrict__ Sin, float* __restrict__ yb)
{
  int blk = blockIdx.x;
  int ch = blk >> 5, h = blk & 31;
  __shared__ float Ssm[64][64];
  __shared__ float Rsm[32][65];
  int tid = threadIdx.x;
  const float* Sp = Sin + (size_t)(ch*NH + h)*HSZ*HSZ;
  #pragma unroll
  for(int q=0;q<16;q++) ((float*)Ssm)[q*256+tid] = Sp[q*256+tid];
  #pragma unroll
  for(int q=0;q<8;q++){
    int ix = q*256 + tid;
    int tl = ix>>6, i = ix&63;
    Rsm[tl][i] = bf2f(rtb[(size_t)(ch*CHUNK+tl)*CC + h*64 + i]);
  }
  __syncthreads();
  int tl = tid >> 3;
  int jq = tid & 7;
  float acc[8];
  #pragma unroll
  for(int jj=0;jj<8;jj++) acc[jj]=0.f;
  for(int i=0;i<64;i++){
    float rv = Rsm[tl][i];
    #pragma unroll
    for(int jj=0;jj<8;jj++) acc[jj] += rv * Ssm[i][jq*8+jj];
  }
  #pragma unroll
  for(int jj=0;jj<8;jj++)
    yb[(size_t)(ch*CHUNK+tl)*CC + h*64 + jq*8+jj] += acc[jj];
}

// ---------------- GroupNorm(H groups) * g -> bf16 ----------------
__global__ __launch_bounds__(256) void gn_mul_kernel(
    const float* __restrict__ yb, const short* __restrict__ gb,
    const float* __restrict__ gam, const float* __restrict__ bet,
    short* __restrict__ yg)
{
  int t = blockIdx.x, tid = threadIdx.x;
  int w = tid >> 6, lane = tid & 63;
  for(int q=0;q<8;q++){
    int h = q*4 + w;
    int cc = h*64 + lane;
    float val = yb[(size_t)t*CC + cc];
    float s = val, ss = val*val;
    #pragma unroll
    for(int off=1;off<64;off<<=1){ s += __shfl_xor(s,off); ss += __shfl_xor(ss,off); }
    float mu = s*(1.f/64.f);
    float var = ss*(1.f/64.f) - mu*mu;
    float rstd = rsqrtf(var + 6.4e-4f);
    float o = (val-mu)*rstd*gam[cc] + bet[cc];
    yg[(size_t)t*CC + cc] = f2bf(o * bf2f(gb[(size_t)t*CC + cc]));
  }
}

// ---------------- final: out += sigmoid(s0+s1)*(kv0+kv1+kv2+kv3) ----------------
__global__ __launch_bounds__(256) void final_kernel(
    const float* __restrict__ s0, const float* __restrict__ s1,
    const float* __restrict__ kv0, const float* __restrict__ kv1,
    const float* __restrict__ kv2, const float* __restrict__ kv3,
    float* __restrict__ out)
{
  size_t i = ((size_t)blockIdx.x*256 + threadIdx.x)*8;
  #pragma unroll
  for(int j=0;j<8;j++){
    float sv = s0[i+j] + s1[i+j];
    float sig = 1.f/(1.f + expf(-sv));
    out[i+j] = out[i+j] + sig*(kv0[i+j] + kv1[i+j] + kv2[i+j] + kv3[i+j]);
  }
}

extern "C" void kernel_launch(void* const* d_in, const int* in_sizes, int n_in,
                              void* d_out, int out_size, void* d_ws, size_t ws_size,
                              hipStream_t stream)
{
  (void)in_sizes; (void)n_in; (void)out_size;
  const float* x         = (const float*)d_in[0];
  const int*   sp        = (const int*)d_in[1];
  const float* att_state = (const float*)d_in[2];
  const float* wkv_state = (const float*)d_in[3];
  const float* ffn_state = (const float*)d_in[4];
  const float* ln1_g=(const float*)d_in[5],  *ln1_b=(const float*)d_in[6];
  const float* ln2_g=(const float*)d_in[7],  *ln2_b=(const float*)d_in[8];
  const float* maa_x=(const float*)d_in[9],  *maa_w=(const float*)d_in[10], *maa_k=(const float*)d_in[11];
  const float* maa_v=(const float*)d_in[12], *maa_r=(const float*)d_in[13], *maa_g=(const float*)d_in[14];
  const float* tm_w1=(const float*)d_in[15], *tm_w2=(const float*)d_in[16];
  const float* td=(const float*)d_in[17],    *td_w1=(const float*)d_in[18], *td_w2=(const float*)d_in[19];
  const float* u = (const float*)d_in[20];
  const float* Wr=(const float*)d_in[21], *Wk=(const float*)d_in[22], *Wv=(const float*)d_in[23];
  const float* Wg=(const float*)d_in[24], *Wo=(const float*)d_in[25];
  const float* lnx_g=(const float*)d_in[26], *lnx_b=(const float*)d_in[27];
  const float* cm_k=(const float*)d_in[28],  *cm_r=(const float*)d_in[29];
  const float* Wck=(const float*)d_in[30], *Wcv=(const float*)d_in[31], *Wcr=(const float*)d_in[32];

  char* ws = (char*)d_ws;
  const size_t SLOT  = (size_t)TT*CC*4;
  const size_t BSLOT = (size_t)TT*CC*2;
  const size_t WT_SZ = (size_t)4*CC*CC*2;
  const size_t NEED  = 6*SLOT + 10*BSLOT + WT_SZ + (4u<<20);
  if(ws_size < NEED) return;

  float* xa   = (float*)(ws + 0*SLOT);   // S0: xa -> BS(32M over S0-S1) -> cr partial z0
  float* xxb  = (float*)(ws + 1*SLOT);   // S1: xxb -> cr partial z1
  float* zw   = (float*)(ws + 2*SLOT);   // S2: xxx partials -> xf -> Wcv partial z0
  float* decb = (float*)(ws + 3*SLOT);   // S3: dec -> Wcv partial z1
  float* yb   = (float*)(ws + 4*SLOT);   // S4: h1 partials -> y -> Wo part z0 -> Wcv z2
  float* S5   = (float*)(ws + 5*SLOT);   // S5: Wo part z1 -> Wcv z3
  float* BS   = xa;
  float* xxxPart = zw;
  float* h1Part  = yb;
  short* bA   = (short*)(ws + 6*SLOT);
  short* bO   = (short*)(ws + 6*SLOT + 4*BSLOT);
  short* b1 = bO + 0*(TT*CC);
  short* b2 = bO + 1*(TT*CC);
  short* b3 = bO + 2*(TT*CC);
  short* b4 = bO + 3*(TT*CC);
  short* b5 = bO + 4*(TT*CC);
  short* b6 = bO + 5*(TT*CC);
  short* WT = (short*)(ws + 6*SLOT + 10*BSLOT);
  char*  aux = (char*)WT + WT_SZ;
  float* xxxb = (float*)(aux);
  float* h1b  = (float*)(aux + (2u<<20));
  float* Pc   = (float*)(aux + (5u<<19));
  float* xmid = (float*)d_out;

  dim3 B256(256), B512(512);
  const int NTC8 = TT*CC/8/256;

  // ---- Tmix front ----
  ln_kernel<<<TT, B256, 0, stream>>>(x, ln1_g, ln1_b, xa, 1e-5f);
  shift1_kernel<<<TT, B256, 0, stream>>>(xa, att_state, sp, xxb);
  zprep_kernel<<<NTC8, B256, 0, stream>>>(xa, xxb, maa_x, bA);
  transpose_f2bf_kernel<<<dim3(4, CC/64), B256, 0, stream>>>(tm_w1, WT, CC, 160);
  gemm_bt_kernel<5><<<dim3(2, TT/128, 8), B256, 0, stream>>>(bA, WT, xxxPart, TT, 256, CC, 256,
      256, 256, (long)TT*256);
  tanh_reduce_kernel<256,160><<<TT, B256, 0, stream>>>(xxxPart, xxxb);
  mix5_kernel<<<NTC8, B256, 0, stream>>>(xxxb, tm_w2, xa, xxb,
      maa_w, maa_k, maa_v, maa_r, maa_g,
      b5, bA + 1*(TT*CC), bA + 2*(TT*CC), bA, bA + 3*(TT*CC));
  transpose_f2bf_kernel<<<dim3(2, CC/64), B256, 0, stream>>>(td_w1, WT, CC, 64);
  gemm_bt_kernel<5><<<dim3(1, TT/128, 8), B256, 0, stream>>>(b5, WT, h1Part, TT, 128, CC, 256,
      256, 256, (long)TT*128);
  tanh_reduce_kernel<128,64><<<TT/2, B256, 0, stream>>>(h1Part, h1b);
  dec_kernel<<<NTC8, B256, 0, stream>>>(h1b, td_w2, td, decb);

  // ---- r,k,v,g projections: batched 256^2 pipeline GEMM (256 blocks) ----
  WPtr4 w4; w4.w[0]=Wr; w4.w[1]=Wk; w4.w[2]=Wv; w4.w[3]=Wg;
  transpose4_f2bf_kernel<<<dim3(CC/64, CC/64, 4), B256, 0, stream>>>(w4, WT);
  gemm256_kernel<6><<<dim3(CC/256, TT/256, 4), B512, 0, stream>>>(bA, WT, b1, TT, CC, CC, CC,
      (long)TT*CC, (long)CC*CC, (long)TT*CC);

  // ---- WKV chunked scan ----
  wkv_chunk_kernel<<<NCHUNK*NH, B256, 0, stream>>>(b1, b2, b3, decb, wkv_state, u, sp,
                                                   yb, b5, BS, Pc);
  wkv_combine_kernel<<<NH*HSZ*HSZ/256, B256, 0, stream>>>(BS, Pc);
  wkv_corr_kernel<<<NCHUNK*NH, B256, 0, stream>>>(b5, BS, yb);
  gn_mul_kernel<<<TT, B256, 0, stream>>>(yb, b4, lnx_g, lnx_b, b6);

  // ---- output projection (128^2 split-K=2) + fused residual+LN2 ----
  transpose_f2bf_kernel<<<dim3(CC/64, CC/64), B256, 0, stream>>>(Wo, WT, CC, CC);
  gemm_bt_kernel<5><<<dim3(CC/128, TT/128, 2), B256, 0, stream>>>(b6, WT, yb, TT, CC, CC, 1024,
      1024, 1024, (long)TT*CC);
  ln2_fused_kernel<<<TT, B256, 0, stream>>>(yb, S5, x, ln2_g, ln2_b, xmid, zw, 1e-5f);

  // ---- CMix ----
  shift2_kernel<<<TT, B256, 0, stream>>>(zw, ffn_state, sp, cm_k, cm_r, bA, bA + 1*(TT*CC));
  transpose_f2bf_kernel<<<dim3(FFND/64, CC/64), B256, 0, stream>>>(Wck, WT, CC, FFND);
  gemm256_kernel<3><<<dim3(FFND/256, TT/256, 1), B512, 0, stream>>>(bA, WT, b1, TT, FFND, CC, CC,
      0, 0, 0);
  transpose_f2bf_kernel<<<dim3(CC/64, FFND/64), B256, 0, stream>>>(Wcv, WT, FFND, CC);
  gemm256_kernel<5><<<dim3(CC/256, TT/256, 4), B512, 0, stream>>>(b1, WT, zw, TT, CC, FFND, 1792,
      1792, 1792, (long)TT*CC);
  transpose_f2bf_kernel<<<dim3(CC/64, CC/64), B256, 0, stream>>>(Wcr, WT, CC, CC);
  gemm_bt_kernel<5><<<dim3(CC/128, TT/128, 2), B256, 0, stream>>>(bA + 1*(TT*CC), WT, xa, TT, CC, CC, 1024,
      1024, 1024, (long)TT*CC);
  final_kernel<<<NTC8, B256, 0, stream>>>(xa, xxb, zw, decb, yb, S5, xmid);
}

// Round 8
// 764.488 us; speedup vs baseline: 2.5345x; 1.0365x over previous
//
#include <hip/hip_runtime.h>
#include <stdint.h>

// RWKV6 block: B=1, T=2048, C=2048, H=32, HS=64, FFN=7168, NS=4
// Workspace: 6*16M (f32) + 4*8M (bA) + 6*8M (bO) + 32M (WT) + 4M aux = 212 MiB.

#define TT 2048
#define CC 2048
#define NH 32
#define HSZ 64
#define FFND 7168
#define CHUNK 32
#define NCHUNK 64

typedef __attribute__((ext_vector_type(8))) short short8;
typedef __attribute__((ext_vector_type(4))) float f32x4;

__device__ __forceinline__ float bf2f(short s){
  return __uint_as_float(((uint32_t)(uint16_t)s) << 16);
}
__device__ __forceinline__ short f2bf(float f){
  uint32_t u = __float_as_uint(f);
  u = u + 0x7fffu + ((u >> 16) & 1u);
  return (short)(u >> 16);
}

// ---------------- LayerNorm (row over C) ----------------
__global__ __launch_bounds__(256) void ln_kernel(
    const float* __restrict__ xin, const float* __restrict__ gam,
    const float* __restrict__ bet, float* __restrict__ out, float eps)
{
  int t = blockIdx.x, tid = threadIdx.x;
  const float* row = xin + (size_t)t*CC;
  float4 v0 = *(const float4*)(row + tid*8);
  float4 v1 = *(const float4*)(row + tid*8 + 4);
  float s  = v0.x+v0.y+v0.z+v0.w + v1.x+v1.y+v1.z+v1.w;
  float ss = v0.x*v0.x+v0.y*v0.y+v0.z*v0.z+v0.w*v0.w
           + v1.x*v1.x+v1.y*v1.y+v1.z*v1.z+v1.w*v1.w;
  #pragma unroll
  for(int off=1; off<64; off<<=1){ s += __shfl_xor(s,off); ss += __shfl_xor(ss,off); }
  __shared__ float sm[8];
  int w = tid>>6;
  if((tid&63)==0){ sm[w]=s; sm[4+w]=ss; }
  __syncthreads();
  s = sm[0]+sm[1]+sm[2]+sm[3]; ss = sm[4]+sm[5]+sm[6]+sm[7];
  float mean = s * (1.f/CC);
  float var  = ss * (1.f/CC) - mean*mean;
  float rstd = rsqrtf(var + eps);
  float* orow = out + (size_t)t*CC;
  int c = tid*8;
  float vv[8] = {v0.x,v0.y,v0.z,v0.w,v1.x,v1.y,v1.z,v1.w};
  #pragma unroll
  for(int j=0;j<8;j++) orow[c+j] = (vv[j]-mean)*rstd*gam[c+j] + bet[c+j];
}

// ---------------- fused: xmid = p0+p1+x ; zw = LN(xmid) ----------------
__global__ __launch_bounds__(256) void ln2_fused_kernel(
    const float* __restrict__ p0, const float* __restrict__ p1,
    const float* __restrict__ xres, const float* __restrict__ gam,
    const float* __restrict__ bet, float* __restrict__ xsum,
    float* __restrict__ lnout, float eps)
{
  int t = blockIdx.x, tid = threadIdx.x;
  size_t base = (size_t)t*CC + tid*8;
  float vv[8];
  float s = 0.f, ss = 0.f;
  #pragma unroll
  for(int j=0;j<8;j++){
    float v = p0[base+j] + p1[base+j] + xres[base+j];
    vv[j] = v; s += v; ss += v*v;
    xsum[base+j] = v;
  }
  #pragma unroll
  for(int off=1; off<64; off<<=1){ s += __shfl_xor(s,off); ss += __shfl_xor(ss,off); }
  __shared__ float sm[8];
  int w = tid>>6;
  if((tid&63)==0){ sm[w]=s; sm[4+w]=ss; }
  __syncthreads();
  s = sm[0]+sm[1]+sm[2]+sm[3]; ss = sm[4]+sm[5]+sm[6]+sm[7];
  float mean = s * (1.f/CC);
  float var  = ss * (1.f/CC) - mean*mean;
  float rstd = rsqrtf(var + eps);
  int c = tid*8;
  #pragma unroll
  for(int j=0;j<8;j++) lnout[base+j] = (vv[j]-mean)*rstd*gam[c+j] + bet[c+j];
}

// ---------------- token shift (attention): xx = sh - xa (f32 out) ----------------
__global__ __launch_bounds__(256) void shift1_kernel(
    const float* __restrict__ xa, const float* __restrict__ st,
    const int* __restrict__ sp, float* __restrict__ xxb)
{
  int t = blockIdx.x, tid = threadIdx.x;
  int sp0=sp[0], sp1=sp[1], sp2=sp[2], sp3=sp[3];
  bool is_start = (sp0==t)|(sp1==t)|(sp2==t)|(sp3==t);
  int sid = (sp0<=t)+(sp1<=t)+(sp2<=t)+(sp3<=t) - 1;
  sid = sid<0?0:(sid>3?3:sid);
  int c = tid*8;
  const float* src = is_start ? (st + (size_t)sid*CC + c)
                   : (t>0 ? xa + (size_t)(t-1)*CC + c : nullptr);
  const float* cur = xa + (size_t)t*CC + c;
  float* o = xxb + (size_t)t*CC + c;
  #pragma unroll
  for(int jj=0;jj<8;jj++){
    float sh = src ? src[jj] : 0.f;
    o[jj] = sh - cur[jj];
  }
}

// ---------------- token shift (ffn): xk2/xr2 fused, bf16 out ----------------
__global__ __launch_bounds__(256) void shift2_kernel(
    const float* __restrict__ xf, const float* __restrict__ st,
    const int* __restrict__ sp, const float* __restrict__ cmk,
    const float* __restrict__ cmr, short* __restrict__ xk2, short* __restrict__ xr2)
{
  int t = blockIdx.x, tid = threadIdx.x;
  int sp0=sp[0], sp1=sp[1], sp2=sp[2], sp3=sp[3];
  bool is_start = (sp0==t)|(sp1==t)|(sp2==t)|(sp3==t);
  int sid = (sp0<=t)+(sp1<=t)+(sp2<=t)+(sp3<=t) - 1;
  sid = sid<0?0:(sid>3?3:sid);
  int c = tid*8;
  const float* src = is_start ? (st + (size_t)sid*CC + c)
                   : (t>0 ? xf + (size_t)(t-1)*CC + c : nullptr);
  const float* cur = xf + (size_t)t*CC + c;
  size_t ix = (size_t)t*CC + c;
  #pragma unroll
  for(int jj=0;jj<8;jj++){
    float xfv = cur[jj];
    float sh = src ? src[jj] : 0.f;
    float d = sh - xfv;
    xk2[ix+jj] = f2bf(xfv + d*cmk[c+jj]);
    xr2[ix+jj] = f2bf(xfv + d*cmr[c+jj]);
  }
}

// ---------------- z = xa + xx*maa_x -> bf16 ----------------
__global__ __launch_bounds__(256) void zprep_kernel(const float* __restrict__ xa,
   const float* __restrict__ xx, const float* __restrict__ maa, short* __restrict__ z)
{
  size_t i = ((size_t)blockIdx.x*256 + threadIdx.x)*8;
  int c = (int)(i & (CC-1));
  #pragma unroll
  for(int j=0;j<8;j++) z[i+j] = f2bf(xa[i+j] + xx[i+j]*maa[c+j]);
}

// ---------------- fused 5-way maa mix -> bf16 outputs ----------------
__global__ __launch_bounds__(256) void mix5_kernel(
    const float* __restrict__ xxxb, const float* __restrict__ w2,
    const float* __restrict__ xa, const float* __restrict__ xxv,
    const float* __restrict__ mw, const float* __restrict__ mk,
    const float* __restrict__ mv, const float* __restrict__ mr,
    const float* __restrict__ mg,
    short* __restrict__ ow, short* __restrict__ ok, short* __restrict__ ov,
    short* __restrict__ orr, short* __restrict__ og)
{
  int g = blockIdx.x*256 + threadIdx.x;
  int c = g & (CC-1);
  int t0 = (g >> 11) * 8;
  float acc[5][8];
  #pragma unroll
  for(int s=0;s<5;s++)
    #pragma unroll
    for(int tt=0;tt<8;tt++) acc[s][tt]=0.f;
  #pragma unroll
  for(int s=0;s<5;s++){
    for(int e=0;e<32;e++){
      float wv = w2[(size_t)(s*32+e)*CC + c];
      #pragma unroll
      for(int tt=0;tt<8;tt++)
        acc[s][tt] += xxxb[(size_t)(t0+tt)*160 + s*32 + e] * wv;
    }
  }
  float vmw=mw[c], vmk=mk[c], vmv=mv[c], vmr=mr[c], vmg=mg[c];
  #pragma unroll
  for(int tt=0;tt<8;tt++){
    size_t ix = (size_t)(t0+tt)*CC + c;
    float av = xa[ix], xv = xxv[ix];
    ow[ix]  = f2bf(av + xv*(vmw + acc[0][tt]));
    ok[ix]  = f2bf(av + xv*(vmk + acc[1][tt]));
    ov[ix]  = f2bf(av + xv*(vmv + acc[2][tt]));
    orr[ix] = f2bf(av + xv*(vmr + acc[3][tt]));
    og[ix]  = f2bf(av + xv*(vmg + acc[4][tt]));
  }
}

// ---------------- dec = exp(-exp(td + h1 @ td_w2)) (f32) ----------------
__global__ __launch_bounds__(256) void dec_kernel(
    const float* __restrict__ h1b, const float* __restrict__ tw2,
    const float* __restrict__ td, float* __restrict__ out)
{
  int g = blockIdx.x*256 + threadIdx.x;
  int c = g & (CC-1);
  int t0 = (g >> 11)*8;
  float acc[8] = {0,0,0,0,0,0,0,0};
  for(int e=0;e<64;e++){
    float wv = tw2[(size_t)e*CC + c];
    #pragma unroll
    for(int tt=0;tt<8;tt++) acc[tt] += h1b[(size_t)(t0+tt)*64 + e]*wv;
  }
  float tdc = td[c];
  #pragma unroll
  for(int tt=0;tt<8;tt++)
    out[(size_t)(t0+tt)*CC + c] = expf(-expf(tdc + acc[tt]));
}

// ---------------- tanh split-K reduce ----------------
template<int N, int NK>
__global__ __launch_bounds__(256) void tanh_reduce_kernel(
    const float* __restrict__ part, float* __restrict__ out)
{
  int idx = blockIdx.x*256 + threadIdx.x;
  int col = idx & (N-1);
  int row = idx >> (N==256 ? 8 : 7);
  float s = 0.f;
  #pragma unroll
  for(int z=0;z<8;z++) s += part[(size_t)z*TT*N + idx];
  if(col < NK) out[(size_t)row*NK + col] = tanhf(s);
}

// ---------------- W[K,N] f32 -> Wt[NPAD,K] bf16 ----------------
__global__ __launch_bounds__(256) void transpose_f2bf_kernel(
    const float* __restrict__ W, short* __restrict__ Wt, int K, int N)
{
  __shared__ float tile[64][65];
  int n0 = blockIdx.x*64, k0 = blockIdx.y*64;
  int tid = threadIdx.x;
  #pragma unroll
  for(int q=0;q<16;q++){
    int ix = q*256 + tid;
    int r = ix >> 6, cc2 = ix & 63;
    tile[r][cc2] = (n0 + cc2 < N) ? W[(size_t)(k0+r)*N + n0 + cc2] : 0.f;
  }
  __syncthreads();
  #pragma unroll
  for(int q=0;q<16;q++){
    int ix = q*256 + tid;
    int r = ix >> 6, cc2 = ix & 63;
    Wt[(size_t)(n0+r)*K + k0 + cc2] = f2bf(tile[cc2][r]);
  }
}

struct WPtr4 { const float* w[4]; };
__global__ __launch_bounds__(256) void transpose4_f2bf_kernel(
    WPtr4 ws4, short* __restrict__ Wt)
{
  __shared__ float tile[64][65];
  int z = blockIdx.z;
  const float* W = ws4.w[z];
  short* dst = Wt + (size_t)z*CC*CC;
  int n0 = blockIdx.x*64, k0 = blockIdx.y*64;
  int tid = threadIdx.x;
  #pragma unroll
  for(int q=0;q<16;q++){
    int ix = q*256 + tid;
    int r = ix >> 6, cc2 = ix & 63;
    tile[r][cc2] = W[(size_t)(k0+r)*CC + n0 + cc2];
  }
  __syncthreads();
  #pragma unroll
  for(int q=0;q<16;q++){
    int ix = q*256 + tid;
    int r = ix >> 6, cc2 = ix & 63;
    dst[(size_t)(n0+r)*CC + k0 + cc2] = f2bf(tile[cc2][r]);
  }
}

__device__ __forceinline__ void load_lds16(const void* g, void* l){
  __builtin_amdgcn_global_load_lds(
      (const __attribute__((address_space(1))) uint32_t*)g,
      (__attribute__((address_space(3))) uint32_t*)l, 16, 0, 0);
}

// ---------------- 128^2 MFMA GEMM (m97-structure + swizzle) ----------------
// EPI: 0 bf16; 3 relu^2 bf16; 5 f32 partial slab; 6 rkvg batch
template<int EPI>
__global__ __launch_bounds__(256) void gemm_bt_kernel(
    const short* __restrict__ A, const short* __restrict__ Bt,
    void* __restrict__ Cout, int M, int N, int Kstride, int Klen,
    long zA, long zB, long zC)
{
  __shared__ __align__(16) short As[128*64];
  __shared__ __align__(16) short Bs[128*64];
  int z = blockIdx.z;
  const short* A0 = A + (size_t)z*zA;
  const short* B0 = Bt + (size_t)z*zB;
  int tid = threadIdx.x;
  int w = tid >> 6, lane = tid & 63;
  int l16 = lane & 15, lhi = lane >> 4;
  int wr = w >> 1, wc = w & 1;
  int gx = gridDim.x;
  int nwg = gx*gridDim.y;
  int lin = blockIdx.y*gx + blockIdx.x;
  int wg = (lin & 7)*(nwg >> 3) + (lin >> 3);
  int bn = wg % gx, bm = wg / gx;
  const short* Ab = A0 + (size_t)bm*128*Kstride;
  const short* Bb = B0 + (size_t)bn*128*Kstride;
  int srow = w*8 + (lane>>3);
  int scol = lane & 7;
  f32x4 acc[4][4] = {};
  for(int kt=0; kt<Klen; kt+=64){
    __syncthreads();
    #pragma unroll
    for(int q=0;q<4;q++){
      int row = q*32 + srow;
      int c8 = scol ^ (row & 7);
      int ldsoff = (q*256 + w*64)*8;
      load_lds16(Ab + (size_t)row*Kstride + kt + c8*8, As + ldsoff);
      load_lds16(Bb + (size_t)row*Kstride + kt + c8*8, Bs + ldsoff);
    }
    __syncthreads();
    #pragma unroll
    for(int kk=0;kk<2;kk++){
      short8 af[4], bf[4];
      #pragma unroll
      for(int m=0;m<4;m++){
        int row = wr*64 + m*16 + l16;
        int slot = (kk*4 + lhi) ^ (row & 7);
        af[m] = *(const short8*)(As + row*64 + slot*8);
      }
      #pragma unroll
      for(int n=0;n<4;n++){
        int row = wc*64 + n*16 + l16;
        int slot = (kk*4 + lhi) ^ (row & 7);
        bf[n] = *(const short8*)(Bs + row*64 + slot*8);
      }
      #pragma unroll
      for(int m=0;m<4;m++){
        #pragma unroll
        for(int n=0;n<4;n++)
          acc[m][n] = __builtin_amdgcn_mfma_f32_16x16x32_bf16(af[m], bf[n], acc[m][n], 0, 0, 0);
      }
    }
  }
  int m0 = bm*128 + wr*64;
  int n0 = bn*128 + wc*64;
  #pragma unroll
  for(int m=0;m<4;m++){
    #pragma unroll
    for(int n=0;n<4;n++){
      #pragma unroll
      for(int jj=0;jj<4;jj++){
        int row = m0 + m*16 + lhi*4 + jj;
        int col = n0 + n*16 + l16;
        size_t ix = (size_t)row*N + col;
        float val = acc[m][n][jj];
        if constexpr (EPI==0){ ((short*)Cout)[(size_t)z*zC + ix] = f2bf(val); }
        else if constexpr (EPI==3){ float rv = fmaxf(val, 0.f); ((short*)Cout)[ix] = f2bf(rv*rv); }
        else if constexpr (EPI==5){ ((float*)Cout)[(size_t)z*zC + ix] = val; }
        else {
          short* o = (short*)Cout + (size_t)z*zC;
          o[ix] = (z==3) ? f2bf(val/(1.f+expf(-val))) : f2bf(val);
        }
      }
    }
  }
}

// ---------------- 256^2 MFMA GEMM, fine 8-phase counted-vmcnt schedule ------
// 512 thr = 8 waves (2M x 4N), wave tile 128x64, BK=64, 128 KiB LDS.
// Even K-tiles live in buf0, odd in buf1. Per iteration (2 K-tiles):
//   p1,p2 stage A(2i+1); p3,p4 stage B(2i+2); p5,p6 stage A(2i+2);
//   p7,p8 stage B(2i+3). Each phase: {ds_read quad | 1 half stage | barrier |
//   lgkmcnt(0) | 16 MFMA | barrier}. vmcnt(4) at p4 and p8 only (retires
//   exactly the halves the next compute needs; newest 2 halves stay in flight).
// EPI: 3 relu^2 bf16; 5 f32 partial slab; 6 rkvg batch (z==3 silu)
template<int EPI>
__global__ __launch_bounds__(512, 1) void gemm256_kernel(
    const short* __restrict__ A, const short* __restrict__ Bt,
    void* __restrict__ Cout, int M, int N, int Kstride, int Klen,
    long zA, long zB, long zC)
{
  __shared__ __align__(16) short As[2][256*64];
  __shared__ __align__(16) short Bs[2][256*64];
  int z = blockIdx.z;
  const short* A0 = A + (size_t)z*zA;
  const short* B0 = Bt + (size_t)z*zB;
  int tid = threadIdx.x;
  int w = tid >> 6, lane = tid & 63;
  int l16 = lane & 15, lhi = lane >> 4;
  int wr = w >> 2, wc = w & 3;
  int gx = gridDim.x;
  int nwg = gx*gridDim.y;
  int lin = blockIdx.y*gx + blockIdx.x;
  int wg = (lin & 7)*(nwg >> 3) + (lin >> 3);
  int bn = wg % gx, bm = wg / gx;
  const short* Ab = A0 + (size_t)bm*256*Kstride;
  const short* Bb = B0 + (size_t)bn*256*Kstride;
  int srow_w = w*8 + (lane>>3);
  int scol = lane & 7;
  f32x4 acc[8][4] = {};

  // stage one half (128 rows) of a tile: 2 global_load_lds per thread
  auto STG = [&](const short* src, short* dst, int half, int kt){
    #pragma unroll
    for(int q=0;q<2;q++){
      int row = half*128 + q*64 + srow_w;
      int c8 = scol ^ (row & 7);
      load_lds16(src + (size_t)row*Kstride + kt + c8*8,
                 dst + (half*128 + q*64 + w*8)*64);
    }
  };
  auto DSA = [&](const short* Ac, int p, short8 afr[2][2]){
    #pragma unroll
    for(int mm=0;mm<2;mm++)
      #pragma unroll
      for(int kk=0;kk<2;kk++){
        int row = wr*128 + (p*2+mm)*16 + l16;
        int slot = (kk*4 + lhi) ^ (row & 7);
        afr[mm][kk] = *(const short8*)(Ac + row*64 + slot*8);
      }
  };
  auto DSB = [&](const short* Bc, short8 bfr[4][2]){
    #pragma unroll
    for(int n=0;n<4;n++)
      #pragma unroll
      for(int kk=0;kk<2;kk++){
        int row = wc*64 + n*16 + l16;
        int slot = (kk*4 + lhi) ^ (row & 7);
        bfr[n][kk] = *(const short8*)(Bc + row*64 + slot*8);
      }
  };
  auto MM = [&](int p, short8 afr[2][2], short8 bfr[4][2]){
    __builtin_amdgcn_s_setprio(1);
    #pragma unroll
    for(int mm=0;mm<2;mm++)
      #pragma unroll
      for(int n=0;n<4;n++)
        #pragma unroll
        for(int kk=0;kk<2;kk++)
          acc[p*2+mm][n] = __builtin_amdgcn_mfma_f32_16x16x32_bf16(
              afr[mm][kk], bfr[n][kk], acc[p*2+mm][n], 0, 0, 0);
    __builtin_amdgcn_s_setprio(0);
  };
  #define PH_SYNC() do{ __builtin_amdgcn_s_barrier(); \
      asm volatile("s_waitcnt lgkmcnt(0)" ::: "memory"); \
      __builtin_amdgcn_sched_barrier(0); }while(0)
  #define PH_END() do{ __builtin_amdgcn_s_barrier(); \
      __builtin_amdgcn_sched_barrier(0); }while(0)

  int NT = Klen >> 6;       // even for all call sites
  int niter = NT >> 1;
  // prologue: A(0),B(0) -> buf0 ; B(1) -> buf1  (12 loads; retire first 8)
  STG(Ab, &As[0][0], 0, 0); STG(Ab, &As[0][0], 1, 0);
  STG(Bb, &Bs[0][0], 0, 0); STG(Bb, &Bs[0][0], 1, 0);
  STG(Bb, &Bs[1][0], 0, 64); STG(Bb, &Bs[1][0], 1, 64);
  asm volatile("s_waitcnt vmcnt(4)" ::: "memory");
  __builtin_amdgcn_s_barrier();
  __builtin_amdgcn_sched_barrier(0);

  for(int i=0;i<niter;++i){
    int kt_o  = (2*i+1) << 6;
    int kt_e2 = (2*i+2) << 6;
    int kt_o2 = (2*i+3) << 6;
    bool st = (i+1 < niter);
    short8 bfr[4][2], afr[2][2];
    // ---- phase 1: B0 frags + A0 q0 | stage A-odd lo ----
    DSB(&Bs[0][0], bfr);
    DSA(&As[0][0], 0, afr);
    STG(Ab, &As[1][0], 0, kt_o);
    PH_SYNC(); MM(0, afr, bfr); PH_END();
    // ---- phase 2: A0 q1 | stage A-odd hi ----
    DSA(&As[0][0], 1, afr);
    STG(Ab, &As[1][0], 1, kt_o);
    PH_SYNC(); MM(1, afr, bfr); PH_END();
    // ---- phase 3: A0 q2 | stage B-even' lo ----
    DSA(&As[0][0], 2, afr);
    if(st) STG(Bb, &Bs[0][0], 0, kt_e2);
    PH_SYNC(); MM(2, afr, bfr); PH_END();
    // ---- phase 4: A0 q3 | stage B-even' hi | vmcnt gate ----
    DSA(&As[0][0], 3, afr);
    if(st) STG(Bb, &Bs[0][0], 1, kt_e2);
    asm volatile("s_waitcnt vmcnt(4)" ::: "memory");
    PH_SYNC(); MM(3, afr, bfr); PH_END();
    // ---- phase 5: B1 frags + A1 q0 | stage A-even' lo ----
    DSB(&Bs[1][0], bfr);
    DSA(&As[1][0], 0, afr);
    if(st) STG(Ab, &As[0][0], 0, kt_e2);
    PH_SYNC(); MM(0, afr, bfr); PH_END();
    // ---- phase 6: A1 q1 | stage A-even' hi ----
    DSA(&As[1][0], 1, afr);
    if(st) STG(Ab, &As[0][0], 1, kt_e2);
    PH_SYNC(); MM(1, afr, bfr); PH_END();
    // ---- phase 7: A1 q2 | stage B-odd' lo ----
    DSA(&As[1][0], 2, afr);
    if(st) STG(Bb, &Bs[1][0], 0, kt_o2);
    PH_SYNC(); MM(2, afr, bfr); PH_END();
    // ---- phase 8: A1 q3 | stage B-odd' hi | vmcnt gate ----
    DSA(&As[1][0], 3, afr);
    if(st) STG(Bb, &Bs[1][0], 1, kt_o2);
    asm volatile("s_waitcnt vmcnt(4)" ::: "memory");
    PH_SYNC(); MM(3, afr, bfr); PH_END();
  }
  #undef PH_SYNC
  #undef PH_END

  int m0 = bm*256 + wr*128;
  int n0 = bn*256 + wc*64;
  #pragma unroll
  for(int m=0;m<8;m++){
    #pragma unroll
    for(int n=0;n<4;n++){
      #pragma unroll
      for(int jj=0;jj<4;jj++){
        int row = m0 + m*16 + lhi*4 + jj;
        int col = n0 + n*16 + l16;
        size_t ix = (size_t)row*N + col;
        float val = acc[m][n][jj];
        if constexpr (EPI==3){ float rv = fmaxf(val, 0.f); ((short*)Cout)[ix] = f2bf(rv*rv); }
        else if constexpr (EPI==5){ ((float*)Cout)[(size_t)z*zC + ix] = val; }
        else {
          short* o = (short*)Cout + (size_t)z*zC;
          o[ix] = (z==3) ? f2bf(val/(1.f+expf(-val))) : f2bf(val);
        }
      }
    }
  }
}

// ---------------- WKV pass A ----------------
__global__ __launch_bounds__(256) void wkv_chunk_kernel(
    const short* __restrict__ rb, const short* __restrict__ kb,
    const short* __restrict__ vb, const float* __restrict__ db,
    const float* __restrict__ wkv_state, const float* __restrict__ u,
    const int* __restrict__ sp,
    float* __restrict__ yb, short* __restrict__ rtb,
    float* __restrict__ Bc, float* __restrict__ Pc)
{
  int blk = blockIdx.x;
  int ch = blk >> 5;
  int h  = blk & 31;
  int tid = threadIdx.x;
  int a = tid & 3, j = tid >> 2;
  int w = tid >> 6, lane = tid & 63;
  __shared__ float sr[2][64], sk[2][64], suk[2][64], sv[2][64], sd[2][64];
  __shared__ float sp_[64];
  float u_reg = (w==1) ? u[h*64 + lane] : 0.f;
  if(tid < 64) sp_[tid] = 1.f;
  float S[16];
  #pragma unroll
  for(int ii=0;ii<16;ii++) S[ii]=0.f;
  int sp0=sp[0], sp1=sp[1], sp2=sp[2], sp3=sp[3];
  int tbase = ch*CHUNK;
  {
    size_t gb = (size_t)tbase*CC + h*64;
    if(w==0)      sr[0][lane] = bf2f(rb[gb+lane]);
    else if(w==1){ float kv_=bf2f(kb[gb+lane]); sk[0][lane]=kv_; suk[0][lane]=u_reg*kv_; }
    else if(w==2) sv[0][lane] = bf2f(vb[gb+lane]);
    else          sd[0][lane] = db[gb+lane];
  }
  __syncthreads();
  for(int tl=0; tl<CHUNK; ++tl){
    int t = tbase + tl;
    int buf = tl & 1;
    if(tl+1 < CHUNK){
      size_t nb = (size_t)(t+1)*CC + h*64;
      int b2_ = buf^1;
      if(w==0)      sr[b2_][lane] = bf2f(rb[nb+lane]);
      else if(w==1){ float kv_=bf2f(kb[nb+lane]); sk[b2_][lane]=kv_; suk[b2_][lane]=u_reg*kv_; }
      else if(w==2) sv[b2_][lane] = bf2f(vb[nb+lane]);
      else          sd[b2_][lane] = db[nb+lane];
    }
    size_t base = (size_t)t*CC + h*64;
    bool is_start = (sp0==t)|(sp1==t)|(sp2==t)|(sp3==t);
    if(is_start){
      int sid = (sp0<=t)+(sp1<=t)+(sp2<=t)+(sp3<=t) - 1;
      sid = sid<0?0:(sid>3?3:sid);
      const float* wsrc = wkv_state + (((size_t)sid*NH + h)*HSZ + a*16)*HSZ + j;
      #pragma unroll
      for(int ii=0;ii<16;ii++) S[ii] = wsrc[(size_t)ii*HSZ];
      if(tid < 64) sp_[tid] = 0.f;
    }
    float vj = sv[buf][j];
    float yp = 0.f, bp = 0.f;
    #pragma unroll
    for(int ii=0;ii<16;ii++){
      int i = a*16 + ii;
      float ri = sr[buf][i];
      yp += ri * S[ii];
      bp += ri * suk[buf][i];
    }
    yp += __shfl_xor(yp, 1); yp += __shfl_xor(yp, 2);
    bp += __shfl_xor(bp, 1); bp += __shfl_xor(bp, 2);
    if(a == 0) yb[base + j] = yp + bp*vj;
    if(tid < 64){
      rtb[base + tid] = f2bf(sr[buf][tid] * sp_[tid]);
      sp_[tid] *= sd[buf][tid];
    }
    #pragma unroll
    for(int ii=0;ii<16;ii++){
      int i = a*16 + ii;
      S[ii] = sd[buf][i]*S[ii] + sk[buf][i]*vj;
    }
    __syncthreads();
  }
  size_t cb = ((size_t)ch*NH + h)*HSZ*HSZ;
  #pragma unroll
  for(int ii=0;ii<16;ii++) Bc[cb + (size_t)(a*16+ii)*HSZ + j] = S[ii];
  if(tid < 64) Pc[((size_t)ch*NH + h)*HSZ + tid] = sp_[tid];
}

// ---------------- WKV pass B ----------------
__global__ __launch_bounds__(256) void wkv_combine_kernel(
    float* __restrict__ BS, const float* __restrict__ Pc)
{
  int idx = blockIdx.x*256 + threadIdx.x;
  int hi = idx >> 6;
  float s = 0.f;
  for(int cc=0; cc<NCHUNK; ++cc){
    size_t ix = (size_t)cc*(NH*HSZ*HSZ) + idx;
    float b = BS[ix];
    BS[ix] = s;
    s = Pc[cc*(NH*HSZ) + hi]*s + b;
  }
}

// ---------------- WKV pass C ----------------
__global__ __launch_bounds__(256) void wkv_corr_kernel(
    const short* __restrict__ rtb, const float* __restrict__ Sin, float* __restrict__ yb)
{
  int blk = blockIdx.x;
  int ch = blk >> 5, h = blk & 31;
  __shared__ float Ssm[64][64];
  __shared__ float Rsm[32][65];
  int tid = threadIdx.x;
  const float* Sp = Sin + (size_t)(ch*NH + h)*HSZ*HSZ;
  #pragma unroll
  for(int q=0;q<16;q++) ((float*)Ssm)[q*256+tid] = Sp[q*256+tid];
  #pragma unroll
  for(int q=0;q<8;q++){
    int ix = q*256 + tid;
    int tl = ix>>6, i = ix&63;
    Rsm[tl][i] = bf2f(rtb[(size_t)(ch*CHUNK+tl)*CC + h*64 + i]);
  }
  __syncthreads();
  int tl = tid >> 3;
  int jq = tid & 7;
  float acc[8];
  #pragma unroll
  for(int jj=0;jj<8;jj++) acc[jj]=0.f;
  for(int i=0;i<64;i++){
    float rv = Rsm[tl][i];
    #pragma unroll
    for(int jj=0;jj<8;jj++) acc[jj] += rv * Ssm[i][jq*8+jj];
  }
  #pragma unroll
  for(int jj=0;jj<8;jj++)
    yb[(size_t)(ch*CHUNK+tl)*CC + h*64 + jq*8+jj] += acc[jj];
}

// ---------------- GroupNorm(H groups) * g -> bf16 ----------------
__global__ __launch_bounds__(256) void gn_mul_kernel(
    const float* __restrict__ yb, const short* __restrict__ gb,
    const float* __restrict__ gam, const float* __restrict__ bet,
    short* __restrict__ yg)
{
  int t = blockIdx.x, tid = threadIdx.x;
  int w = tid >> 6, lane = tid & 63;
  for(int q=0;q<8;q++){
    int h = q*4 + w;
    int cc = h*64 + lane;
    float val = yb[(size_t)t*CC + cc];
    float s = val, ss = val*val;
    #pragma unroll
    for(int off=1;off<64;off<<=1){ s += __shfl_xor(s,off); ss += __shfl_xor(ss,off); }
    float mu = s*(1.f/64.f);
    float var = ss*(1.f/64.f) - mu*mu;
    float rstd = rsqrtf(var + 6.4e-4f);
    float o = (val-mu)*rstd*gam[cc] + bet[cc];
    yg[(size_t)t*CC + cc] = f2bf(o * bf2f(gb[(size_t)t*CC + cc]));
  }
}

// ---------------- final: out += sigmoid(s0+s1)*(kv0+kv1+kv2+kv3) ----------------
__global__ __launch_bounds__(256) void final_kernel(
    const float* __restrict__ s0, const float* __restrict__ s1,
    const float* __restrict__ kv0, const float* __restrict__ kv1,
    const float* __restrict__ kv2, const float* __restrict__ kv3,
    float* __restrict__ out)
{
  size_t i = ((size_t)blockIdx.x*256 + threadIdx.x)*8;
  #pragma unroll
  for(int j=0;j<8;j++){
    float sv = s0[i+j] + s1[i+j];
    float sig = 1.f/(1.f + expf(-sv));
    out[i+j] = out[i+j] + sig*(kv0[i+j] + kv1[i+j] + kv2[i+j] + kv3[i+j]);
  }
}

extern "C" void kernel_launch(void* const* d_in, const int* in_sizes, int n_in,
                              void* d_out, int out_size, void* d_ws, size_t ws_size,
                              hipStream_t stream)
{
  (void)in_sizes; (void)n_in; (void)out_size;
  const float* x         = (const float*)d_in[0];
  const int*   sp        = (const int*)d_in[1];
  const float* att_state = (const float*)d_in[2];
  const float* wkv_state = (const float*)d_in[3];
  const float* ffn_state = (const float*)d_in[4];
  const float* ln1_g=(const float*)d_in[5],  *ln1_b=(const float*)d_in[6];
  const float* ln2_g=(const float*)d_in[7],  *ln2_b=(const float*)d_in[8];
  const float* maa_x=(const float*)d_in[9],  *maa_w=(const float*)d_in[10], *maa_k=(const float*)d_in[11];
  const float* maa_v=(const float*)d_in[12], *maa_r=(const float*)d_in[13], *maa_g=(const float*)d_in[14];
  const float* tm_w1=(const float*)d_in[15], *tm_w2=(const float*)d_in[16];
  const float* td=(const float*)d_in[17],    *td_w1=(const float*)d_in[18], *td_w2=(const float*)d_in[19];
  const float* u = (const float*)d_in[20];
  const float* Wr=(const float*)d_in[21], *Wk=(const float*)d_in[22], *Wv=(const float*)d_in[23];
  const float* Wg=(const float*)d_in[24], *Wo=(const float*)d_in[25];
  const float* lnx_g=(const float*)d_in[26], *lnx_b=(const float*)d_in[27];
  const float* cm_k=(const float*)d_in[28],  *cm_r=(const float*)d_in[29];
  const float* Wck=(const float*)d_in[30], *Wcv=(const float*)d_in[31], *Wcr=(const float*)d_in[32];

  char* ws = (char*)d_ws;
  const size_t SLOT  = (size_t)TT*CC*4;
  const size_t BSLOT = (size_t)TT*CC*2;
  const size_t WT_SZ = (size_t)4*CC*CC*2;
  const size_t NEED  = 6*SLOT + 10*BSLOT + WT_SZ + (4u<<20);
  if(ws_size < NEED) return;

  float* xa   = (float*)(ws + 0*SLOT);
  float* xxb  = (float*)(ws + 1*SLOT);
  float* zw   = (float*)(ws + 2*SLOT);
  float* decb = (float*)(ws + 3*SLOT);
  float* yb   = (float*)(ws + 4*SLOT);
  float* S5   = (float*)(ws + 5*SLOT);
  float* BS   = xa;
  float* xxxPart = zw;
  float* h1Part  = yb;
  short* bA   = (short*)(ws + 6*SLOT);
  short* bO   = (short*)(ws + 6*SLOT + 4*BSLOT);
  short* b1 = bO + 0*(TT*CC);
  short* b2 = bO + 1*(TT*CC);
  short* b3 = bO + 2*(TT*CC);
  short* b4 = bO + 3*(TT*CC);
  short* b5 = bO + 4*(TT*CC);
  short* b6 = bO + 5*(TT*CC);
  short* WT = (short*)(ws + 6*SLOT + 10*BSLOT);
  char*  aux = (char*)WT + WT_SZ;
  float* xxxb = (float*)(aux);
  float* h1b  = (float*)(aux + (2u<<20));
  float* Pc   = (float*)(aux + (5u<<19));
  float* xmid = (float*)d_out;

  dim3 B256(256), B512(512);
  const int NTC8 = TT*CC/8/256;

  // ---- Tmix front ----
  ln_kernel<<<TT, B256, 0, stream>>>(x, ln1_g, ln1_b, xa, 1e-5f);
  shift1_kernel<<<TT, B256, 0, stream>>>(xa, att_state, sp, xxb);
  zprep_kernel<<<NTC8, B256, 0, stream>>>(xa, xxb, maa_x, bA);
  transpose_f2bf_kernel<<<dim3(4, CC/64), B256, 0, stream>>>(tm_w1, WT, CC, 160);
  gemm_bt_kernel<5><<<dim3(2, TT/128, 8), B256, 0, stream>>>(bA, WT, xxxPart, TT, 256, CC, 256,
      256, 256, (long)TT*256);
  tanh_reduce_kernel<256,160><<<TT, B256, 0, stream>>>(xxxPart, xxxb);
  mix5_kernel<<<NTC8, B256, 0, stream>>>(xxxb, tm_w2, xa, xxb,
      maa_w, maa_k, maa_v, maa_r, maa_g,
      b5, bA + 1*(TT*CC), bA + 2*(TT*CC), bA, bA + 3*(TT*CC));
  transpose_f2bf_kernel<<<dim3(2, CC/64), B256, 0, stream>>>(td_w1, WT, CC, 64);
  gemm_bt_kernel<5><<<dim3(1, TT/128, 8), B256, 0, stream>>>(b5, WT, h1Part, TT, 128, CC, 256,
      256, 256, (long)TT*128);
  tanh_reduce_kernel<128,64><<<TT/2, B256, 0, stream>>>(h1Part, h1b);
  dec_kernel<<<NTC8, B256, 0, stream>>>(h1b, td_w2, td, decb);

  // ---- r,k,v,g projections: batched 256^2 8-phase GEMM (256 blocks) ----
  WPtr4 w4; w4.w[0]=Wr; w4.w[1]=Wk; w4.w[2]=Wv; w4.w[3]=Wg;
  transpose4_f2bf_kernel<<<dim3(CC/64, CC/64, 4), B256, 0, stream>>>(w4, WT);
  gemm256_kernel<6><<<dim3(CC/256, TT/256, 4), B512, 0, stream>>>(bA, WT, b1, TT, CC, CC, CC,
      (long)TT*CC, (long)CC*CC, (long)TT*CC);

  // ---- WKV chunked scan ----
  wkv_chunk_kernel<<<NCHUNK*NH, B256, 0, stream>>>(b1, b2, b3, decb, wkv_state, u, sp,
                                                   yb, b5, BS, Pc);
  wkv_combine_kernel<<<NH*HSZ*HSZ/256, B256, 0, stream>>>(BS, Pc);
  wkv_corr_kernel<<<NCHUNK*NH, B256, 0, stream>>>(b5, BS, yb);
  gn_mul_kernel<<<TT, B256, 0, stream>>>(yb, b4, lnx_g, lnx_b, b6);

  // ---- output projection (128^2 split-K=2) + fused residual+LN2 ----
  transpose_f2bf_kernel<<<dim3(CC/64, CC/64), B256, 0, stream>>>(Wo, WT, CC, CC);
  gemm_bt_kernel<5><<<dim3(CC/128, TT/128, 2), B256, 0, stream>>>(b6, WT, yb, TT, CC, CC, 1024,
      1024, 1024, (long)TT*CC);
  ln2_fused_kernel<<<TT, B256, 0, stream>>>(yb, S5, x, ln2_g, ln2_b, xmid, zw, 1e-5f);

  // ---- CMix ----
  shift2_kernel<<<TT, B256, 0, stream>>>(zw, ffn_state, sp, cm_k, cm_r, bA, bA + 1*(TT*CC));
  transpose_f2bf_kernel<<<dim3(FFND/64, CC/64), B256, 0, stream>>>(Wck, WT, CC, FFND);
  gemm256_kernel<3><<<dim3(FFND/256, TT/256, 1), B512, 0, stream>>>(bA, WT, b1, TT, FFND, CC, CC,
      0, 0, 0);
  transpose_f2bf_kernel<<<dim3(CC/64, FFND/64), B256, 0, stream>>>(Wcv, WT, FFND, CC);
  gemm256_kernel<5><<<dim3(CC/256, TT/256, 4), B512, 0, stream>>>(b1, WT, zw, TT, CC, FFND, 1792,
      1792, 1792, (long)TT*CC);
  transpose_f2bf_kernel<<<dim3(CC/64, CC/64), B256, 0, stream>>>(Wcr, WT, CC, CC);
  gemm_bt_kernel<5><<<dim3(CC/128, TT/128, 2), B256, 0, stream>>>(bA + 1*(TT*CC), WT, xa, TT, CC, CC, 1024,
      1024, 1024, (long)TT*CC);
  final_kernel<<<NTC8, B256, 0, stream>>>(xa, xxb, zw, decb, yb, S5, xmid);
}

// Round 9
// 699.121 us; speedup vs baseline: 2.7715x; 1.0935x over previous
//
#include <hip/hip_runtime.h>
#include <stdint.h>

// RWKV6 block: B=1, T=2048, C=2048, H=32, HS=64, FFN=7168, NS=4
// Workspace: 6*16M (f32) + 4*8M (bA) + 6*8M (bO) + 32M (WT) + 4M aux = 212 MiB.

#define TT 2048
#define CC 2048
#define NH 32
#define HSZ 64
#define FFND 7168
#define CHUNK 32
#define NCHUNK 64

typedef __attribute__((ext_vector_type(8))) short short8;
typedef __attribute__((ext_vector_type(4))) float f32x4;

__device__ __forceinline__ float bf2f(short s){
  return __uint_as_float(((uint32_t)(uint16_t)s) << 16);
}
__device__ __forceinline__ short f2bf(float f){
  uint32_t u = __float_as_uint(f);
  u = u + 0x7fffu + ((u >> 16) & 1u);
  return (short)(u >> 16);
}

// ---------------- LayerNorm (row over C) ----------------
__global__ __launch_bounds__(256) void ln_kernel(
    const float* __restrict__ xin, const float* __restrict__ gam,
    const float* __restrict__ bet, float* __restrict__ out, float eps)
{
  int t = blockIdx.x, tid = threadIdx.x;
  const float* row = xin + (size_t)t*CC;
  float4 v0 = *(const float4*)(row + tid*8);
  float4 v1 = *(const float4*)(row + tid*8 + 4);
  float s  = v0.x+v0.y+v0.z+v0.w + v1.x+v1.y+v1.z+v1.w;
  float ss = v0.x*v0.x+v0.y*v0.y+v0.z*v0.z+v0.w*v0.w
           + v1.x*v1.x+v1.y*v1.y+v1.z*v1.z+v1.w*v1.w;
  #pragma unroll
  for(int off=1; off<64; off<<=1){ s += __shfl_xor(s,off); ss += __shfl_xor(ss,off); }
  __shared__ float sm[8];
  int w = tid>>6;
  if((tid&63)==0){ sm[w]=s; sm[4+w]=ss; }
  __syncthreads();
  s = sm[0]+sm[1]+sm[2]+sm[3]; ss = sm[4]+sm[5]+sm[6]+sm[7];
  float mean = s * (1.f/CC);
  float var  = ss * (1.f/CC) - mean*mean;
  float rstd = rsqrtf(var + eps);
  float* orow = out + (size_t)t*CC;
  int c = tid*8;
  float vv[8] = {v0.x,v0.y,v0.z,v0.w,v1.x,v1.y,v1.z,v1.w};
  #pragma unroll
  for(int j=0;j<8;j++) orow[c+j] = (vv[j]-mean)*rstd*gam[c+j] + bet[c+j];
}

// ---------------- fused: xmid = p0+p1+x ; zw = LN(xmid) ----------------
__global__ __launch_bounds__(256) void ln2_fused_kernel(
    const float* __restrict__ p0, const float* __restrict__ p1,
    const float* __restrict__ xres, const float* __restrict__ gam,
    const float* __restrict__ bet, float* __restrict__ xsum,
    float* __restrict__ lnout, float eps)
{
  int t = blockIdx.x, tid = threadIdx.x;
  size_t base = (size_t)t*CC + tid*8;
  float vv[8];
  float s = 0.f, ss = 0.f;
  #pragma unroll
  for(int j=0;j<8;j++){
    float v = p0[base+j] + p1[base+j] + xres[base+j];
    vv[j] = v; s += v; ss += v*v;
    xsum[base+j] = v;
  }
  #pragma unroll
  for(int off=1; off<64; off<<=1){ s += __shfl_xor(s,off); ss += __shfl_xor(ss,off); }
  __shared__ float sm[8];
  int w = tid>>6;
  if((tid&63)==0){ sm[w]=s; sm[4+w]=ss; }
  __syncthreads();
  s = sm[0]+sm[1]+sm[2]+sm[3]; ss = sm[4]+sm[5]+sm[6]+sm[7];
  float mean = s * (1.f/CC);
  float var  = ss * (1.f/CC) - mean*mean;
  float rstd = rsqrtf(var + eps);
  int c = tid*8;
  #pragma unroll
  for(int j=0;j<8;j++) lnout[base+j] = (vv[j]-mean)*rstd*gam[c+j] + bet[c+j];
}

// ---------------- token shift (attention): xx = sh - xa (f32 out) ----------------
__global__ __launch_bounds__(256) void shift1_kernel(
    const float* __restrict__ xa, const float* __restrict__ st,
    const int* __restrict__ sp, float* __restrict__ xxb)
{
  int t = blockIdx.x, tid = threadIdx.x;
  int sp0=sp[0], sp1=sp[1], sp2=sp[2], sp3=sp[3];
  bool is_start = (sp0==t)|(sp1==t)|(sp2==t)|(sp3==t);
  int sid = (sp0<=t)+(sp1<=t)+(sp2<=t)+(sp3<=t) - 1;
  sid = sid<0?0:(sid>3?3:sid);
  int c = tid*8;
  const float* src = is_start ? (st + (size_t)sid*CC + c)
                   : (t>0 ? xa + (size_t)(t-1)*CC + c : nullptr);
  const float* cur = xa + (size_t)t*CC + c;
  float* o = xxb + (size_t)t*CC + c;
  #pragma unroll
  for(int jj=0;jj<8;jj++){
    float sh = src ? src[jj] : 0.f;
    o[jj] = sh - cur[jj];
  }
}

// ---------------- token shift (ffn): xk2/xr2 fused, bf16 out ----------------
__global__ __launch_bounds__(256) void shift2_kernel(
    const float* __restrict__ xf, const float* __restrict__ st,
    const int* __restrict__ sp, const float* __restrict__ cmk,
    const float* __restrict__ cmr, short* __restrict__ xk2, short* __restrict__ xr2)
{
  int t = blockIdx.x, tid = threadIdx.x;
  int sp0=sp[0], sp1=sp[1], sp2=sp[2], sp3=sp[3];
  bool is_start = (sp0==t)|(sp1==t)|(sp2==t)|(sp3==t);
  int sid = (sp0<=t)+(sp1<=t)+(sp2<=t)+(sp3<=t) - 1;
  sid = sid<0?0:(sid>3?3:sid);
  int c = tid*8;
  const float* src = is_start ? (st + (size_t)sid*CC + c)
                   : (t>0 ? xf + (size_t)(t-1)*CC + c : nullptr);
  const float* cur = xf + (size_t)t*CC + c;
  size_t ix = (size_t)t*CC + c;
  #pragma unroll
  for(int jj=0;jj<8;jj++){
    float xfv = cur[jj];
    float sh = src ? src[jj] : 0.f;
    float d = sh - xfv;
    xk2[ix+jj] = f2bf(xfv + d*cmk[c+jj]);
    xr2[ix+jj] = f2bf(xfv + d*cmr[c+jj]);
  }
}

// ---------------- z = xa + xx*maa_x -> bf16 ----------------
__global__ __launch_bounds__(256) void zprep_kernel(const float* __restrict__ xa,
   const float* __restrict__ xx, const float* __restrict__ maa, short* __restrict__ z)
{
  size_t i = ((size_t)blockIdx.x*256 + threadIdx.x)*8;
  int c = (int)(i & (CC-1));
  #pragma unroll
  for(int j=0;j<8;j++) z[i+j] = f2bf(xa[i+j] + xx[i+j]*maa[c+j]);
}

// ---------------- fused 5-way maa mix -> bf16 outputs ----------------
// t0/c derived from blockIdx only => xxxb index is wave-uniform => SMEM loads.
__global__ __launch_bounds__(256) void mix5_kernel(
    const float* __restrict__ xxxb, const float* __restrict__ w2,
    const float* __restrict__ xa, const float* __restrict__ xxv,
    const float* __restrict__ mw, const float* __restrict__ mk,
    const float* __restrict__ mv, const float* __restrict__ mr,
    const float* __restrict__ mg,
    short* __restrict__ ow, short* __restrict__ ok, short* __restrict__ ov,
    short* __restrict__ orr, short* __restrict__ og)
{
  int t0 = (blockIdx.x >> 3) * 8;                  // uniform (no tid)
  int c  = ((blockIdx.x & 7) << 8) + threadIdx.x;  // 0..2047
  float acc[5][8];
  #pragma unroll
  for(int s=0;s<5;s++)
    #pragma unroll
    for(int tt=0;tt<8;tt++) acc[s][tt]=0.f;
  #pragma unroll
  for(int s=0;s<5;s++){
    for(int e=0;e<32;e++){
      float wv = w2[(size_t)(s*32+e)*CC + c];
      #pragma unroll
      for(int tt=0;tt<8;tt++)
        acc[s][tt] += xxxb[(size_t)(t0+tt)*160 + s*32 + e] * wv;
    }
  }
  float vmw=mw[c], vmk=mk[c], vmv=mv[c], vmr=mr[c], vmg=mg[c];
  #pragma unroll
  for(int tt=0;tt<8;tt++){
    size_t ix = (size_t)(t0+tt)*CC + c;
    float av = xa[ix], xv = xxv[ix];
    ow[ix]  = f2bf(av + xv*(vmw + acc[0][tt]));
    ok[ix]  = f2bf(av + xv*(vmk + acc[1][tt]));
    ov[ix]  = f2bf(av + xv*(vmv + acc[2][tt]));
    orr[ix] = f2bf(av + xv*(vmr + acc[3][tt]));
    og[ix]  = f2bf(av + xv*(vmg + acc[4][tt]));
  }
}

// ---------------- dec = exp(-exp(td + h1 @ td_w2)) (f32) ----------------
// Same uniformity transform: h1b index wave-uniform => SMEM.
__global__ __launch_bounds__(256) void dec_kernel(
    const float* __restrict__ h1b, const float* __restrict__ tw2,
    const float* __restrict__ td, float* __restrict__ out)
{
  int t0 = (blockIdx.x >> 3) * 8;
  int c  = ((blockIdx.x & 7) << 8) + threadIdx.x;
  float acc[8] = {0,0,0,0,0,0,0,0};
  for(int e=0;e<64;e++){
    float wv = tw2[(size_t)e*CC + c];
    #pragma unroll
    for(int tt=0;tt<8;tt++) acc[tt] += h1b[(size_t)(t0+tt)*64 + e]*wv;
  }
  float tdc = td[c];
  #pragma unroll
  for(int tt=0;tt<8;tt++)
    out[(size_t)(t0+tt)*CC + c] = expf(-expf(tdc + acc[tt]));
}

// ---------------- tanh split-K reduce ----------------
template<int N, int NK>
__global__ __launch_bounds__(256) void tanh_reduce_kernel(
    const float* __restrict__ part, float* __restrict__ out)
{
  int idx = blockIdx.x*256 + threadIdx.x;
  int col = idx & (N-1);
  int row = idx >> (N==256 ? 8 : 7);
  float s = 0.f;
  #pragma unroll
  for(int z=0;z<8;z++) s += part[(size_t)z*TT*N + idx];
  if(col < NK) out[(size_t)row*NK + col] = tanhf(s);
}

// ---------------- W[K,N] f32 -> Wt[NPAD,K] bf16 ----------------
__global__ __launch_bounds__(256) void transpose_f2bf_kernel(
    const float* __restrict__ W, short* __restrict__ Wt, int K, int N)
{
  __shared__ float tile[64][65];
  int n0 = blockIdx.x*64, k0 = blockIdx.y*64;
  int tid = threadIdx.x;
  #pragma unroll
  for(int q=0;q<16;q++){
    int ix = q*256 + tid;
    int r = ix >> 6, cc2 = ix & 63;
    tile[r][cc2] = (n0 + cc2 < N) ? W[(size_t)(k0+r)*N + n0 + cc2] : 0.f;
  }
  __syncthreads();
  #pragma unroll
  for(int q=0;q<16;q++){
    int ix = q*256 + tid;
    int r = ix >> 6, cc2 = ix & 63;
    Wt[(size_t)(n0+r)*K + k0 + cc2] = f2bf(tile[cc2][r]);
  }
}

struct WPtr4 { const float* w[4]; };
__global__ __launch_bounds__(256) void transpose4_f2bf_kernel(
    WPtr4 ws4, short* __restrict__ Wt)
{
  __shared__ float tile[64][65];
  int z = blockIdx.z;
  const float* W = ws4.w[z];
  short* dst = Wt + (size_t)z*CC*CC;
  int n0 = blockIdx.x*64, k0 = blockIdx.y*64;
  int tid = threadIdx.x;
  #pragma unroll
  for(int q=0;q<16;q++){
    int ix = q*256 + tid;
    int r = ix >> 6, cc2 = ix & 63;
    tile[r][cc2] = W[(size_t)(k0+r)*CC + n0 + cc2];
  }
  __syncthreads();
  #pragma unroll
  for(int q=0;q<16;q++){
    int ix = q*256 + tid;
    int r = ix >> 6, cc2 = ix & 63;
    dst[(size_t)(n0+r)*CC + k0 + cc2] = f2bf(tile[cc2][r]);
  }
}

__device__ __forceinline__ void load_lds16(const void* g, void* l){
  __builtin_amdgcn_global_load_lds(
      (const __attribute__((address_space(1))) uint32_t*)g,
      (__attribute__((address_space(3))) uint32_t*)l, 16, 0, 0);
}

// ---------------- 128^2 MFMA GEMM (m97-structure + swizzle) ----------------
// EPI: 0 bf16; 3 relu^2 bf16; 5 f32 partial slab; 6 rkvg batch
template<int EPI>
__global__ __launch_bounds__(256) void gemm_bt_kernel(
    const short* __restrict__ A, const short* __restrict__ Bt,
    void* __restrict__ Cout, int M, int N, int Kstride, int Klen,
    long zA, long zB, long zC)
{
  __shared__ __align__(16) short As[128*64];
  __shared__ __align__(16) short Bs[128*64];
  int z = blockIdx.z;
  const short* A0 = A + (size_t)z*zA;
  const short* B0 = Bt + (size_t)z*zB;
  int tid = threadIdx.x;
  int w = tid >> 6, lane = tid & 63;
  int l16 = lane & 15, lhi = lane >> 4;
  int wr = w >> 1, wc = w & 1;
  int gx = gridDim.x;
  int nwg = gx*gridDim.y;
  int lin = blockIdx.y*gx + blockIdx.x;
  int wg = (lin & 7)*(nwg >> 3) + (lin >> 3);
  int bn = wg % gx, bm = wg / gx;
  const short* Ab = A0 + (size_t)bm*128*Kstride;
  const short* Bb = B0 + (size_t)bn*128*Kstride;
  int srow = w*8 + (lane>>3);
  int scol = lane & 7;
  f32x4 acc[4][4] = {};
  for(int kt=0; kt<Klen; kt+=64){
    __syncthreads();
    #pragma unroll
    for(int q=0;q<4;q++){
      int row = q*32 + srow;
      int c8 = scol ^ (row & 7);
      int ldsoff = (q*256 + w*64)*8;
      load_lds16(Ab + (size_t)row*Kstride + kt + c8*8, As + ldsoff);
      load_lds16(Bb + (size_t)row*Kstride + kt + c8*8, Bs + ldsoff);
    }
    __syncthreads();
    #pragma unroll
    for(int kk=0;kk<2;kk++){
      short8 af[4], bf[4];
      #pragma unroll
      for(int m=0;m<4;m++){
        int row = wr*64 + m*16 + l16;
        int slot = (kk*4 + lhi) ^ (row & 7);
        af[m] = *(const short8*)(As + row*64 + slot*8);
      }
      #pragma unroll
      for(int n=0;n<4;n++){
        int row = wc*64 + n*16 + l16;
        int slot = (kk*4 + lhi) ^ (row & 7);
        bf[n] = *(const short8*)(Bs + row*64 + slot*8);
      }
      #pragma unroll
      for(int m=0;m<4;m++){
        #pragma unroll
        for(int n=0;n<4;n++)
          acc[m][n] = __builtin_amdgcn_mfma_f32_16x16x32_bf16(af[m], bf[n], acc[m][n], 0, 0, 0);
      }
    }
  }
  int m0 = bm*128 + wr*64;
  int n0 = bn*128 + wc*64;
  #pragma unroll
  for(int m=0;m<4;m++){
    #pragma unroll
    for(int n=0;n<4;n++){
      #pragma unroll
      for(int jj=0;jj<4;jj++){
        int row = m0 + m*16 + lhi*4 + jj;
        int col = n0 + n*16 + l16;
        size_t ix = (size_t)row*N + col;
        float val = acc[m][n][jj];
        if constexpr (EPI==0){ ((short*)Cout)[(size_t)z*zC + ix] = f2bf(val); }
        else if constexpr (EPI==3){ float rv = fmaxf(val, 0.f); ((short*)Cout)[ix] = f2bf(rv*rv); }
        else if constexpr (EPI==5){ ((float*)Cout)[(size_t)z*zC + ix] = val; }
        else {
          short* o = (short*)Cout + (size_t)z*zC;
          o[ix] = (z==3) ? f2bf(val/(1.f+expf(-val))) : f2bf(val);
        }
      }
    }
  }
}

// ---------------- 256^2 MFMA GEMM, fine 8-phase counted-vmcnt schedule ------
template<int EPI>
__global__ __launch_bounds__(512, 1) void gemm256_kernel(
    const short* __restrict__ A, const short* __restrict__ Bt,
    void* __restrict__ Cout, int M, int N, int Kstride, int Klen,
    long zA, long zB, long zC)
{
  __shared__ __align__(16) short As[2][256*64];
  __shared__ __align__(16) short Bs[2][256*64];
  int z = blockIdx.z;
  const short* A0 = A + (size_t)z*zA;
  const short* B0 = Bt + (size_t)z*zB;
  int tid = threadIdx.x;
  int w = tid >> 6, lane = tid & 63;
  int l16 = lane & 15, lhi = lane >> 4;
  int wr = w >> 2, wc = w & 3;
  int gx = gridDim.x;
  int nwg = gx*gridDim.y;
  int lin = blockIdx.y*gx + blockIdx.x;
  int wg = (lin & 7)*(nwg >> 3) + (lin >> 3);
  int bn = wg % gx, bm = wg / gx;
  const short* Ab = A0 + (size_t)bm*256*Kstride;
  const short* Bb = B0 + (size_t)bn*256*Kstride;
  int srow_w = w*8 + (lane>>3);
  int scol = lane & 7;
  f32x4 acc[8][4] = {};

  auto STG = [&](const short* src, short* dst, int half, int kt){
    #pragma unroll
    for(int q=0;q<2;q++){
      int row = half*128 + q*64 + srow_w;
      int c8 = scol ^ (row & 7);
      load_lds16(src + (size_t)row*Kstride + kt + c8*8,
                 dst + (half*128 + q*64 + w*8)*64);
    }
  };
  auto DSA = [&](const short* Ac, int p, short8 afr[2][2]){
    #pragma unroll
    for(int mm=0;mm<2;mm++)
      #pragma unroll
      for(int kk=0;kk<2;kk++){
        int row = wr*128 + (p*2+mm)*16 + l16;
        int slot = (kk*4 + lhi) ^ (row & 7);
        afr[mm][kk] = *(const short8*)(Ac + row*64 + slot*8);
      }
  };
  auto DSB = [&](const short* Bc, short8 bfr[4][2]){
    #pragma unroll
    for(int n=0;n<4;n++)
      #pragma unroll
      for(int kk=0;kk<2;kk++){
        int row = wc*64 + n*16 + l16;
        int slot = (kk*4 + lhi) ^ (row & 7);
        bfr[n][kk] = *(const short8*)(Bc + row*64 + slot*8);
      }
  };
  auto MM = [&](int p, short8 afr[2][2], short8 bfr[4][2]){
    __builtin_amdgcn_s_setprio(1);
    #pragma unroll
    for(int mm=0;mm<2;mm++)
      #pragma unroll
      for(int n=0;n<4;n++)
        #pragma unroll
        for(int kk=0;kk<2;kk++)
          acc[p*2+mm][n] = __builtin_amdgcn_mfma_f32_16x16x32_bf16(
              afr[mm][kk], bfr[n][kk], acc[p*2+mm][n], 0, 0, 0);
    __builtin_amdgcn_s_setprio(0);
  };
  #define PH_SYNC() do{ __builtin_amdgcn_s_barrier(); \
      asm volatile("s_waitcnt lgkmcnt(0)" ::: "memory"); \
      __builtin_amdgcn_sched_barrier(0); }while(0)
  #define PH_END() do{ __builtin_amdgcn_s_barrier(); \
      __builtin_amdgcn_sched_barrier(0); }while(0)

  int NT = Klen >> 6;
  int niter = NT >> 1;
  STG(Ab, &As[0][0], 0, 0); STG(Ab, &As[0][0], 1, 0);
  STG(Bb, &Bs[0][0], 0, 0); STG(Bb, &Bs[0][0], 1, 0);
  STG(Bb, &Bs[1][0], 0, 64); STG(Bb, &Bs[1][0], 1, 64);
  asm volatile("s_waitcnt vmcnt(4)" ::: "memory");
  __builtin_amdgcn_s_barrier();
  __builtin_amdgcn_sched_barrier(0);

  for(int i=0;i<niter;++i){
    int kt_o  = (2*i+1) << 6;
    int kt_e2 = (2*i+2) << 6;
    int kt_o2 = (2*i+3) << 6;
    bool st = (i+1 < niter);
    short8 bfr[4][2], afr[2][2];
    DSB(&Bs[0][0], bfr);
    DSA(&As[0][0], 0, afr);
    STG(Ab, &As[1][0], 0, kt_o);
    PH_SYNC(); MM(0, afr, bfr); PH_END();
    DSA(&As[0][0], 1, afr);
    STG(Ab, &As[1][0], 1, kt_o);
    PH_SYNC(); MM(1, afr, bfr); PH_END();
    DSA(&As[0][0], 2, afr);
    if(st) STG(Bb, &Bs[0][0], 0, kt_e2);
    PH_SYNC(); MM(2, afr, bfr); PH_END();
    DSA(&As[0][0], 3, afr);
    if(st) STG(Bb, &Bs[0][0], 1, kt_e2);
    asm volatile("s_waitcnt vmcnt(4)" ::: "memory");
    PH_SYNC(); MM(3, afr, bfr); PH_END();
    DSB(&Bs[1][0], bfr);
    DSA(&As[1][0], 0, afr);
    if(st) STG(Ab, &As[0][0], 0, kt_e2);
    PH_SYNC(); MM(0, afr, bfr); PH_END();
    DSA(&As[1][0], 1, afr);
    if(st) STG(Ab, &As[0][0], 1, kt_e2);
    PH_SYNC(); MM(1, afr, bfr); PH_END();
    DSA(&As[1][0], 2, afr);
    if(st) STG(Bb, &Bs[1][0], 0, kt_o2);
    PH_SYNC(); MM(2, afr, bfr); PH_END();
    DSA(&As[1][0], 3, afr);
    if(st) STG(Bb, &Bs[1][0], 1, kt_o2);
    asm volatile("s_waitcnt vmcnt(4)" ::: "memory");
    PH_SYNC(); MM(3, afr, bfr); PH_END();
  }
  #undef PH_SYNC
  #undef PH_END

  int m0 = bm*256 + wr*128;
  int n0 = bn*256 + wc*64;
  #pragma unroll
  for(int m=0;m<8;m++){
    #pragma unroll
    for(int n=0;n<4;n++){
      #pragma unroll
      for(int jj=0;jj<4;jj++){
        int row = m0 + m*16 + lhi*4 + jj;
        int col = n0 + n*16 + l16;
        size_t ix = (size_t)row*N + col;
        float val = acc[m][n][jj];
        if constexpr (EPI==3){ float rv = fmaxf(val, 0.f); ((short*)Cout)[ix] = f2bf(rv*rv); }
        else if constexpr (EPI==5){ ((float*)Cout)[(size_t)z*zC + ix] = val; }
        else {
          short* o = (short*)Cout + (size_t)z*zC;
          o[ix] = (z==3) ? f2bf(val/(1.f+expf(-val))) : f2bf(val);
        }
      }
    }
  }
}

// ---------------- WKV pass A ----------------
__global__ __launch_bounds__(256) void wkv_chunk_kernel(
    const short* __restrict__ rb, const short* __restrict__ kb,
    const short* __restrict__ vb, const float* __restrict__ db,
    const float* __restrict__ wkv_state, const float* __restrict__ u,
    const int* __restrict__ sp,
    float* __restrict__ yb, short* __restrict__ rtb,
    float* __restrict__ Bc, float* __restrict__ Pc)
{
  int blk = blockIdx.x;
  int ch = blk >> 5;
  int h  = blk & 31;
  int tid = threadIdx.x;
  int a = tid & 3, j = tid >> 2;
  int w = tid >> 6, lane = tid & 63;
  __shared__ float sr[2][64], sk[2][64], suk[2][64], sv[2][64], sd[2][64];
  __shared__ float sp_[64];
  float u_reg = (w==1) ? u[h*64 + lane] : 0.f;
  if(tid < 64) sp_[tid] = 1.f;
  float S[16];
  #pragma unroll
  for(int ii=0;ii<16;ii++) S[ii]=0.f;
  int sp0=sp[0], sp1=sp[1], sp2=sp[2], sp3=sp[3];
  int tbase = ch*CHUNK;
  {
    size_t gb = (size_t)tbase*CC + h*64;
    if(w==0)      sr[0][lane] = bf2f(rb[gb+lane]);
    else if(w==1){ float kv_=bf2f(kb[gb+lane]); sk[0][lane]=kv_; suk[0][lane]=u_reg*kv_; }
    else if(w==2) sv[0][lane] = bf2f(vb[gb+lane]);
    else          sd[0][lane] = db[gb+lane];
  }
  __syncthreads();
  for(int tl=0; tl<CHUNK; ++tl){
    int t = tbase + tl;
    int buf = tl & 1;
    if(tl+1 < CHUNK){
      size_t nb = (size_t)(t+1)*CC + h*64;
      int b2_ = buf^1;
      if(w==0)      sr[b2_][lane] = bf2f(rb[nb+lane]);
      else if(w==1){ float kv_=bf2f(kb[nb+lane]); sk[b2_][lane]=kv_; suk[b2_][lane]=u_reg*kv_; }
      else if(w==2) sv[b2_][lane] = bf2f(vb[nb+lane]);
      else          sd[b2_][lane] = db[nb+lane];
    }
    size_t base = (size_t)t*CC + h*64;
    bool is_start = (sp0==t)|(sp1==t)|(sp2==t)|(sp3==t);
    if(is_start){
      int sid = (sp0<=t)+(sp1<=t)+(sp2<=t)+(sp3<=t) - 1;
      sid = sid<0?0:(sid>3?3:sid);
      const float* wsrc = wkv_state + (((size_t)sid*NH + h)*HSZ + a*16)*HSZ + j;
      #pragma unroll
      for(int ii=0;ii<16;ii++) S[ii] = wsrc[(size_t)ii*HSZ];
      if(tid < 64) sp_[tid] = 0.f;
    }
    float vj = sv[buf][j];
    float yp = 0.f, bp = 0.f;
    #pragma unroll
    for(int ii=0;ii<16;ii++){
      int i = a*16 + ii;
      float ri = sr[buf][i];
      yp += ri * S[ii];
      bp += ri * suk[buf][i];
    }
    yp += __shfl_xor(yp, 1); yp += __shfl_xor(yp, 2);
    bp += __shfl_xor(bp, 1); bp += __shfl_xor(bp, 2);
    if(a == 0) yb[base + j] = yp + bp*vj;
    if(tid < 64){
      rtb[base + tid] = f2bf(sr[buf][tid] * sp_[tid]);
      sp_[tid] *= sd[buf][tid];
    }
    #pragma unroll
    for(int ii=0;ii<16;ii++){
      int i = a*16 + ii;
      S[ii] = sd[buf][i]*S[ii] + sk[buf][i]*vj;
    }
    __syncthreads();
  }
  size_t cb = ((size_t)ch*NH + h)*HSZ*HSZ;
  #pragma unroll
  for(int ii=0;ii<16;ii++) Bc[cb + (size_t)(a*16+ii)*HSZ + j] = S[ii];
  if(tid < 64) Pc[((size_t)ch*NH + h)*HSZ + tid] = sp_[tid];
}

// ---------------- WKV pass B ----------------
__global__ __launch_bounds__(256) void wkv_combine_kernel(
    float* __restrict__ BS, const float* __restrict__ Pc)
{
  int idx = blockIdx.x*256 + threadIdx.x;
  int hi = idx >> 6;
  float s = 0.f;
  for(int cc=0; cc<NCHUNK; ++cc){
    size_t ix = (size_t)cc*(NH*HSZ*HSZ) + idx;
    float b = BS[ix];
    BS[ix] = s;
    s = Pc[cc*(NH*HSZ) + hi]*s + b;
  }
}

// ---------------- WKV pass C ----------------
__global__ __launch_bounds__(256) void wkv_corr_kernel(
    const short* __restrict__ rtb, const float* __restrict__ Sin, float* __restrict__ yb)
{
  int blk = blockIdx.x;
  int ch = blk >> 5, h = blk & 31;
  __shared__ float Ssm[64][64];
  __shared__ float Rsm[32][65];
  int tid = threadIdx.x;
  const float* Sp = Sin + (size_t)(ch*NH + h)*HSZ*HSZ;
  #pragma unroll
  for(int q=0;q<16;q++) ((float*)Ssm)[q*256+tid] = Sp[q*256+tid];
  #pragma unroll
  for(int q=0;q<8;q++){
    int ix = q*256 + tid;
    int tl = ix>>6, i = ix&63;
    Rsm[tl][i] = bf2f(rtb[(size_t)(ch*CHUNK+tl)*CC + h*64 + i]);
  }
  __syncthreads();
  int tl = tid >> 3;
  int jq = tid & 7;
  float acc[8];
  #pragma unroll
  for(int jj=0;jj<8;jj++) acc[jj]=0.f;
  for(int i=0;i<64;i++){
    float rv = Rsm[tl][i];
    #pragma unroll
    for(int jj=0;jj<8;jj++) acc[jj] += rv * Ssm[i][jq*8+jj];
  }
  #pragma unroll
  for(int jj=0;jj<8;jj++)
    yb[(size_t)(ch*CHUNK+tl)*CC + h*64 + jq*8+jj] += acc[jj];
}

// ---------------- GroupNorm(H groups) * g -> bf16 ----------------
__global__ __launch_bounds__(256) void gn_mul_kernel(
    const float* __restrict__ yb, const short* __restrict__ gb,
    const float* __restrict__ gam, const float* __restrict__ bet,
    short* __restrict__ yg)
{
  int t = blockIdx.x, tid = threadIdx.x;
  int w = tid >> 6, lane = tid & 63;
  for(int q=0;q<8;q++){
    int h = q*4 + w;
    int cc = h*64 + lane;
    float val = yb[(size_t)t*CC + cc];
    float s = val, ss = val*val;
    #pragma unroll
    for(int off=1;off<64;off<<=1){ s += __shfl_xor(s,off); ss += __shfl_xor(ss,off); }
    float mu = s*(1.f/64.f);
    float var = ss*(1.f/64.f) - mu*mu;
    float rstd = rsqrtf(var + 6.4e-4f);
    float o = (val-mu)*rstd*gam[cc] + bet[cc];
    yg[(size_t)t*CC + cc] = f2bf(o * bf2f(gb[(size_t)t*CC + cc]));
  }
}

// ---------------- final: out += sigmoid(s0+s1)*(kv0+kv1+kv2+kv3) ----------------
__global__ __launch_bounds__(256) void final_kernel(
    const float* __restrict__ s0, const float* __restrict__ s1,
    const float* __restrict__ kv0, const float* __restrict__ kv1,
    const float* __restrict__ kv2, const float* __restrict__ kv3,
    float* __restrict__ out)
{
  size_t i = ((size_t)blockIdx.x*256 + threadIdx.x)*8;
  #pragma unroll
  for(int j=0;j<8;j++){
    float sv = s0[i+j] + s1[i+j];
    float sig = 1.f/(1.f + expf(-sv));
    out[i+j] = out[i+j] + sig*(kv0[i+j] + kv1[i+j] + kv2[i+j] + kv3[i+j]);
  }
}

extern "C" void kernel_launch(void* const* d_in, const int* in_sizes, int n_in,
                              void* d_out, int out_size, void* d_ws, size_t ws_size,
                              hipStream_t stream)
{
  (void)in_sizes; (void)n_in; (void)out_size;
  const float* x         = (const float*)d_in[0];
  const int*   sp        = (const int*)d_in[1];
  const float* att_state = (const float*)d_in[2];
  const float* wkv_state = (const float*)d_in[3];
  const float* ffn_state = (const float*)d_in[4];
  const float* ln1_g=(const float*)d_in[5],  *ln1_b=(const float*)d_in[6];
  const float* ln2_g=(const float*)d_in[7],  *ln2_b=(const float*)d_in[8];
  const float* maa_x=(const float*)d_in[9],  *maa_w=(const float*)d_in[10], *maa_k=(const float*)d_in[11];
  const float* maa_v=(const float*)d_in[12], *maa_r=(const float*)d_in[13], *maa_g=(const float*)d_in[14];
  const float* tm_w1=(const float*)d_in[15], *tm_w2=(const float*)d_in[16];
  const float* td=(const float*)d_in[17],    *td_w1=(const float*)d_in[18], *td_w2=(const float*)d_in[19];
  const float* u = (const float*)d_in[20];
  const float* Wr=(const float*)d_in[21], *Wk=(const float*)d_in[22], *Wv=(const float*)d_in[23];
  const float* Wg=(const float*)d_in[24], *Wo=(const float*)d_in[25];
  const float* lnx_g=(const float*)d_in[26], *lnx_b=(const float*)d_in[27];
  const float* cm_k=(const float*)d_in[28],  *cm_r=(const float*)d_in[29];
  const float* Wck=(const float*)d_in[30], *Wcv=(const float*)d_in[31], *Wcr=(const float*)d_in[32];

  char* ws = (char*)d_ws;
  const size_t SLOT  = (size_t)TT*CC*4;
  const size_t BSLOT = (size_t)TT*CC*2;
  const size_t WT_SZ = (size_t)4*CC*CC*2;
  const size_t NEED  = 6*SLOT + 10*BSLOT + WT_SZ + (4u<<20);
  if(ws_size < NEED) return;

  float* xa   = (float*)(ws + 0*SLOT);
  float* xxb  = (float*)(ws + 1*SLOT);
  float* zw   = (float*)(ws + 2*SLOT);
  float* decb = (float*)(ws + 3*SLOT);
  float* yb   = (float*)(ws + 4*SLOT);
  float* S5   = (float*)(ws + 5*SLOT);
  float* BS   = xa;
  float* xxxPart = zw;
  float* h1Part  = yb;
  short* bA   = (short*)(ws + 6*SLOT);
  short* bO   = (short*)(ws + 6*SLOT + 4*BSLOT);
  short* b1 = bO + 0*(TT*CC);
  short* b2 = bO + 1*(TT*CC);
  short* b3 = bO + 2*(TT*CC);
  short* b4 = bO + 3*(TT*CC);
  short* b5 = bO + 4*(TT*CC);
  short* b6 = bO + 5*(TT*CC);
  short* WT = (short*)(ws + 6*SLOT + 10*BSLOT);
  char*  aux = (char*)WT + WT_SZ;
  float* xxxb = (float*)(aux);
  float* h1b  = (float*)(aux + (2u<<20));
  float* Pc   = (float*)(aux + (5u<<19));
  float* xmid = (float*)d_out;

  dim3 B256(256), B512(512);
  const int NTC8 = TT*CC/8/256;

  // ---- Tmix front ----
  ln_kernel<<<TT, B256, 0, stream>>>(x, ln1_g, ln1_b, xa, 1e-5f);
  shift1_kernel<<<TT, B256, 0, stream>>>(xa, att_state, sp, xxb);
  zprep_kernel<<<NTC8, B256, 0, stream>>>(xa, xxb, maa_x, bA);
  transpose_f2bf_kernel<<<dim3(4, CC/64), B256, 0, stream>>>(tm_w1, WT, CC, 160);
  gemm_bt_kernel<5><<<dim3(2, TT/128, 8), B256, 0, stream>>>(bA, WT, xxxPart, TT, 256, CC, 256,
      256, 256, (long)TT*256);
  tanh_reduce_kernel<256,160><<<TT, B256, 0, stream>>>(xxxPart, xxxb);
  mix5_kernel<<<NTC8, B256, 0, stream>>>(xxxb, tm_w2, xa, xxb,
      maa_w, maa_k, maa_v, maa_r, maa_g,
      b5, bA + 1*(TT*CC), bA + 2*(TT*CC), bA, bA + 3*(TT*CC));
  transpose_f2bf_kernel<<<dim3(2, CC/64), B256, 0, stream>>>(td_w1, WT, CC, 64);
  gemm_bt_kernel<5><<<dim3(1, TT/128, 8), B256, 0, stream>>>(b5, WT, h1Part, TT, 128, CC, 256,
      256, 256, (long)TT*128);
  tanh_reduce_kernel<128,64><<<TT/2, B256, 0, stream>>>(h1Part, h1b);
  dec_kernel<<<NTC8, B256, 0, stream>>>(h1b, td_w2, td, decb);

  // ---- r,k,v,g projections: batched 256^2 8-phase GEMM (256 blocks) ----
  WPtr4 w4; w4.w[0]=Wr; w4.w[1]=Wk; w4.w[2]=Wv; w4.w[3]=Wg;
  transpose4_f2bf_kernel<<<dim3(CC/64, CC/64, 4), B256, 0, stream>>>(w4, WT);
  gemm256_kernel<6><<<dim3(CC/256, TT/256, 4), B512, 0, stream>>>(bA, WT, b1, TT, CC, CC, CC,
      (long)TT*CC, (long)CC*CC, (long)TT*CC);

  // ---- WKV chunked scan ----
  wkv_chunk_kernel<<<NCHUNK*NH, B256, 0, stream>>>(b1, b2, b3, decb, wkv_state, u, sp,
                                                   yb, b5, BS, Pc);
  wkv_combine_kernel<<<NH*HSZ*HSZ/256, B256, 0, stream>>>(BS, Pc);
  wkv_corr_kernel<<<NCHUNK*NH, B256, 0, stream>>>(b5, BS, yb);
  gn_mul_kernel<<<TT, B256, 0, stream>>>(yb, b4, lnx_g, lnx_b, b6);

  // ---- output projection (128^2 split-K=2) + fused residual+LN2 ----
  transpose_f2bf_kernel<<<dim3(CC/64, CC/64), B256, 0, stream>>>(Wo, WT, CC, CC);
  gemm_bt_kernel<5><<<dim3(CC/128, TT/128, 2), B256, 0, stream>>>(b6, WT, yb, TT, CC, CC, 1024,
      1024, 1024, (long)TT*CC);
  ln2_fused_kernel<<<TT, B256, 0, stream>>>(yb, S5, x, ln2_g, ln2_b, xmid, zw, 1e-5f);

  // ---- CMix ----
  shift2_kernel<<<TT, B256, 0, stream>>>(zw, ffn_state, sp, cm_k, cm_r, bA, bA + 1*(TT*CC));
  transpose_f2bf_kernel<<<dim3(FFND/64, CC/64), B256, 0, stream>>>(Wck, WT, CC, FFND);
  gemm256_kernel<3><<<dim3(FFND/256, TT/256, 1), B512, 0, stream>>>(bA, WT, b1, TT, FFND, CC, CC,
      0, 0, 0);
  transpose_f2bf_kernel<<<dim3(CC/64, FFND/64), B256, 0, stream>>>(Wcv, WT, FFND, CC);
  gemm256_kernel<5><<<dim3(CC/256, TT/256, 4), B512, 0, stream>>>(b1, WT, zw, TT, CC, FFND, 1792,
      1792, 1792, (long)TT*CC);
  transpose_f2bf_kernel<<<dim3(CC/64, CC/64), B256, 0, stream>>>(Wcr, WT, CC, CC);
  gemm_bt_kernel<5><<<dim3(CC/128, TT/128, 2), B256, 0, stream>>>(bA + 1*(TT*CC), WT, xa, TT, CC, CC, 1024,
      1024, 1024, (long)TT*CC);
  final_kernel<<<NTC8, B256, 0, stream>>>(xa, xxb, zw, decb, yb, S5, xmid);
}